// Round 10
// baseline (753.457 us; speedup 1.0000x reference)
//
#include <hip/hip_runtime.h>
#include <math.h>

#define EPSV 1e-5f
#define GF_RELU 1
#define GF_ACCUM 2

typedef unsigned long long u64;
typedef unsigned int u32;
typedef float v2f __attribute__((ext_vector_type(2)));

static const int Bn = 8;
static const int Nmax = 2048;
static const int KNN_K = 8;

// ---------------- precompute: fold BN into scale/bias, zero picks ----------------
__global__ void precompute_kernel(const float* __restrict__ bn_g, const float* __restrict__ bn_b,
                                  const float* __restrict__ bp1,
                                  float* __restrict__ sc, float* __restrict__ bb,
                                  float* __restrict__ picks) {
  int t = threadIdx.x;
  if (t < 128) {
    float s = bn_g[t] / sqrtf(1.0f + EPSV);
    sc[t] = s;
    bb[t] = bp1[t] * s + bn_b[t];
  }
  for (int i = t; i < Bn * 256; i += blockDim.x) picks[i] = 0.0f;
}

// ---------------- repack Ws/Wn [L][h][d][e] -> [L][d][h*128+e] -----------------
__global__ void repack_ws_kernel(const float* __restrict__ Ws, const float* __restrict__ Wn,
                                 float* __restrict__ WsP, float* __restrict__ WnP) {
  int idx = blockIdx.x * 256 + threadIdx.x;
  const int total = 3 * 4 * 128 * 128;
  if (idx >= total) return;
  int e = idx & 127, d = (idx >> 7) & 127, h = (idx >> 14) & 3, L = idx >> 16;
  size_t dst = ((size_t)L * 128 + d) * 512 + h * 128 + e;
  WsP[dst] = Ws[idx];
  WnP[dst] = Wn[idx];
}

// ---------------- KNN: keys in registers, 8 wave-min extraction rounds ---------
template<int T>
__global__ __launch_bounds__(64) void knn_sel_kernel(const float* __restrict__ cent,
                                                     int* __restrict__ knn_idx, int Ni) {
  int i = blockIdx.x, b = blockIdx.y, lane = threadIdx.x;
  const float2* cb = (const float2*)(cent + (size_t)b * Ni * 2);
  float2 ci = cb[i];
  u64 keys[T];
#pragma unroll
  for (int t = 0; t < T; ++t) {
    int j = (t << 6) + lane;
    float2 cj = cb[j];
    float dx = __fsub_rn(ci.x, cj.x);
    float dy = __fsub_rn(ci.y, cj.y);
    float d2 = __fadd_rn(__fmul_rn(dx, dx), __fmul_rn(dy, dy));
    keys[t] = ((u64)__float_as_uint(d2) << 32) | (u32)j;
  }
  u64 prev = 0;
  for (int r = 0; r < KNN_K; ++r) {
    u64 best = ~0ULL;
    if (r == 0) {
#pragma unroll
      for (int t = 0; t < T; ++t) { if (keys[t] < best) best = keys[t]; }
    } else {
#pragma unroll
      for (int t = 0; t < T; ++t) { if (keys[t] > prev && keys[t] < best) best = keys[t]; }
    }
    for (int off = 32; off >= 1; off >>= 1) {
      u64 o = __shfl_xor(best, off, 64);
      if (o < best) best = o;
    }
    if (lane == 0) knn_idx[((size_t)(b * Ni + i)) * KNN_K + r] = (int)(best & 0xffffffffULL);
    prev = best;
  }
}

// ---------------- adjacency bitmask: A = mask | mask^T -------------------------
__global__ void build_adj_kernel(const int* __restrict__ knn_idx, u32* __restrict__ adj, int Ni) {
  int e = blockIdx.x * blockDim.x + threadIdx.x;
  int total = Bn * Ni * KNN_K;
  if (e >= total) return;
  int b = e / (Ni * KNN_K);
  int rem = e % (Ni * KNN_K);
  int r = rem / KNN_K;
  int j = knn_idx[e];
  atomicOr(&adj[((size_t)(b * Nmax + r)) * 64 + (j >> 5)], 1u << (j & 31));
  atomicOr(&adj[((size_t)(b * Nmax + j)) * 64 + (r >> 5)], 1u << (r & 31));
}

// ---------------- layernorm: one wave per row, shuffle butterfly ---------------
__global__ __launch_bounds__(256) void layernorm_kernel(const float* __restrict__ x,
                                                        const float* __restrict__ g,
                                                        const float* __restrict__ be,
                                                        float* __restrict__ xn) {
  int row = blockIdx.x * 4 + (threadIdx.x >> 6);
  int lane = threadIdx.x & 63;
  const float* xr = x + (size_t)row * 128;
  float v1 = xr[lane], v2 = xr[lane + 64];
  float s = v1 + v2;
  for (int off = 32; off >= 1; off >>= 1) s += __shfl_xor(s, off, 64);
  float mean = s / 128.0f;
  float d1 = v1 - mean, d2 = v2 - mean;
  float q = d1 * d1 + d2 * d2;
  for (int off = 32; off >= 1; off >>= 1) q += __shfl_xor(q, off, 64);
  float rs = rsqrtf(q / 128.0f + EPSV);
  float* xo = xn + (size_t)row * 128;
  xo[lane] = d1 * rs * g[lane] + be[lane];
  xo[lane + 64] = d2 * rs * g[lane + 64] + be[lane + 64];
}

// ---------------- neighbor-mean aggregation + degree ---------------------------
__global__ void aggregate_kernel(const u32* __restrict__ adj, const float* __restrict__ xn,
                                 float* __restrict__ m, float* __restrict__ dinv, int Ni) {
  int i = blockIdx.x, b = blockIdx.y, t = threadIdx.x;
  __shared__ int cnt;
  extern __shared__ int list[];
  if (t == 0) cnt = 0;
  __syncthreads();
  int wpr = Ni >> 5;
  for (int w = t; w < wpr; w += blockDim.x) {
    u32 bits = adj[((size_t)(b * Nmax + i)) * 64 + w];
    while (bits) {
      int bit = __ffs(bits) - 1;
      bits &= bits - 1;
      int pos = atomicAdd(&cnt, 1);
      list[pos] = (w << 5) + bit;
    }
  }
  __syncthreads();
  int d = cnt;
  float acc = 0.0f;
  for (int k = 0; k < d; ++k) acc += xn[((size_t)b * Ni + list[k]) * 128 + t];
  m[((size_t)b * Ni + i) * 128 + t] = acc / (float)d;
  if (t == 0) dinv[b * Nmax + i] = 1.0f / sqrtf((float)d);
}

// ---------------- fp32 GEMM, TMx128 tile, packed v2f FMA, register prefetch ----
template<int TM>
__global__ __launch_bounds__(256) void gemm_kernel(
    const float* __restrict__ A, const float* __restrict__ W,
    const float* __restrict__ A2, const float* __restrict__ W2,
    const float* __restrict__ scale, const float* __restrict__ bias,
    float* __restrict__ C, int M, int N, int K, int flags) {
  constexpr int RPT = TM / 8;
  __shared__ float As[16][TM + 4];
  __shared__ float Bs[16][132];
  int tid = threadIdx.x;
  int tx = tid & 31;
  int ty = tid >> 5;
  int colBase = blockIdx.x * 128, rowBase = blockIdx.y * TM;
  v2f acc[RPT][2] = {};
  int ktiles = K >> 4;
  int total = (A2 ? 2 : 1) * ktiles;

  int arow = tid >> 2, aq = (tid & 3) * 4;
  int bk = tid >> 5, bc = (tid & 31) * 4;

  float4 pa, pb0, pb1;
  {
    if (TM == 64 || tid < TM * 4)
      pa = *(const float4*)(A + (size_t)(rowBase + arow) * K + aq);
    pb0 = *(const float4*)(W + (size_t)bk * N + colBase + bc);
    pb1 = *(const float4*)(W + (size_t)(bk + 8) * N + colBase + bc);
  }
  for (int t = 0; t < total; ++t) {
    if (TM == 64 || tid < TM * 4) {
      As[aq + 0][arow] = pa.x;
      As[aq + 1][arow] = pa.y;
      As[aq + 2][arow] = pa.z;
      As[aq + 3][arow] = pa.w;
    }
    *(float4*)&Bs[bk][bc] = pb0;
    *(float4*)&Bs[bk + 8][bc] = pb1;
    __syncthreads();
    if (t + 1 < total) {
      int tn = t + 1;
      const float* Ap = (tn >= ktiles) ? A2 : A;
      const float* Wp = (tn >= ktiles) ? W2 : W;
      int k0 = ((tn >= ktiles) ? tn - ktiles : tn) << 4;
      if (TM == 64 || tid < TM * 4)
        pa = *(const float4*)(Ap + (size_t)(rowBase + arow) * K + k0 + aq);
      pb0 = *(const float4*)(Wp + (size_t)(k0 + bk) * N + colBase + bc);
      pb1 = *(const float4*)(Wp + (size_t)(k0 + bk + 8) * N + colBase + bc);
    }
#pragma unroll
    for (int kk = 0; kk < 16; ++kk) {
      float a[RPT];
      v2f bv[2];
      if (RPT == 8) {
        *(float4*)&a[0] = *(const float4*)&As[kk][ty * 8];
        *(float4*)&a[4] = *(const float4*)&As[kk][ty * 8 + 4];
      } else {
        *(float4*)&a[0] = *(const float4*)&As[kk][ty * 4];
      }
      *(float4*)&bv[0] = *(const float4*)&Bs[kk][tx * 4];
#pragma unroll
      for (int r = 0; r < RPT; ++r)
#pragma unroll
        for (int c = 0; c < 2; ++c) acc[r][c] += a[r] * bv[c];
    }
    __syncthreads();
  }
#pragma unroll
  for (int r = 0; r < RPT; ++r) {
    int row = rowBase + ty * RPT + r;
    int col = colBase + tx * 4;
    float av[4];
    *(v2f*)&av[0] = acc[r][0];
    *(v2f*)&av[2] = acc[r][1];
    float4 v;
    float* vp = (float*)&v;
#pragma unroll
    for (int c = 0; c < 4; ++c) {
      float t = av[c];
      if (scale) t *= scale[col + c];
      if (bias) t += bias[col + c];
      if (flags & GF_RELU) t = fmaxf(t, 0.0f);
      vp[c] = t;
    }
    size_t o = (size_t)row * N + col;
    if (flags & GF_ACCUM) {
      float4 old = *(float4*)&C[o];
      v.x += old.x; v.y += old.y; v.z += old.z; v.w += old.w;
    }
    *(float4*)&C[o] = v;
  }
}

// ---------------- fp32 GEMM, 128x128 tile, 8x8/thread, packed v2f FMA ----------
// Conflict-free LDS (stride-4 lane patterns), 64 FMA per 4 b128 reads.
__global__ __launch_bounds__(256) void gemm128_kernel(
    const float* __restrict__ A, const float* __restrict__ W,
    const float* __restrict__ A2, const float* __restrict__ W2,
    const float* __restrict__ bias, float* __restrict__ C,
    int M, int N, int K, int flags) {
  __shared__ float As[16][132];
  __shared__ float Bs[16][132];
  int tid = threadIdx.x;
  int tx = tid & 15;
  int ty = tid >> 4;
  int colBase = blockIdx.x * 128, rowBase = blockIdx.y * 128;
  v2f acc[8][4] = {};
  int ktiles = K >> 4;
  int total = (A2 ? 2 : 1) * ktiles;

  int arow = tid >> 1, aq = (tid & 1) * 8;
  int bk = tid >> 4, bq4 = (tid & 15) * 4;

  float4 pa0, pa1, pb0, pb1;
  {
    const float* ap = A + (size_t)(rowBase + arow) * K + aq;
    pa0 = *(const float4*)ap;
    pa1 = *(const float4*)(ap + 4);
    const float* bp = W + (size_t)bk * N + colBase;
    pb0 = *(const float4*)(bp + bq4);
    pb1 = *(const float4*)(bp + 64 + bq4);
  }
  for (int t = 0; t < total; ++t) {
    As[aq + 0][arow] = pa0.x; As[aq + 1][arow] = pa0.y;
    As[aq + 2][arow] = pa0.z; As[aq + 3][arow] = pa0.w;
    As[aq + 4][arow] = pa1.x; As[aq + 5][arow] = pa1.y;
    As[aq + 6][arow] = pa1.z; As[aq + 7][arow] = pa1.w;
    *(float4*)&Bs[bk][bq4] = pb0;
    *(float4*)&Bs[bk][64 + bq4] = pb1;
    __syncthreads();
    if (t + 1 < total) {
      int tn = t + 1;
      const float* Ap = (tn >= ktiles) ? A2 : A;
      const float* Wp = (tn >= ktiles) ? W2 : W;
      int k0 = ((tn >= ktiles) ? tn - ktiles : tn) << 4;
      const float* ap = Ap + (size_t)(rowBase + arow) * K + k0 + aq;
      pa0 = *(const float4*)ap;
      pa1 = *(const float4*)(ap + 4);
      const float* bp = Wp + (size_t)(k0 + bk) * N + colBase;
      pb0 = *(const float4*)(bp + bq4);
      pb1 = *(const float4*)(bp + 64 + bq4);
    }
#pragma unroll
    for (int kk = 0; kk < 16; ++kk) {
      float a[8];
      v2f bv[4];
      *(float4*)&a[0] = *(const float4*)&As[kk][ty * 8];
      *(float4*)&a[4] = *(const float4*)&As[kk][ty * 8 + 4];
      *(float4*)&bv[0] = *(const float4*)&Bs[kk][tx * 4];
      *(float4*)&bv[2] = *(const float4*)&Bs[kk][64 + tx * 4];
#pragma unroll
      for (int r = 0; r < 8; ++r)
#pragma unroll
        for (int c = 0; c < 4; ++c) acc[r][c] += a[r] * bv[c];
    }
    __syncthreads();
  }
#pragma unroll
  for (int r = 0; r < 8; ++r) {
    int row = rowBase + ty * 8 + r;
#pragma unroll
    for (int h = 0; h < 2; ++h) {
      int col = colBase + h * 64 + tx * 4;
      float av[4];
      *(v2f*)&av[0] = acc[r][h * 2 + 0];
      *(v2f*)&av[2] = acc[r][h * 2 + 1];
      float4 v;
      float* vp = (float*)&v;
#pragma unroll
      for (int c = 0; c < 4; ++c) {
        float t = av[c];
        if (bias) t += bias[col + c];
        if (flags & GF_RELU) t = fmaxf(t, 0.0f);
        vp[c] = t;
      }
      size_t o = (size_t)row * N + col;
      if (flags & GF_ACCUM) {
        float4 old = *(float4*)&C[o];
        v.x += old.x; v.y += old.y; v.z += old.z; v.w += old.w;
      }
      *(float4*)&C[o] = v;
    }
  }
}

// ---------------- split-K fp32 GEMM, 128x128 tile over K-slice of 128 ----------
// N must be 128. grid=(ksplit, M/128); slice s covers k in [s*128,(s+1)*128).
// Writes raw partials to Cp + s*M*128. Same 1 B/MAC LDS pattern as gemm128.
__global__ __launch_bounds__(256) void gemm128sk_kernel(
    const float* __restrict__ A, const float* __restrict__ W,
    float* __restrict__ Cp, int M, int K) {
  __shared__ float As[16][132];
  __shared__ float Bs[16][132];
  int tid = threadIdx.x;
  int tx = tid & 15;
  int ty = tid >> 4;
  int rowBase = blockIdx.y * 128;
  int kbase = blockIdx.x * 128;
  v2f acc[8][4] = {};

  int arow = tid >> 1, aq = (tid & 1) * 8;
  int bk = tid >> 4, bq4 = (tid & 15) * 4;

  float4 pa0, pa1, pb0, pb1;
  {
    const float* ap = A + (size_t)(rowBase + arow) * K + kbase + aq;
    pa0 = *(const float4*)ap;
    pa1 = *(const float4*)(ap + 4);
    const float* bp = W + (size_t)(kbase + bk) * 128;
    pb0 = *(const float4*)(bp + bq4);
    pb1 = *(const float4*)(bp + 64 + bq4);
  }
  for (int t = 0; t < 8; ++t) {
    As[aq + 0][arow] = pa0.x; As[aq + 1][arow] = pa0.y;
    As[aq + 2][arow] = pa0.z; As[aq + 3][arow] = pa0.w;
    As[aq + 4][arow] = pa1.x; As[aq + 5][arow] = pa1.y;
    As[aq + 6][arow] = pa1.z; As[aq + 7][arow] = pa1.w;
    *(float4*)&Bs[bk][bq4] = pb0;
    *(float4*)&Bs[bk][64 + bq4] = pb1;
    __syncthreads();
    if (t + 1 < 8) {
      int k0 = kbase + ((t + 1) << 4);
      const float* ap = A + (size_t)(rowBase + arow) * K + k0 + aq;
      pa0 = *(const float4*)ap;
      pa1 = *(const float4*)(ap + 4);
      const float* bp = W + (size_t)(k0 + bk) * 128;
      pb0 = *(const float4*)(bp + bq4);
      pb1 = *(const float4*)(bp + 64 + bq4);
    }
#pragma unroll
    for (int kk = 0; kk < 16; ++kk) {
      float a[8];
      v2f bv[4];
      *(float4*)&a[0] = *(const float4*)&As[kk][ty * 8];
      *(float4*)&a[4] = *(const float4*)&As[kk][ty * 8 + 4];
      *(float4*)&bv[0] = *(const float4*)&Bs[kk][tx * 4];
      *(float4*)&bv[2] = *(const float4*)&Bs[kk][64 + tx * 4];
#pragma unroll
      for (int r = 0; r < 8; ++r)
#pragma unroll
        for (int c = 0; c < 4; ++c) acc[r][c] += a[r] * bv[c];
    }
    __syncthreads();
  }
  float* dst = Cp + (size_t)blockIdx.x * M * 128;
#pragma unroll
  for (int r = 0; r < 8; ++r) {
    int row = rowBase + ty * 8 + r;
#pragma unroll
    for (int h = 0; h < 2; ++h) {
      int col = h * 64 + tx * 4;
      float4 v;
      *(v2f*)&v.x = acc[r][h * 2 + 0];
      *(v2f*)&v.z = acc[r][h * 2 + 1];
      *(float4*)&dst[(size_t)row * 128 + col] = v;
    }
  }
}

// ---------------- combine 4 split-K partials: C = f(sum + scale/bias) ----------
__global__ void combine4_kernel(const float* __restrict__ P,
                                const float* __restrict__ scale,
                                const float* __restrict__ bias,
                                float* __restrict__ C, size_t total, int flags) {
  size_t i = ((size_t)blockIdx.x * 256 + threadIdx.x) * 4;
  if (i >= total) return;
  float4 a = *(const float4*)&P[i];
  float4 b = *(const float4*)&P[total + i];
  float4 c = *(const float4*)&P[2 * total + i];
  float4 d = *(const float4*)&P[3 * total + i];
  int col = (int)(i & 127);
  float v[4] = {((a.x + b.x) + c.x) + d.x, ((a.y + b.y) + c.y) + d.y,
                ((a.z + b.z) + c.z) + d.z, ((a.w + b.w) + c.w) + d.w};
  float4 o;
  float* op = (float*)&o;
#pragma unroll
  for (int q = 0; q < 4; ++q) {
    float t = v[q];
    if (scale) t *= scale[col + q];
    if (bias) t += bias[col + q];
    if (flags & GF_RELU) t = fmaxf(t, 0.0f);
    op[q] = t;
  }
  if (flags & GF_ACCUM) {
    float4 old = *(float4*)&C[i];
    o.x += old.x; o.y += old.y; o.z += old.z; o.w += old.w;
  }
  *(float4*)&C[i] = o;
}

// ---------------- fused FFN: x += relu(xn2@W1 + b1) @ W2 + b2 ------------------
__global__ __launch_bounds__(256) void ffn_fused_kernel(
    const float* __restrict__ xn, const float* __restrict__ W1,
    const float* __restrict__ b1, const float* __restrict__ W2,
    const float* __restrict__ b2, float* __restrict__ x) {
  __shared__ float Axn[128 * 36];
  __shared__ float Hs [128 * 36];
  __shared__ float Bs [16 * 132];
  int tid = threadIdx.x;
  int rowBase = blockIdx.x * 32;
  int tx = tid & 31, ty = tid >> 5;
  {
    int row = tid >> 3, ks = (tid & 7) * 16;
    const float* s1 = xn + (size_t)(rowBase + row) * 128 + ks;
#pragma unroll
    for (int q = 0; q < 4; ++q) {
      float4 v = *(const float4*)(s1 + q * 4);
      int k = ks + q * 4;
      Axn[(k + 0) * 36 + row] = v.x; Axn[(k + 1) * 36 + row] = v.y;
      Axn[(k + 2) * 36 + row] = v.z; Axn[(k + 3) * 36 + row] = v.w;
    }
  }
  int bk = tid >> 4, bc = (tid & 15) * 8;
  v2f hacc[4][2] = {};
  {
    float4 p0 = *(const float4*)(W1 + (size_t)bk * 128 + bc);
    float4 p1 = *(const float4*)(W1 + (size_t)bk * 128 + bc + 4);
    for (int kt = 0; kt < 8; ++kt) {
      __syncthreads();
      *(float4*)&Bs[bk * 132 + bc] = p0;
      *(float4*)&Bs[bk * 132 + bc + 4] = p1;
      __syncthreads();
      if (kt < 7) {
        p0 = *(const float4*)(W1 + (size_t)(kt * 16 + 16 + bk) * 128 + bc);
        p1 = *(const float4*)(W1 + (size_t)(kt * 16 + 16 + bk) * 128 + bc + 4);
      }
      int k0 = kt * 16;
#pragma unroll
      for (int kk = 0; kk < 16; ++kk) {
        float av[4];
        v2f bv[2];
        *(float4*)av = *(const float4*)&Axn[(k0 + kk) * 36 + ty * 4];
        *(float4*)&bv[0] = *(const float4*)&Bs[kk * 132 + tx * 4];
#pragma unroll
        for (int r = 0; r < 4; ++r)
#pragma unroll
          for (int c = 0; c < 2; ++c) hacc[r][c] += av[r] * bv[c];
      }
    }
  }
  __syncthreads();
#pragma unroll
  for (int r = 0; r < 4; ++r) {
    float hv[4];
    *(v2f*)&hv[0] = hacc[r][0];
    *(v2f*)&hv[2] = hacc[r][1];
#pragma unroll
    for (int c = 0; c < 4; ++c) {
      float v = hv[c] + b1[tx * 4 + c];
      v = fmaxf(v, 0.0f);
      Hs[(tx * 4 + c) * 36 + ty * 4 + r] = v;
    }
  }
  v2f oacc[4][2] = {};
  {
    float4 q0 = *(const float4*)(W2 + (size_t)bk * 128 + bc);
    float4 q1 = *(const float4*)(W2 + (size_t)bk * 128 + bc + 4);
    for (int kt = 0; kt < 8; ++kt) {
      __syncthreads();
      *(float4*)&Bs[bk * 132 + bc] = q0;
      *(float4*)&Bs[bk * 132 + bc + 4] = q1;
      __syncthreads();
      if (kt < 7) {
        q0 = *(const float4*)(W2 + (size_t)(kt * 16 + 16 + bk) * 128 + bc);
        q1 = *(const float4*)(W2 + (size_t)(kt * 16 + 16 + bk) * 128 + bc + 4);
      }
      int k0 = kt * 16;
#pragma unroll
      for (int kk = 0; kk < 16; ++kk) {
        float av[4];
        v2f bv[2];
        *(float4*)av = *(const float4*)&Hs[(k0 + kk) * 36 + ty * 4];
        *(float4*)&bv[0] = *(const float4*)&Bs[kk * 132 + tx * 4];
#pragma unroll
        for (int r = 0; r < 4; ++r)
#pragma unroll
          for (int c = 0; c < 2; ++c) oacc[r][c] += av[r] * bv[c];
      }
    }
  }
#pragma unroll
  for (int r = 0; r < 4; ++r) {
    int row = rowBase + ty * 4 + r;
    float ov[4];
    *(v2f*)&ov[0] = oacc[r][0];
    *(v2f*)&ov[2] = oacc[r][1];
    float4 old = *(float4*)&x[(size_t)row * 128 + tx * 4];
    float4 v;
    v.x = ov[0] + b2[tx * 4 + 0]; v.x += old.x;
    v.y = ov[1] + b2[tx * 4 + 1]; v.y += old.y;
    v.z = ov[2] + b2[tx * 4 + 2]; v.z += old.z;
    v.w = ov[3] + b2[tx * 4 + 3]; v.w += old.w;
    *(float4*)&x[(size_t)row * 128 + tx * 4] = v;
  }
}

// ---------------- q = x@Wq ; p = dinv*q ---------------------------------------
__global__ void qp_kernel(const float* __restrict__ x, const float* __restrict__ Wq,
                          const float* __restrict__ dinv, float* __restrict__ p, int Ni) {
  int node = blockIdx.x;
  int lane = threadIdx.x;
  int b = node / Ni, i = node % Ni;
  float v = x[(size_t)node * 128 + lane] * Wq[lane] +
            x[(size_t)node * 128 + 64 + lane] * Wq[64 + lane];
  for (int off = 32; off >= 1; off >>= 1) v += __shfl_xor(v, off, 64);
  if (lane == 0) p[b * Nmax + i] = dinv[b * Nmax + i] * v;
}

// ---------------- s = dinv * (A @ p) + bq -------------------------------------
__global__ void score_kernel(const u32* __restrict__ adj, const float* __restrict__ p,
                             const float* __restrict__ dinv, const float* __restrict__ bq,
                             float* __restrict__ s, int Ni) {
  int i = blockIdx.x, b = blockIdx.y, lane = threadIdx.x;
  int wpr = Ni >> 5;
  float acc = 0.0f;
  if (lane < wpr) {
    u32 bits = adj[((size_t)(b * Nmax + i)) * 64 + lane];
    while (bits) {
      int bit = __ffs(bits) - 1;
      bits &= bits - 1;
      acc += p[b * Nmax + (lane << 5) + bit];
    }
  }
  for (int off = 32; off >= 1; off >>= 1) acc += __shfl_xor(acc, off, 64);
  if (lane == 0) s[b * Nmax + i] = dinv[b * Nmax + i] * acc + bq[0];
}

// ---------------- top-k via exact rank counting --------------------------------
__global__ void topk_rank_kernel(const float* __restrict__ s, int Ni, int* __restrict__ topi) {
  int b = blockIdx.y;
  int e0 = blockIdx.x * 256;
  int t = threadIdx.x;
  __shared__ u64 keys[2048];
  for (int e = t; e < Ni; e += 256) {
    u32 u = __float_as_uint(s[b * Nmax + e]);
    u32 mono = (u & 0x80000000u) ? ~u : (u | 0x80000000u);
    keys[e] = ((u64)(~mono) << 32) | (u32)e;
  }
  __syncthreads();
  int e = e0 + t;
  if (e >= Ni) return;
  u64 my = keys[e];
  int rank = 0;
  for (int q = 0; q < Ni; ++q) rank += (keys[q] < my) ? 1 : 0;
  int kkeep = Ni >> 1;
  if (rank < kkeep) topi[b * 1024 + rank] = e;
}

// ---------------- gather + tanh gate ------------------------------------------
__global__ void gather_kernel(const float* __restrict__ x, const float* __restrict__ c,
                              const float* __restrict__ s, const int* __restrict__ topi,
                              float* __restrict__ xo, float* __restrict__ co, int Ni) {
  int inew = blockIdx.x, b = blockIdx.y, t = threadIdx.x;
  int kkeep = Ni >> 1;
  int old = topi[b * 1024 + inew];
  float gate = tanhf(s[b * Nmax + old]);
  xo[((size_t)b * kkeep + inew) * 128 + t] = x[((size_t)b * Ni + old) * 128 + t] * gate;
  if (t < 2) co[((size_t)b * kkeep + inew) * 2 + t] = c[((size_t)b * Ni + old) * 2 + t];
}

// ---------------- picks: two-stage [max ; mean] reduction ----------------------
__global__ void picks_partial_kernel(const float* __restrict__ x, float* __restrict__ part,
                                     int kkeep, int G) {
  int b = blockIdx.x, g = blockIdx.y, t = threadIdx.x;
  int per = kkeep / G;
  int start = g * per;
  float mx = -INFINITY, sm = 0.0f;
  for (int i = start; i < start + per; ++i) {
    float v = x[((size_t)b * kkeep + i) * 128 + t];
    mx = fmaxf(mx, v);
    sm += v;
  }
  part[((size_t)(b * G + g)) * 256 + t] = mx;
  part[((size_t)(b * G + g)) * 256 + 128 + t] = sm;
}

__global__ void picks_combine_kernel(const float* __restrict__ part, float* __restrict__ picks,
                                     int kkeep, int G) {
  int b = blockIdx.x, t = threadIdx.x;
  float mx = -INFINITY, sm = 0.0f;
  for (int g = 0; g < G; ++g) {
    mx = fmaxf(mx, part[((size_t)(b * G + g)) * 256 + t]);
    sm += part[((size_t)(b * G + g)) * 256 + 128 + t];
  }
  picks[b * 256 + t] += mx;
  picks[b * 256 + 128 + t] += sm / (float)kkeep;
}

// ---------------- final 2-layer MLP -------------------------------------------
__global__ void final_kernel(const float* __restrict__ picks, const float* __restrict__ Wf1,
                             const float* __restrict__ bf1, const float* __restrict__ Wf2,
                             const float* __restrict__ bf2, float* __restrict__ out) {
  int b = blockIdx.x, t = threadIdx.x;
  __shared__ float pk[256];
  __shared__ float fm[128];
  pk[t] = picks[b * 256 + t];
  pk[t + 128] = picks[b * 256 + 128 + t];
  __syncthreads();
  float acc = bf1[t];
  for (int k = 0; k < 256; ++k) acc += pk[k] * Wf1[k * 128 + t];
  fm[t] = fmaxf(acc, 0.0f);
  __syncthreads();
  if (t < 32) {
    float a2 = bf2[t];
    for (int k = 0; k < 128; ++k) a2 += fm[k] * Wf2[k * 32 + t];
    out[b * 32 + t] = fmaxf(a2, 0.0f);
  }
}

extern "C" void kernel_launch(void* const* d_in, const int* in_sizes, int n_in,
                              void* d_out, int out_size, void* d_ws, size_t ws_size,
                              hipStream_t stream) {
  const float* feats = (const float*)d_in[0];
  const float* cent  = (const float*)d_in[1];
  const float* Wp1 = (const float*)d_in[2];
  const float* bp1 = (const float*)d_in[3];
  const float* bn_g = (const float*)d_in[4];
  const float* bn_b = (const float*)d_in[5];
  const float* Wp2 = (const float*)d_in[6];
  const float* bp2 = (const float*)d_in[7];
  const float* g1  = (const float*)d_in[8];
  const float* be1 = (const float*)d_in[9];
  const float* g2  = (const float*)d_in[10];
  const float* be2 = (const float*)d_in[11];
  const float* Ws  = (const float*)d_in[12];
  const float* Wn  = (const float*)d_in[13];
  const float* bs  = (const float*)d_in[14];
  const float* Wg  = (const float*)d_in[15];
  const float* bg  = (const float*)d_in[16];
  const float* W1  = (const float*)d_in[17];
  const float* b1  = (const float*)d_in[18];
  const float* W2  = (const float*)d_in[19];
  const float* b2  = (const float*)d_in[20];
  const float* Wq  = (const float*)d_in[21];
  const float* bq  = (const float*)d_in[22];
  const float* Wf1 = (const float*)d_in[23];
  const float* bf1 = (const float*)d_in[24];
  const float* Wf2 = (const float*)d_in[25];
  const float* bf2 = (const float*)d_in[26];
  float* out = (float*)d_out;

  float* p = (float*)d_ws;
  const size_t SZX = (size_t)Bn * Nmax * 128;
  float* SC = p;    p += 128;
  float* BBv = p;   p += 128;
  float* DINV = p;  p += Bn * Nmax;
  float* PV = p;    p += Bn * Nmax;
  float* SS = p;    p += Bn * Nmax;
  float* PICKS = p; p += Bn * 256;
  float* PART = p;  p += (size_t)Bn * 32 * 256;
  float* C0 = p;    p += (size_t)Bn * Nmax * 2;
  float* C1 = p;    p += (size_t)Bn * Nmax * 2;
  int* KNN = (int*)p;  p += (size_t)Bn * Nmax * KNN_K;
  int* TOPI = (int*)p; p += Bn * 1024;
  u32* ADJ = (u32*)p;  p += (size_t)Bn * Nmax * 64;
  float* X0 = p;    p += SZX;
  float* X1 = p;    p += SZX;
  float* BA = p;    p += SZX;
  float* BB = p;    p += SZX;
  float* HB = p;    // fused: 4*SZX for h (M x 512); also preconv1 sk-partials
  size_t base_floats = (size_t)(p - (float*)d_ws);
  const size_t WPSZ = (size_t)3 * 128 * 512;
  bool fused = ws_size >= (base_floats + 4 * SZX + 2 * WPSZ) * sizeof(float);
  float* WSP = HB + 4 * SZX;
  float* WNP = WSP + WPSZ;
  float* PK = WNP + WPSZ;  // Wg sk-partials: 4*SZX
  bool fused2 = ws_size >= (base_floats + 8 * SZX + 2 * WPSZ) * sizeof(float);

  hipLaunchKernelGGL(precompute_kernel, dim3(1), dim3(256), 0, stream,
                     bn_g, bn_b, bp1, SC, BBv, PICKS);
  if (fused) {
    hipLaunchKernelGGL(repack_ws_kernel, dim3(768), dim3(256), 0, stream, Ws, Wn, WSP, WNP);
  }

  // ---- preconv ----
  const int M0 = Bn * Nmax;
  if (fused) {
    // split-K: partials into HB (free here), combine applies BN scale/bias + relu
    hipLaunchKernelGGL(gemm128sk_kernel, dim3(4, M0 / 128), dim3(256), 0, stream,
                       feats, Wp1, HB, M0, 512);
    hipLaunchKernelGGL(combine4_kernel, dim3((int)((size_t)M0 * 128 / 1024)), dim3(256), 0, stream,
                       HB, SC, BBv, BA, (size_t)M0 * 128, GF_RELU);
  } else {
    hipLaunchKernelGGL(gemm_kernel<32>, dim3(1, M0 / 32), dim3(256), 0, stream,
                       feats, Wp1, (const float*)nullptr, (const float*)nullptr,
                       SC, BBv, BA, M0, 128, 512, GF_RELU);
  }
  hipLaunchKernelGGL(gemm_kernel<32>, dim3(1, M0 / 32), dim3(256), 0, stream,
                     BA, Wp2, (const float*)nullptr, (const float*)nullptr,
                     (const float*)nullptr, bp2, X0, M0, 128, 128, 0);

  float* xc = X0;
  float* xo = X1;
  const float* cc = cent;
  float* co = C0;
  int Ni = Nmax;
  for (int L = 0; L < 3; ++L) {
    int M = Bn * Ni;
    if (Ni == 2048)      hipLaunchKernelGGL(knn_sel_kernel<32>, dim3(Ni, Bn), dim3(64), 0, stream, cc, KNN, Ni);
    else if (Ni == 1024) hipLaunchKernelGGL(knn_sel_kernel<16>, dim3(Ni, Bn), dim3(64), 0, stream, cc, KNN, Ni);
    else                 hipLaunchKernelGGL(knn_sel_kernel<8>,  dim3(Ni, Bn), dim3(64), 0, stream, cc, KNN, Ni);
    hipMemsetAsync(ADJ, 0, (size_t)Bn * Nmax * 64 * sizeof(u32), stream);
    int tot = Bn * Ni * KNN_K;
    hipLaunchKernelGGL(build_adj_kernel, dim3((tot + 255) / 256), dim3(256), 0, stream,
                       KNN, ADJ, Ni);
    hipLaunchKernelGGL(layernorm_kernel, dim3(M / 4), dim3(256), 0, stream,
                       xc, g1 + L * 128, be1 + L * 128, BA);
    hipLaunchKernelGGL(aggregate_kernel, dim3(Ni, Bn), dim3(128), Ni * sizeof(int), stream,
                       ADJ, BA, BB, DINV, Ni);
    if (fused) {
      hipLaunchKernelGGL(gemm128_kernel, dim3(4, M / 128), dim3(256), 0, stream,
                         BA, WSP + (size_t)L * 128 * 512,
                         BB, WNP + (size_t)L * 128 * 512,
                         bs + L * 512, HB, M, 512, 128, GF_RELU);
      if (fused2) {
        hipLaunchKernelGGL(gemm128sk_kernel, dim3(4, M / 128), dim3(256), 0, stream,
                           HB, Wg + (size_t)L * 512 * 128, PK, M, 512);
        hipLaunchKernelGGL(combine4_kernel, dim3((int)((size_t)M * 128 / 1024)), dim3(256), 0, stream,
                           PK, (const float*)nullptr, bg + L * 128, xc, (size_t)M * 128, GF_ACCUM);
      } else {
        hipLaunchKernelGGL(gemm_kernel<32>, dim3(1, M / 32), dim3(256), 0, stream,
                           HB, Wg + (size_t)L * 512 * 128,
                           (const float*)nullptr, (const float*)nullptr,
                           (const float*)nullptr, bg + L * 128,
                           xc, M, 128, 512, GF_ACCUM);
      }
    } else {
      for (int hh = 0; hh < 4; ++hh) {
        hipLaunchKernelGGL(gemm_kernel<32>, dim3(1, M / 32), dim3(256), 0, stream,
                           BA, Ws + ((size_t)(L * 4 + hh)) * 128 * 128,
                           BB, Wn + ((size_t)(L * 4 + hh)) * 128 * 128,
                           (const float*)nullptr, bs + (L * 4 + hh) * 128,
                           HB, M, 128, 128, GF_RELU);
        hipLaunchKernelGGL(gemm_kernel<32>, dim3(1, M / 32), dim3(256), 0, stream,
                           HB, Wg + ((size_t)L * 512 + hh * 128) * 128,
                           (const float*)nullptr, (const float*)nullptr,
                           (const float*)nullptr, (hh == 0) ? (bg + L * 128) : (const float*)nullptr,
                           xc, M, 128, 128, GF_ACCUM);
      }
    }
    hipLaunchKernelGGL(layernorm_kernel, dim3(M / 4), dim3(256), 0, stream,
                       xc, g2 + L * 128, be2 + L * 128, BA);
    hipLaunchKernelGGL(ffn_fused_kernel, dim3(M / 32), dim3(256), 0, stream,
                       BA, W1 + (size_t)L * 128 * 128, b1 + L * 128,
                       W2 + (size_t)L * 128 * 128, b2 + L * 128, xc);
    hipLaunchKernelGGL(qp_kernel, dim3(M), dim3(64), 0, stream, xc, Wq + L * 128, DINV, PV, Ni);
    hipLaunchKernelGGL(score_kernel, dim3(Ni, Bn), dim3(64), 0, stream, ADJ, PV, DINV, bq + L, SS, Ni);
    hipLaunchKernelGGL(topk_rank_kernel, dim3((Ni + 255) / 256, Bn), dim3(256), 0, stream,
                       SS, Ni, TOPI);
    int kkeep = Ni >> 1;
    hipLaunchKernelGGL(gather_kernel, dim3(kkeep, Bn), dim3(128), 0, stream,
                       xc, cc, SS, TOPI, xo, co, Ni);
    int G = kkeep / 32;
    hipLaunchKernelGGL(picks_partial_kernel, dim3(Bn, G), dim3(128), 0, stream,
                       xo, PART, kkeep, G);
    hipLaunchKernelGGL(picks_combine_kernel, dim3(Bn), dim3(128), 0, stream,
                       PART, PICKS, kkeep, G);
    float* tmp = xc; xc = xo; xo = tmp;
    cc = co;
    co = (co == C0) ? C1 : C0;
    Ni = kkeep;
  }
  hipLaunchKernelGGL(final_kernel, dim3(Bn), dim3(128), 0, stream,
                     PICKS, Wf1, bf1, Wf2, bf2, out);
}

// Round 11
// 745.436 us; speedup vs baseline: 1.0108x; 1.0108x over previous
//
#include <hip/hip_runtime.h>
#include <math.h>

#define EPSV 1e-5f
#define GF_RELU 1
#define GF_ACCUM 2

typedef unsigned long long u64;
typedef unsigned int u32;
typedef float v2f __attribute__((ext_vector_type(2)));

static const int Bn = 8;
static const int Nmax = 2048;
static const int KNN_K = 8;

// ---------------- precompute: fold BN into scale/bias, zero picks ----------------
__global__ void precompute_kernel(const float* __restrict__ bn_g, const float* __restrict__ bn_b,
                                  const float* __restrict__ bp1,
                                  float* __restrict__ sc, float* __restrict__ bb,
                                  float* __restrict__ picks) {
  int t = threadIdx.x;
  if (t < 128) {
    float s = bn_g[t] / sqrtf(1.0f + EPSV);
    sc[t] = s;
    bb[t] = bp1[t] * s + bn_b[t];
  }
  for (int i = t; i < Bn * 256; i += blockDim.x) picks[i] = 0.0f;
}

// ---------------- repack Ws/Wn [L][h][d][e] -> [L][d][h*128+e] -----------------
__global__ void repack_ws_kernel(const float* __restrict__ Ws, const float* __restrict__ Wn,
                                 float* __restrict__ WsP, float* __restrict__ WnP) {
  int idx = blockIdx.x * 256 + threadIdx.x;
  const int total = 3 * 4 * 128 * 128;
  if (idx >= total) return;
  int e = idx & 127, d = (idx >> 7) & 127, h = (idx >> 14) & 3, L = idx >> 16;
  size_t dst = ((size_t)L * 128 + d) * 512 + h * 128 + e;
  WsP[dst] = Ws[idx];
  WnP[dst] = Wn[idx];
}

// ---------------- KNN: keys in registers, 8 wave-min extraction rounds ---------
template<int T>
__global__ __launch_bounds__(64) void knn_sel_kernel(const float* __restrict__ cent,
                                                     int* __restrict__ knn_idx, int Ni) {
  int i = blockIdx.x, b = blockIdx.y, lane = threadIdx.x;
  const float2* cb = (const float2*)(cent + (size_t)b * Ni * 2);
  float2 ci = cb[i];
  u64 keys[T];
#pragma unroll
  for (int t = 0; t < T; ++t) {
    int j = (t << 6) + lane;
    float2 cj = cb[j];
    float dx = __fsub_rn(ci.x, cj.x);
    float dy = __fsub_rn(ci.y, cj.y);
    float d2 = __fadd_rn(__fmul_rn(dx, dx), __fmul_rn(dy, dy));
    keys[t] = ((u64)__float_as_uint(d2) << 32) | (u32)j;
  }
  u64 prev = 0;
  for (int r = 0; r < KNN_K; ++r) {
    u64 best = ~0ULL;
    if (r == 0) {
#pragma unroll
      for (int t = 0; t < T; ++t) { if (keys[t] < best) best = keys[t]; }
    } else {
#pragma unroll
      for (int t = 0; t < T; ++t) { if (keys[t] > prev && keys[t] < best) best = keys[t]; }
    }
    for (int off = 32; off >= 1; off >>= 1) {
      u64 o = __shfl_xor(best, off, 64);
      if (o < best) best = o;
    }
    if (lane == 0) knn_idx[((size_t)(b * Ni + i)) * KNN_K + r] = (int)(best & 0xffffffffULL);
    prev = best;
  }
}

// ---------------- adjacency bitmask: A = mask | mask^T -------------------------
__global__ void build_adj_kernel(const int* __restrict__ knn_idx, u32* __restrict__ adj, int Ni) {
  int e = blockIdx.x * blockDim.x + threadIdx.x;
  int total = Bn * Ni * KNN_K;
  if (e >= total) return;
  int b = e / (Ni * KNN_K);
  int rem = e % (Ni * KNN_K);
  int r = rem / KNN_K;
  int j = knn_idx[e];
  atomicOr(&adj[((size_t)(b * Nmax + r)) * 64 + (j >> 5)], 1u << (j & 31));
  atomicOr(&adj[((size_t)(b * Nmax + j)) * 64 + (r >> 5)], 1u << (r & 31));
}

// ---------------- layernorm: one wave per row, shuffle butterfly ---------------
__global__ __launch_bounds__(256) void layernorm_kernel(const float* __restrict__ x,
                                                        const float* __restrict__ g,
                                                        const float* __restrict__ be,
                                                        float* __restrict__ xn) {
  int row = blockIdx.x * 4 + (threadIdx.x >> 6);
  int lane = threadIdx.x & 63;
  const float* xr = x + (size_t)row * 128;
  float v1 = xr[lane], v2 = xr[lane + 64];
  float s = v1 + v2;
  for (int off = 32; off >= 1; off >>= 1) s += __shfl_xor(s, off, 64);
  float mean = s / 128.0f;
  float d1 = v1 - mean, d2 = v2 - mean;
  float q = d1 * d1 + d2 * d2;
  for (int off = 32; off >= 1; off >>= 1) q += __shfl_xor(q, off, 64);
  float rs = rsqrtf(q / 128.0f + EPSV);
  float* xo = xn + (size_t)row * 128;
  xo[lane] = d1 * rs * g[lane] + be[lane];
  xo[lane + 64] = d2 * rs * g[lane + 64] + be[lane + 64];
}

// ---------------- neighbor-mean aggregation + degree ---------------------------
__global__ void aggregate_kernel(const u32* __restrict__ adj, const float* __restrict__ xn,
                                 float* __restrict__ m, float* __restrict__ dinv, int Ni) {
  int i = blockIdx.x, b = blockIdx.y, t = threadIdx.x;
  __shared__ int cnt;
  extern __shared__ int list[];
  if (t == 0) cnt = 0;
  __syncthreads();
  int wpr = Ni >> 5;
  for (int w = t; w < wpr; w += blockDim.x) {
    u32 bits = adj[((size_t)(b * Nmax + i)) * 64 + w];
    while (bits) {
      int bit = __ffs(bits) - 1;
      bits &= bits - 1;
      int pos = atomicAdd(&cnt, 1);
      list[pos] = (w << 5) + bit;
    }
  }
  __syncthreads();
  int d = cnt;
  float acc = 0.0f;
  for (int k = 0; k < d; ++k) acc += xn[((size_t)b * Ni + list[k]) * 128 + t];
  m[((size_t)b * Ni + i) * 128 + t] = acc / (float)d;
  if (t == 0) dinv[b * Nmax + i] = 1.0f / sqrtf((float)d);
}

// ---------------- fp32 GEMM, TMx128 tile, packed v2f FMA, register prefetch ----
template<int TM>
__global__ __launch_bounds__(256) void gemm_kernel(
    const float* __restrict__ A, const float* __restrict__ W,
    const float* __restrict__ A2, const float* __restrict__ W2,
    const float* __restrict__ scale, const float* __restrict__ bias,
    float* __restrict__ C, int M, int N, int K, int flags) {
  constexpr int RPT = TM / 8;
  __shared__ float As[16][TM + 4];
  __shared__ float Bs[16][132];
  int tid = threadIdx.x;
  int tx = tid & 31;
  int ty = tid >> 5;
  int colBase = blockIdx.x * 128, rowBase = blockIdx.y * TM;
  v2f acc[RPT][2] = {};
  int ktiles = K >> 4;
  int total = (A2 ? 2 : 1) * ktiles;

  int arow = tid >> 2, aq = (tid & 3) * 4;
  int bk = tid >> 5, bc = (tid & 31) * 4;

  float4 pa, pb0, pb1;
  {
    if (TM == 64 || tid < TM * 4)
      pa = *(const float4*)(A + (size_t)(rowBase + arow) * K + aq);
    pb0 = *(const float4*)(W + (size_t)bk * N + colBase + bc);
    pb1 = *(const float4*)(W + (size_t)(bk + 8) * N + colBase + bc);
  }
  for (int t = 0; t < total; ++t) {
    if (TM == 64 || tid < TM * 4) {
      As[aq + 0][arow] = pa.x;
      As[aq + 1][arow] = pa.y;
      As[aq + 2][arow] = pa.z;
      As[aq + 3][arow] = pa.w;
    }
    *(float4*)&Bs[bk][bc] = pb0;
    *(float4*)&Bs[bk + 8][bc] = pb1;
    __syncthreads();
    if (t + 1 < total) {
      int tn = t + 1;
      const float* Ap = (tn >= ktiles) ? A2 : A;
      const float* Wp = (tn >= ktiles) ? W2 : W;
      int k0 = ((tn >= ktiles) ? tn - ktiles : tn) << 4;
      if (TM == 64 || tid < TM * 4)
        pa = *(const float4*)(Ap + (size_t)(rowBase + arow) * K + k0 + aq);
      pb0 = *(const float4*)(Wp + (size_t)(k0 + bk) * N + colBase + bc);
      pb1 = *(const float4*)(Wp + (size_t)(k0 + bk + 8) * N + colBase + bc);
    }
#pragma unroll
    for (int kk = 0; kk < 16; ++kk) {
      float a[RPT];
      v2f bv[2];
      if (RPT == 8) {
        *(float4*)&a[0] = *(const float4*)&As[kk][ty * 8];
        *(float4*)&a[4] = *(const float4*)&As[kk][ty * 8 + 4];
      } else {
        *(float4*)&a[0] = *(const float4*)&As[kk][ty * 4];
      }
      *(float4*)&bv[0] = *(const float4*)&Bs[kk][tx * 4];
#pragma unroll
      for (int r = 0; r < RPT; ++r)
#pragma unroll
        for (int c = 0; c < 2; ++c) acc[r][c] += a[r] * bv[c];
    }
    __syncthreads();
  }
#pragma unroll
  for (int r = 0; r < RPT; ++r) {
    int row = rowBase + ty * RPT + r;
    int col = colBase + tx * 4;
    float av[4];
    *(v2f*)&av[0] = acc[r][0];
    *(v2f*)&av[2] = acc[r][1];
    float4 v;
    float* vp = (float*)&v;
#pragma unroll
    for (int c = 0; c < 4; ++c) {
      float t = av[c];
      if (scale) t *= scale[col + c];
      if (bias) t += bias[col + c];
      if (flags & GF_RELU) t = fmaxf(t, 0.0f);
      vp[c] = t;
    }
    size_t o = (size_t)row * N + col;
    if (flags & GF_ACCUM) {
      float4 old = *(float4*)&C[o];
      v.x += old.x; v.y += old.y; v.z += old.z; v.w += old.w;
    }
    *(float4*)&C[o] = v;
  }
}

// ---------------- dual-operand 128x128-tile GEMM, raw partials -----------------
// z=0: C0 = A0 @ W0 ; z=1: C1 = A1 @ W1. K=128 (8 k-tiles). N arbitrary mult 128.
// Same conflict-free LDS pattern as gemm128; doubles blocks/CU vs dual-pass.
__global__ __launch_bounds__(256) void gemm128dual_kernel(
    const float* __restrict__ A0, const float* __restrict__ W0,
    const float* __restrict__ A1, const float* __restrict__ W1,
    float* __restrict__ C0p, float* __restrict__ C1p, int M, int N) {
  const float* A = blockIdx.z ? A1 : A0;
  const float* W = blockIdx.z ? W1 : W0;
  float* C = blockIdx.z ? C1p : C0p;
  __shared__ float As[16][132];
  __shared__ float Bs[16][132];
  int tid = threadIdx.x;
  int tx = tid & 15;
  int ty = tid >> 4;
  int colBase = blockIdx.x * 128, rowBase = blockIdx.y * 128;
  v2f acc[8][4] = {};

  int arow = tid >> 1, aq = (tid & 1) * 8;
  int bk = tid >> 4, bq4 = (tid & 15) * 4;

  float4 pa0, pa1, pb0, pb1;
  {
    const float* ap = A + (size_t)(rowBase + arow) * 128 + aq;
    pa0 = *(const float4*)ap;
    pa1 = *(const float4*)(ap + 4);
    const float* bp = W + (size_t)bk * N + colBase;
    pb0 = *(const float4*)(bp + bq4);
    pb1 = *(const float4*)(bp + 64 + bq4);
  }
  for (int t = 0; t < 8; ++t) {
    As[aq + 0][arow] = pa0.x; As[aq + 1][arow] = pa0.y;
    As[aq + 2][arow] = pa0.z; As[aq + 3][arow] = pa0.w;
    As[aq + 4][arow] = pa1.x; As[aq + 5][arow] = pa1.y;
    As[aq + 6][arow] = pa1.z; As[aq + 7][arow] = pa1.w;
    *(float4*)&Bs[bk][bq4] = pb0;
    *(float4*)&Bs[bk][64 + bq4] = pb1;
    __syncthreads();
    if (t + 1 < 8) {
      int k0 = (t + 1) << 4;
      const float* ap = A + (size_t)(rowBase + arow) * 128 + k0 + aq;
      pa0 = *(const float4*)ap;
      pa1 = *(const float4*)(ap + 4);
      const float* bp = W + (size_t)(k0 + bk) * N + colBase;
      pb0 = *(const float4*)(bp + bq4);
      pb1 = *(const float4*)(bp + 64 + bq4);
    }
#pragma unroll
    for (int kk = 0; kk < 16; ++kk) {
      float a[8];
      v2f bv[4];
      *(float4*)&a[0] = *(const float4*)&As[kk][ty * 8];
      *(float4*)&a[4] = *(const float4*)&As[kk][ty * 8 + 4];
      *(float4*)&bv[0] = *(const float4*)&Bs[kk][tx * 4];
      *(float4*)&bv[2] = *(const float4*)&Bs[kk][64 + tx * 4];
#pragma unroll
      for (int r = 0; r < 8; ++r)
#pragma unroll
        for (int c = 0; c < 4; ++c) acc[r][c] += a[r] * bv[c];
    }
    __syncthreads();
  }
#pragma unroll
  for (int r = 0; r < 8; ++r) {
    int row = rowBase + ty * 8 + r;
#pragma unroll
    for (int h = 0; h < 2; ++h) {
      int col = colBase + h * 64 + tx * 4;
      float4 v;
      *(v2f*)&v.x = acc[r][h * 2 + 0];
      *(v2f*)&v.z = acc[r][h * 2 + 1];
      *(float4*)&C[(size_t)row * N + col] = v;
    }
  }
}

// ---------------- Wg GEMM with fused h-combine on A-load -----------------------
// A element (row,k) = relu(P0[row*512+k] + P1[row*512+k] + hbias[k]); K=512.
// C (N=128) = A @ W + bias, accumulated into C. 32x128 tile, register prefetch.
__global__ __launch_bounds__(256) void gemm_hsum_kernel(
    const float* __restrict__ P0, const float* __restrict__ P1,
    const float* __restrict__ hbias, const float* __restrict__ W,
    const float* __restrict__ bias, float* __restrict__ C, int M) {
  __shared__ float As[16][36];
  __shared__ float Bs[16][132];
  int tid = threadIdx.x;
  int tx = tid & 31;
  int ty = tid >> 5;
  int rowBase = blockIdx.y * 32;
  v2f acc[4][2] = {};

  int arow = tid >> 3, aq = (tid & 7) * 4 & 15;   // 32 rows x (16/4) quads? ->
  // A stage: 32 rows x 16 k per tile; 128 threads stage (tid<128), 1 float4 each
  arow = tid >> 2; aq = (tid & 3) * 4;
  int bk = tid >> 5, bc = (tid & 31) * 4;

  float4 pq0, pq1, pb0, pb1, hb;
  {
    if (tid < 128) {
      size_t o = (size_t)(rowBase + arow) * 512 + aq;
      pq0 = *(const float4*)(P0 + o);
      pq1 = *(const float4*)(P1 + o);
      hb = *(const float4*)(hbias + aq);
    }
    pb0 = *(const float4*)(W + (size_t)bk * 128 + bc);
    pb1 = *(const float4*)(W + (size_t)(bk + 8) * 128 + bc);
  }
  for (int t = 0; t < 32; ++t) {
    if (tid < 128) {
      As[aq + 0][arow] = fmaxf(pq0.x + pq1.x + hb.x, 0.0f);
      As[aq + 1][arow] = fmaxf(pq0.y + pq1.y + hb.y, 0.0f);
      As[aq + 2][arow] = fmaxf(pq0.z + pq1.z + hb.z, 0.0f);
      As[aq + 3][arow] = fmaxf(pq0.w + pq1.w + hb.w, 0.0f);
    }
    *(float4*)&Bs[bk][bc] = pb0;
    *(float4*)&Bs[bk + 8][bc] = pb1;
    __syncthreads();
    if (t + 1 < 32) {
      int k0 = (t + 1) << 4;
      if (tid < 128) {
        size_t o = (size_t)(rowBase + arow) * 512 + k0 + aq;
        pq0 = *(const float4*)(P0 + o);
        pq1 = *(const float4*)(P1 + o);
        hb = *(const float4*)(hbias + k0 + aq);
      }
      pb0 = *(const float4*)(W + (size_t)(k0 + bk) * 128 + bc);
      pb1 = *(const float4*)(W + (size_t)(k0 + bk + 8) * 128 + bc);
    }
#pragma unroll
    for (int kk = 0; kk < 16; ++kk) {
      float a[4];
      v2f bv[2];
      *(float4*)&a[0] = *(const float4*)&As[kk][ty * 4];
      *(float4*)&bv[0] = *(const float4*)&Bs[kk][tx * 4];
#pragma unroll
      for (int r = 0; r < 4; ++r)
#pragma unroll
        for (int c = 0; c < 2; ++c) acc[r][c] += a[r] * bv[c];
    }
    __syncthreads();
  }
#pragma unroll
  for (int r = 0; r < 4; ++r) {
    int row = rowBase + ty * 4 + r;
    int col = tx * 4;
    float av[4];
    *(v2f*)&av[0] = acc[r][0];
    *(v2f*)&av[2] = acc[r][1];
    size_t o = (size_t)row * 128 + col;
    float4 old = *(float4*)&C[o];
    float4 v;
    v.x = av[0] + bias[col + 0] + old.x;
    v.y = av[1] + bias[col + 1] + old.y;
    v.z = av[2] + bias[col + 2] + old.z;
    v.w = av[3] + bias[col + 3] + old.w;
    *(float4*)&C[o] = v;
  }
}

// ---------------- fp32 GEMM, 128x128 tile, 8x8/thread, packed v2f FMA ----------
__global__ __launch_bounds__(256) void gemm128_kernel(
    const float* __restrict__ A, const float* __restrict__ W,
    const float* __restrict__ A2, const float* __restrict__ W2,
    const float* __restrict__ bias, float* __restrict__ C,
    int M, int N, int K, int flags) {
  __shared__ float As[16][132];
  __shared__ float Bs[16][132];
  int tid = threadIdx.x;
  int tx = tid & 15;
  int ty = tid >> 4;
  int colBase = blockIdx.x * 128, rowBase = blockIdx.y * 128;
  v2f acc[8][4] = {};
  int ktiles = K >> 4;
  int total = (A2 ? 2 : 1) * ktiles;

  int arow = tid >> 1, aq = (tid & 1) * 8;
  int bk = tid >> 4, bq4 = (tid & 15) * 4;

  float4 pa0, pa1, pb0, pb1;
  {
    const float* ap = A + (size_t)(rowBase + arow) * K + aq;
    pa0 = *(const float4*)ap;
    pa1 = *(const float4*)(ap + 4);
    const float* bp = W + (size_t)bk * N + colBase;
    pb0 = *(const float4*)(bp + bq4);
    pb1 = *(const float4*)(bp + 64 + bq4);
  }
  for (int t = 0; t < total; ++t) {
    As[aq + 0][arow] = pa0.x; As[aq + 1][arow] = pa0.y;
    As[aq + 2][arow] = pa0.z; As[aq + 3][arow] = pa0.w;
    As[aq + 4][arow] = pa1.x; As[aq + 5][arow] = pa1.y;
    As[aq + 6][arow] = pa1.z; As[aq + 7][arow] = pa1.w;
    *(float4*)&Bs[bk][bq4] = pb0;
    *(float4*)&Bs[bk][64 + bq4] = pb1;
    __syncthreads();
    if (t + 1 < total) {
      int tn = t + 1;
      const float* Ap = (tn >= ktiles) ? A2 : A;
      const float* Wp = (tn >= ktiles) ? W2 : W;
      int k0 = ((tn >= ktiles) ? tn - ktiles : tn) << 4;
      const float* ap = Ap + (size_t)(rowBase + arow) * K + k0 + aq;
      pa0 = *(const float4*)ap;
      pa1 = *(const float4*)(ap + 4);
      const float* bp = Wp + (size_t)(k0 + bk) * N + colBase;
      pb0 = *(const float4*)(bp + bq4);
      pb1 = *(const float4*)(bp + 64 + bq4);
    }
#pragma unroll
    for (int kk = 0; kk < 16; ++kk) {
      float a[8];
      v2f bv[4];
      *(float4*)&a[0] = *(const float4*)&As[kk][ty * 8];
      *(float4*)&a[4] = *(const float4*)&As[kk][ty * 8 + 4];
      *(float4*)&bv[0] = *(const float4*)&Bs[kk][tx * 4];
      *(float4*)&bv[2] = *(const float4*)&Bs[kk][64 + tx * 4];
#pragma unroll
      for (int r = 0; r < 8; ++r)
#pragma unroll
        for (int c = 0; c < 4; ++c) acc[r][c] += a[r] * bv[c];
    }
    __syncthreads();
  }
#pragma unroll
  for (int r = 0; r < 8; ++r) {
    int row = rowBase + ty * 8 + r;
#pragma unroll
    for (int h = 0; h < 2; ++h) {
      int col = colBase + h * 64 + tx * 4;
      float av[4];
      *(v2f*)&av[0] = acc[r][h * 2 + 0];
      *(v2f*)&av[2] = acc[r][h * 2 + 1];
      float4 v;
      float* vp = (float*)&v;
#pragma unroll
      for (int c = 0; c < 4; ++c) {
        float t = av[c];
        if (bias) t += bias[col + c];
        if (flags & GF_RELU) t = fmaxf(t, 0.0f);
        vp[c] = t;
      }
      size_t o = (size_t)row * N + col;
      if (flags & GF_ACCUM) {
        float4 old = *(float4*)&C[o];
        v.x += old.x; v.y += old.y; v.z += old.z; v.w += old.w;
      }
      *(float4*)&C[o] = v;
    }
  }
}

// ---------------- fused FFN: x += relu(xn2@W1 + b1) @ W2 + b2 ------------------
__global__ __launch_bounds__(256) void ffn_fused_kernel(
    const float* __restrict__ xn, const float* __restrict__ W1,
    const float* __restrict__ b1, const float* __restrict__ W2,
    const float* __restrict__ b2, float* __restrict__ x) {
  __shared__ float Axn[128 * 36];
  __shared__ float Hs [128 * 36];
  __shared__ float Bs [16 * 132];
  int tid = threadIdx.x;
  int rowBase = blockIdx.x * 32;
  int tx = tid & 31, ty = tid >> 5;
  {
    int row = tid >> 3, ks = (tid & 7) * 16;
    const float* s1 = xn + (size_t)(rowBase + row) * 128 + ks;
#pragma unroll
    for (int q = 0; q < 4; ++q) {
      float4 v = *(const float4*)(s1 + q * 4);
      int k = ks + q * 4;
      Axn[(k + 0) * 36 + row] = v.x; Axn[(k + 1) * 36 + row] = v.y;
      Axn[(k + 2) * 36 + row] = v.z; Axn[(k + 3) * 36 + row] = v.w;
    }
  }
  int bk = tid >> 4, bc = (tid & 15) * 8;
  v2f hacc[4][2] = {};
  {
    float4 p0 = *(const float4*)(W1 + (size_t)bk * 128 + bc);
    float4 p1 = *(const float4*)(W1 + (size_t)bk * 128 + bc + 4);
    for (int kt = 0; kt < 8; ++kt) {
      __syncthreads();
      *(float4*)&Bs[bk * 132 + bc] = p0;
      *(float4*)&Bs[bk * 132 + bc + 4] = p1;
      __syncthreads();
      if (kt < 7) {
        p0 = *(const float4*)(W1 + (size_t)(kt * 16 + 16 + bk) * 128 + bc);
        p1 = *(const float4*)(W1 + (size_t)(kt * 16 + 16 + bk) * 128 + bc + 4);
      }
      int k0 = kt * 16;
#pragma unroll
      for (int kk = 0; kk < 16; ++kk) {
        float av[4];
        v2f bv[2];
        *(float4*)av = *(const float4*)&Axn[(k0 + kk) * 36 + ty * 4];
        *(float4*)&bv[0] = *(const float4*)&Bs[kk * 132 + tx * 4];
#pragma unroll
        for (int r = 0; r < 4; ++r)
#pragma unroll
          for (int c = 0; c < 2; ++c) hacc[r][c] += av[r] * bv[c];
      }
    }
  }
  __syncthreads();
#pragma unroll
  for (int r = 0; r < 4; ++r) {
    float hv[4];
    *(v2f*)&hv[0] = hacc[r][0];
    *(v2f*)&hv[2] = hacc[r][1];
#pragma unroll
    for (int c = 0; c < 4; ++c) {
      float v = hv[c] + b1[tx * 4 + c];
      v = fmaxf(v, 0.0f);
      Hs[(tx * 4 + c) * 36 + ty * 4 + r] = v;
    }
  }
  v2f oacc[4][2] = {};
  {
    float4 q0 = *(const float4*)(W2 + (size_t)bk * 128 + bc);
    float4 q1 = *(const float4*)(W2 + (size_t)bk * 128 + bc + 4);
    for (int kt = 0; kt < 8; ++kt) {
      __syncthreads();
      *(float4*)&Bs[bk * 132 + bc] = q0;
      *(float4*)&Bs[bk * 132 + bc + 4] = q1;
      __syncthreads();
      if (kt < 7) {
        q0 = *(const float4*)(W2 + (size_t)(kt * 16 + 16 + bk) * 128 + bc);
        q1 = *(const float4*)(W2 + (size_t)(kt * 16 + 16 + bk) * 128 + bc + 4);
      }
      int k0 = kt * 16;
#pragma unroll
      for (int kk = 0; kk < 16; ++kk) {
        float av[4];
        v2f bv[2];
        *(float4*)av = *(const float4*)&Hs[(k0 + kk) * 36 + ty * 4];
        *(float4*)&bv[0] = *(const float4*)&Bs[kk * 132 + tx * 4];
#pragma unroll
        for (int r = 0; r < 4; ++r)
#pragma unroll
          for (int c = 0; c < 2; ++c) oacc[r][c] += av[r] * bv[c];
      }
    }
  }
#pragma unroll
  for (int r = 0; r < 4; ++r) {
    int row = rowBase + ty * 4 + r;
    float ov[4];
    *(v2f*)&ov[0] = oacc[r][0];
    *(v2f*)&ov[2] = oacc[r][1];
    float4 old = *(float4*)&x[(size_t)row * 128 + tx * 4];
    float4 v;
    v.x = ov[0] + b2[tx * 4 + 0]; v.x += old.x;
    v.y = ov[1] + b2[tx * 4 + 1]; v.y += old.y;
    v.z = ov[2] + b2[tx * 4 + 2]; v.z += old.z;
    v.w = ov[3] + b2[tx * 4 + 3]; v.w += old.w;
    *(float4*)&x[(size_t)row * 128 + tx * 4] = v;
  }
}

// ---------------- q = x@Wq ; p = dinv*q ---------------------------------------
__global__ void qp_kernel(const float* __restrict__ x, const float* __restrict__ Wq,
                          const float* __restrict__ dinv, float* __restrict__ p, int Ni) {
  int node = blockIdx.x;
  int lane = threadIdx.x;
  int b = node / Ni, i = node % Ni;
  float v = x[(size_t)node * 128 + lane] * Wq[lane] +
            x[(size_t)node * 128 + 64 + lane] * Wq[64 + lane];
  for (int off = 32; off >= 1; off >>= 1) v += __shfl_xor(v, off, 64);
  if (lane == 0) p[b * Nmax + i] = dinv[b * Nmax + i] * v;
}

// ---------------- s = dinv * (A @ p) + bq -------------------------------------
__global__ void score_kernel(const u32* __restrict__ adj, const float* __restrict__ p,
                             const float* __restrict__ dinv, const float* __restrict__ bq,
                             float* __restrict__ s, int Ni) {
  int i = blockIdx.x, b = blockIdx.y, lane = threadIdx.x;
  int wpr = Ni >> 5;
  float acc = 0.0f;
  if (lane < wpr) {
    u32 bits = adj[((size_t)(b * Nmax + i)) * 64 + lane];
    while (bits) {
      int bit = __ffs(bits) - 1;
      bits &= bits - 1;
      acc += p[b * Nmax + (lane << 5) + bit];
    }
  }
  for (int off = 32; off >= 1; off >>= 1) acc += __shfl_xor(acc, off, 64);
  if (lane == 0) s[b * Nmax + i] = dinv[b * Nmax + i] * acc + bq[0];
}

// ---------------- top-k via exact rank counting --------------------------------
__global__ void topk_rank_kernel(const float* __restrict__ s, int Ni, int* __restrict__ topi) {
  int b = blockIdx.y;
  int e0 = blockIdx.x * 256;
  int t = threadIdx.x;
  __shared__ u64 keys[2048];
  for (int e = t; e < Ni; e += 256) {
    u32 u = __float_as_uint(s[b * Nmax + e]);
    u32 mono = (u & 0x80000000u) ? ~u : (u | 0x80000000u);
    keys[e] = ((u64)(~mono) << 32) | (u32)e;
  }
  __syncthreads();
  int e = e0 + t;
  if (e >= Ni) return;
  u64 my = keys[e];
  int rank = 0;
  for (int q = 0; q < Ni; ++q) rank += (keys[q] < my) ? 1 : 0;
  int kkeep = Ni >> 1;
  if (rank < kkeep) topi[b * 1024 + rank] = e;
}

// ---------------- gather + tanh gate ------------------------------------------
__global__ void gather_kernel(const float* __restrict__ x, const float* __restrict__ c,
                              const float* __restrict__ s, const int* __restrict__ topi,
                              float* __restrict__ xo, float* __restrict__ co, int Ni) {
  int inew = blockIdx.x, b = blockIdx.y, t = threadIdx.x;
  int kkeep = Ni >> 1;
  int old = topi[b * 1024 + inew];
  float gate = tanhf(s[b * Nmax + old]);
  xo[((size_t)b * kkeep + inew) * 128 + t] = x[((size_t)b * Ni + old) * 128 + t] * gate;
  if (t < 2) co[((size_t)b * kkeep + inew) * 2 + t] = c[((size_t)b * Ni + old) * 2 + t];
}

// ---------------- picks: two-stage [max ; mean] reduction ----------------------
__global__ void picks_partial_kernel(const float* __restrict__ x, float* __restrict__ part,
                                     int kkeep, int G) {
  int b = blockIdx.x, g = blockIdx.y, t = threadIdx.x;
  int per = kkeep / G;
  int start = g * per;
  float mx = -INFINITY, sm = 0.0f;
  for (int i = start; i < start + per; ++i) {
    float v = x[((size_t)b * kkeep + i) * 128 + t];
    mx = fmaxf(mx, v);
    sm += v;
  }
  part[((size_t)(b * G + g)) * 256 + t] = mx;
  part[((size_t)(b * G + g)) * 256 + 128 + t] = sm;
}

__global__ void picks_combine_kernel(const float* __restrict__ part, float* __restrict__ picks,
                                     int kkeep, int G) {
  int b = blockIdx.x, t = threadIdx.x;
  float mx = -INFINITY, sm = 0.0f;
  for (int g = 0; g < G; ++g) {
    mx = fmaxf(mx, part[((size_t)(b * G + g)) * 256 + t]);
    sm += part[((size_t)(b * G + g)) * 256 + 128 + t];
  }
  picks[b * 256 + t] += mx;
  picks[b * 256 + 128 + t] += sm / (float)kkeep;
}

// ---------------- final 2-layer MLP -------------------------------------------
__global__ void final_kernel(const float* __restrict__ picks, const float* __restrict__ Wf1,
                             const float* __restrict__ bf1, const float* __restrict__ Wf2,
                             const float* __restrict__ bf2, float* __restrict__ out) {
  int b = blockIdx.x, t = threadIdx.x;
  __shared__ float pk[256];
  __shared__ float fm[128];
  pk[t] = picks[b * 256 + t];
  pk[t + 128] = picks[b * 256 + 128 + t];
  __syncthreads();
  float acc = bf1[t];
  for (int k = 0; k < 256; ++k) acc += pk[k] * Wf1[k * 128 + t];
  fm[t] = fmaxf(acc, 0.0f);
  __syncthreads();
  if (t < 32) {
    float a2 = bf2[t];
    for (int k = 0; k < 128; ++k) a2 += fm[k] * Wf2[k * 32 + t];
    out[b * 32 + t] = fmaxf(a2, 0.0f);
  }
}

extern "C" void kernel_launch(void* const* d_in, const int* in_sizes, int n_in,
                              void* d_out, int out_size, void* d_ws, size_t ws_size,
                              hipStream_t stream) {
  const float* feats = (const float*)d_in[0];
  const float* cent  = (const float*)d_in[1];
  const float* Wp1 = (const float*)d_in[2];
  const float* bp1 = (const float*)d_in[3];
  const float* bn_g = (const float*)d_in[4];
  const float* bn_b = (const float*)d_in[5];
  const float* Wp2 = (const float*)d_in[6];
  const float* bp2 = (const float*)d_in[7];
  const float* g1  = (const float*)d_in[8];
  const float* be1 = (const float*)d_in[9];
  const float* g2  = (const float*)d_in[10];
  const float* be2 = (const float*)d_in[11];
  const float* Ws  = (const float*)d_in[12];
  const float* Wn  = (const float*)d_in[13];
  const float* bs  = (const float*)d_in[14];
  const float* Wg  = (const float*)d_in[15];
  const float* bg  = (const float*)d_in[16];
  const float* W1  = (const float*)d_in[17];
  const float* b1  = (const float*)d_in[18];
  const float* W2  = (const float*)d_in[19];
  const float* b2  = (const float*)d_in[20];
  const float* Wq  = (const float*)d_in[21];
  const float* bq  = (const float*)d_in[22];
  const float* Wf1 = (const float*)d_in[23];
  const float* bf1 = (const float*)d_in[24];
  const float* Wf2 = (const float*)d_in[25];
  const float* bf2 = (const float*)d_in[26];
  float* out = (float*)d_out;

  float* p = (float*)d_ws;
  const size_t SZX = (size_t)Bn * Nmax * 128;
  float* SC = p;    p += 128;
  float* BBv = p;   p += 128;
  float* DINV = p;  p += Bn * Nmax;
  float* PV = p;    p += Bn * Nmax;
  float* SS = p;    p += Bn * Nmax;
  float* PICKS = p; p += Bn * 256;
  float* PART = p;  p += (size_t)Bn * 32 * 256;
  float* C0 = p;    p += (size_t)Bn * Nmax * 2;
  float* C1 = p;    p += (size_t)Bn * Nmax * 2;
  int* KNN = (int*)p;  p += (size_t)Bn * Nmax * KNN_K;
  int* TOPI = (int*)p; p += Bn * 1024;
  u32* ADJ = (u32*)p;  p += (size_t)Bn * Nmax * 64;
  float* X0 = p;    p += SZX;
  float* X1 = p;    p += SZX;
  float* BA = p;    p += SZX;
  float* BB = p;    p += SZX;
  float* HB = p;    // h partial 0 (or full h): 4*SZX
  size_t base_floats = (size_t)(p - (float*)d_ws);
  const size_t WPSZ = (size_t)3 * 128 * 512;
  bool fused = ws_size >= (base_floats + 4 * SZX + 2 * WPSZ) * sizeof(float);
  float* WSP = HB + 4 * SZX;
  float* WNP = WSP + WPSZ;
  float* PK = WNP + WPSZ;  // h partial 1: 4*SZX
  bool fused2 = ws_size >= (base_floats + 8 * SZX + 2 * WPSZ) * sizeof(float);

  hipLaunchKernelGGL(precompute_kernel, dim3(1), dim3(256), 0, stream,
                     bn_g, bn_b, bp1, SC, BBv, PICKS);
  if (fused) {
    hipLaunchKernelGGL(repack_ws_kernel, dim3(768), dim3(256), 0, stream, Ws, Wn, WSP, WNP);
  }

  // ---- preconv ----
  const int M0 = Bn * Nmax;
  hipLaunchKernelGGL(gemm_kernel<32>, dim3(1, M0 / 32), dim3(256), 0, stream,
                     feats, Wp1, (const float*)nullptr, (const float*)nullptr,
                     SC, BBv, BA, M0, 128, 512, GF_RELU);
  hipLaunchKernelGGL(gemm_kernel<32>, dim3(1, M0 / 32), dim3(256), 0, stream,
                     BA, Wp2, (const float*)nullptr, (const float*)nullptr,
                     (const float*)nullptr, bp2, X0, M0, 128, 128, 0);

  float* xc = X0;
  float* xo = X1;
  const float* cc = cent;
  float* co = C0;
  int Ni = Nmax;
  for (int L = 0; L < 3; ++L) {
    int M = Bn * Ni;
    if (Ni == 2048)      hipLaunchKernelGGL(knn_sel_kernel<32>, dim3(Ni, Bn), dim3(64), 0, stream, cc, KNN, Ni);
    else if (Ni == 1024) hipLaunchKernelGGL(knn_sel_kernel<16>, dim3(Ni, Bn), dim3(64), 0, stream, cc, KNN, Ni);
    else                 hipLaunchKernelGGL(knn_sel_kernel<8>,  dim3(Ni, Bn), dim3(64), 0, stream, cc, KNN, Ni);
    hipMemsetAsync(ADJ, 0, (size_t)Bn * Nmax * 64 * sizeof(u32), stream);
    int tot = Bn * Ni * KNN_K;
    hipLaunchKernelGGL(build_adj_kernel, dim3((tot + 255) / 256), dim3(256), 0, stream,
                       KNN, ADJ, Ni);
    hipLaunchKernelGGL(layernorm_kernel, dim3(M / 4), dim3(256), 0, stream,
                       xc, g1 + L * 128, be1 + L * 128, BA);
    hipLaunchKernelGGL(aggregate_kernel, dim3(Ni, Bn), dim3(128), Ni * sizeof(int), stream,
                       ADJ, BA, BB, DINV, Ni);
    if (fused2) {
      // z-split h partials: HB = xn@Ws, PK = m@Wn; combine fused into Wg A-load
      hipLaunchKernelGGL(gemm128dual_kernel, dim3(4, M / 128, 2), dim3(256), 0, stream,
                         BA, WSP + (size_t)L * 128 * 512,
                         BB, WNP + (size_t)L * 128 * 512,
                         HB, PK, M, 512);
      hipLaunchKernelGGL(gemm_hsum_kernel, dim3(1, M / 32), dim3(256), 0, stream,
                         HB, PK, bs + L * 512, Wg + (size_t)L * 512 * 128,
                         bg + L * 128, xc, M);
    } else if (fused) {
      hipLaunchKernelGGL(gemm128_kernel, dim3(4, M / 128), dim3(256), 0, stream,
                         BA, WSP + (size_t)L * 128 * 512,
                         BB, WNP + (size_t)L * 128 * 512,
                         bs + L * 512, HB, M, 512, 128, GF_RELU);
      hipLaunchKernelGGL(gemm_kernel<32>, dim3(1, M / 32), dim3(256), 0, stream,
                         HB, Wg + (size_t)L * 512 * 128,
                         (const float*)nullptr, (const float*)nullptr,
                         (const float*)nullptr, bg + L * 128,
                         xc, M, 128, 512, GF_ACCUM);
    } else {
      for (int hh = 0; hh < 4; ++hh) {
        hipLaunchKernelGGL(gemm_kernel<32>, dim3(1, M / 32), dim3(256), 0, stream,
                           BA, Ws + ((size_t)(L * 4 + hh)) * 128 * 128,
                           BB, Wn + ((size_t)(L * 4 + hh)) * 128 * 128,
                           (const float*)nullptr, bs + (L * 4 + hh) * 128,
                           HB, M, 128, 128, GF_RELU);
        hipLaunchKernelGGL(gemm_kernel<32>, dim3(1, M / 32), dim3(256), 0, stream,
                           HB, Wg + ((size_t)L * 512 + hh * 128) * 128,
                           (const float*)nullptr, (const float*)nullptr,
                           (const float*)nullptr, (hh == 0) ? (bg + L * 128) : (const float*)nullptr,
                           xc, M, 128, 128, GF_ACCUM);
      }
    }
    hipLaunchKernelGGL(layernorm_kernel, dim3(M / 4), dim3(256), 0, stream,
                       xc, g2 + L * 128, be2 + L * 128, BA);
    hipLaunchKernelGGL(ffn_fused_kernel, dim3(M / 32), dim3(256), 0, stream,
                       BA, W1 + (size_t)L * 128 * 128, b1 + L * 128,
                       W2 + (size_t)L * 128 * 128, b2 + L * 128, xc);
    hipLaunchKernelGGL(qp_kernel, dim3(M), dim3(64), 0, stream, xc, Wq + L * 128, DINV, PV, Ni);
    hipLaunchKernelGGL(score_kernel, dim3(Ni, Bn), dim3(64), 0, stream, ADJ, PV, DINV, bq + L, SS, Ni);
    hipLaunchKernelGGL(topk_rank_kernel, dim3((Ni + 255) / 256, Bn), dim3(256), 0, stream,
                       SS, Ni, TOPI);
    int kkeep = Ni >> 1;
    hipLaunchKernelGGL(gather_kernel, dim3(kkeep, Bn), dim3(128), 0, stream,
                       xc, cc, SS, TOPI, xo, co, Ni);
    int G = kkeep / 32;
    hipLaunchKernelGGL(picks_partial_kernel, dim3(Bn, G), dim3(128), 0, stream,
                       xo, PART, kkeep, G);
    hipLaunchKernelGGL(picks_combine_kernel, dim3(Bn), dim3(128), 0, stream,
                       PART, PICKS, kkeep, G);
    float* tmp = xc; xc = xo; xo = tmp;
    cc = co;
    co = (co == C0) ? C1 : C0;
    Ni = kkeep;
  }
  hipLaunchKernelGGL(final_kernel, dim3(Bn), dim3(128), 0, stream,
                     PICKS, Wf1, bf1, Wf2, bf2, out);
}

// Round 12
// 691.411 us; speedup vs baseline: 1.0897x; 1.0781x over previous
//
#include <hip/hip_runtime.h>
#include <math.h>

#define EPSV 1e-5f
#define GF_RELU 1
#define GF_ACCUM 2

typedef unsigned long long u64;
typedef unsigned int u32;
typedef float v2f __attribute__((ext_vector_type(2)));

static const int Bn = 8;
static const int Nmax = 2048;
static const int KNN_K = 8;

// ---------------- precompute: fold BN into scale/bias, zero picks ----------------
__global__ void precompute_kernel(const float* __restrict__ bn_g, const float* __restrict__ bn_b,
                                  const float* __restrict__ bp1,
                                  float* __restrict__ sc, float* __restrict__ bb,
                                  float* __restrict__ picks) {
  int t = threadIdx.x;
  if (t < 128) {
    float s = bn_g[t] / sqrtf(1.0f + EPSV);
    sc[t] = s;
    bb[t] = bp1[t] * s + bn_b[t];
  }
  for (int i = t; i < Bn * 256; i += blockDim.x) picks[i] = 0.0f;
}

// ---------------- repack Ws/Wn [L][h][d][e] -> [L][d][h*128+e] -----------------
__global__ void repack_ws_kernel(const float* __restrict__ Ws, const float* __restrict__ Wn,
                                 float* __restrict__ WsP, float* __restrict__ WnP) {
  int idx = blockIdx.x * 256 + threadIdx.x;
  const int total = 3 * 4 * 128 * 128;
  if (idx >= total) return;
  int e = idx & 127, d = (idx >> 7) & 127, h = (idx >> 14) & 3, L = idx >> 16;
  size_t dst = ((size_t)L * 128 + d) * 512 + h * 128 + e;
  WsP[dst] = Ws[idx];
  WnP[dst] = Wn[idx];
}

// ---------------- KNN: keys in registers, 8 wave-min extraction rounds ---------
template<int T>
__global__ __launch_bounds__(64) void knn_sel_kernel(const float* __restrict__ cent,
                                                     int* __restrict__ knn_idx, int Ni) {
  int i = blockIdx.x, b = blockIdx.y, lane = threadIdx.x;
  const float2* cb = (const float2*)(cent + (size_t)b * Ni * 2);
  float2 ci = cb[i];
  u64 keys[T];
#pragma unroll
  for (int t = 0; t < T; ++t) {
    int j = (t << 6) + lane;
    float2 cj = cb[j];
    float dx = __fsub_rn(ci.x, cj.x);
    float dy = __fsub_rn(ci.y, cj.y);
    float d2 = __fadd_rn(__fmul_rn(dx, dx), __fmul_rn(dy, dy));
    keys[t] = ((u64)__float_as_uint(d2) << 32) | (u32)j;
  }
  u64 prev = 0;
  for (int r = 0; r < KNN_K; ++r) {
    u64 best = ~0ULL;
    if (r == 0) {
#pragma unroll
      for (int t = 0; t < T; ++t) { if (keys[t] < best) best = keys[t]; }
    } else {
#pragma unroll
      for (int t = 0; t < T; ++t) { if (keys[t] > prev && keys[t] < best) best = keys[t]; }
    }
    for (int off = 32; off >= 1; off >>= 1) {
      u64 o = __shfl_xor(best, off, 64);
      if (o < best) best = o;
    }
    if (lane == 0) knn_idx[((size_t)(b * Ni + i)) * KNN_K + r] = (int)(best & 0xffffffffULL);
    prev = best;
  }
}

// ---------------- adjacency bitmask: A = mask | mask^T -------------------------
__global__ void build_adj_kernel(const int* __restrict__ knn_idx, u32* __restrict__ adj, int Ni) {
  int e = blockIdx.x * blockDim.x + threadIdx.x;
  int total = Bn * Ni * KNN_K;
  if (e >= total) return;
  int b = e / (Ni * KNN_K);
  int rem = e % (Ni * KNN_K);
  int r = rem / KNN_K;
  int j = knn_idx[e];
  atomicOr(&adj[((size_t)(b * Nmax + r)) * 64 + (j >> 5)], 1u << (j & 31));
  atomicOr(&adj[((size_t)(b * Nmax + j)) * 64 + (r >> 5)], 1u << (r & 31));
}

// ---------------- layernorm: one wave per row, shuffle butterfly ---------------
__global__ __launch_bounds__(256) void layernorm_kernel(const float* __restrict__ x,
                                                        const float* __restrict__ g,
                                                        const float* __restrict__ be,
                                                        float* __restrict__ xn) {
  int row = blockIdx.x * 4 + (threadIdx.x >> 6);
  int lane = threadIdx.x & 63;
  const float* xr = x + (size_t)row * 128;
  float v1 = xr[lane], v2 = xr[lane + 64];
  float s = v1 + v2;
  for (int off = 32; off >= 1; off >>= 1) s += __shfl_xor(s, off, 64);
  float mean = s / 128.0f;
  float d1 = v1 - mean, d2 = v2 - mean;
  float q = d1 * d1 + d2 * d2;
  for (int off = 32; off >= 1; off >>= 1) q += __shfl_xor(q, off, 64);
  float rs = rsqrtf(q / 128.0f + EPSV);
  float* xo = xn + (size_t)row * 128;
  xo[lane] = d1 * rs * g[lane] + be[lane];
  xo[lane + 64] = d2 * rs * g[lane + 64] + be[lane + 64];
}

// ---------------- neighbor-mean aggregation + degree ---------------------------
__global__ void aggregate_kernel(const u32* __restrict__ adj, const float* __restrict__ xn,
                                 float* __restrict__ m, float* __restrict__ dinv, int Ni) {
  int i = blockIdx.x, b = blockIdx.y, t = threadIdx.x;
  __shared__ int cnt;
  extern __shared__ int list[];
  if (t == 0) cnt = 0;
  __syncthreads();
  int wpr = Ni >> 5;
  for (int w = t; w < wpr; w += blockDim.x) {
    u32 bits = adj[((size_t)(b * Nmax + i)) * 64 + w];
    while (bits) {
      int bit = __ffs(bits) - 1;
      bits &= bits - 1;
      int pos = atomicAdd(&cnt, 1);
      list[pos] = (w << 5) + bit;
    }
  }
  __syncthreads();
  int d = cnt;
  float acc = 0.0f;
  for (int k = 0; k < d; ++k) acc += xn[((size_t)b * Ni + list[k]) * 128 + t];
  m[((size_t)b * Ni + i) * 128 + t] = acc / (float)d;
  if (t == 0) dinv[b * Nmax + i] = 1.0f / sqrtf((float)d);
}

// ---------------- fp32 GEMM, TMx128 tile, packed v2f FMA, register prefetch ----
template<int TM>
__global__ __launch_bounds__(256) void gemm_kernel(
    const float* __restrict__ A, const float* __restrict__ W,
    const float* __restrict__ A2, const float* __restrict__ W2,
    const float* __restrict__ scale, const float* __restrict__ bias,
    float* __restrict__ C, int M, int N, int K, int flags) {
  constexpr int RPT = TM / 8;
  __shared__ float As[16][TM + 4];
  __shared__ float Bs[16][132];
  int tid = threadIdx.x;
  int tx = tid & 31;
  int ty = tid >> 5;
  int colBase = blockIdx.x * 128, rowBase = blockIdx.y * TM;
  v2f acc[RPT][2] = {};
  int ktiles = K >> 4;
  int total = (A2 ? 2 : 1) * ktiles;

  int arow = tid >> 2, aq = (tid & 3) * 4;
  int bk = tid >> 5, bc = (tid & 31) * 4;

  float4 pa, pb0, pb1;
  {
    if (TM == 64 || tid < TM * 4)
      pa = *(const float4*)(A + (size_t)(rowBase + arow) * K + aq);
    pb0 = *(const float4*)(W + (size_t)bk * N + colBase + bc);
    pb1 = *(const float4*)(W + (size_t)(bk + 8) * N + colBase + bc);
  }
  for (int t = 0; t < total; ++t) {
    if (TM == 64 || tid < TM * 4) {
      As[aq + 0][arow] = pa.x;
      As[aq + 1][arow] = pa.y;
      As[aq + 2][arow] = pa.z;
      As[aq + 3][arow] = pa.w;
    }
    *(float4*)&Bs[bk][bc] = pb0;
    *(float4*)&Bs[bk + 8][bc] = pb1;
    __syncthreads();
    if (t + 1 < total) {
      int tn = t + 1;
      const float* Ap = (tn >= ktiles) ? A2 : A;
      const float* Wp = (tn >= ktiles) ? W2 : W;
      int k0 = ((tn >= ktiles) ? tn - ktiles : tn) << 4;
      if (TM == 64 || tid < TM * 4)
        pa = *(const float4*)(Ap + (size_t)(rowBase + arow) * K + k0 + aq);
      pb0 = *(const float4*)(Wp + (size_t)(k0 + bk) * N + colBase + bc);
      pb1 = *(const float4*)(Wp + (size_t)(k0 + bk + 8) * N + colBase + bc);
    }
#pragma unroll
    for (int kk = 0; kk < 16; ++kk) {
      float a[RPT];
      v2f bv[2];
      if (RPT == 8) {
        *(float4*)&a[0] = *(const float4*)&As[kk][ty * 8];
        *(float4*)&a[4] = *(const float4*)&As[kk][ty * 8 + 4];
      } else {
        *(float4*)&a[0] = *(const float4*)&As[kk][ty * 4];
      }
      *(float4*)&bv[0] = *(const float4*)&Bs[kk][tx * 4];
#pragma unroll
      for (int r = 0; r < RPT; ++r)
#pragma unroll
        for (int c = 0; c < 2; ++c) acc[r][c] += a[r] * bv[c];
    }
    __syncthreads();
  }
#pragma unroll
  for (int r = 0; r < RPT; ++r) {
    int row = rowBase + ty * RPT + r;
    int col = colBase + tx * 4;
    float av[4];
    *(v2f*)&av[0] = acc[r][0];
    *(v2f*)&av[2] = acc[r][1];
    float4 v;
    float* vp = (float*)&v;
#pragma unroll
    for (int c = 0; c < 4; ++c) {
      float t = av[c];
      if (scale) t *= scale[col + c];
      if (bias) t += bias[col + c];
      if (flags & GF_RELU) t = fmaxf(t, 0.0f);
      vp[c] = t;
    }
    size_t o = (size_t)row * N + col;
    if (flags & GF_ACCUM) {
      float4 old = *(float4*)&C[o];
      v.x += old.x; v.y += old.y; v.z += old.z; v.w += old.w;
    }
    *(float4*)&C[o] = v;
  }
}

// ---------------- dual-operand 128x128-tile GEMM, raw partials -----------------
__global__ __launch_bounds__(256) void gemm128dual_kernel(
    const float* __restrict__ A0, const float* __restrict__ W0,
    const float* __restrict__ A1, const float* __restrict__ W1,
    float* __restrict__ C0p, float* __restrict__ C1p, int M, int N) {
  const float* A = blockIdx.z ? A1 : A0;
  const float* W = blockIdx.z ? W1 : W0;
  float* C = blockIdx.z ? C1p : C0p;
  __shared__ float As[16][132];
  __shared__ float Bs[16][132];
  int tid = threadIdx.x;
  int tx = tid & 15;
  int ty = tid >> 4;
  int colBase = blockIdx.x * 128, rowBase = blockIdx.y * 128;
  v2f acc[8][4] = {};

  int arow = tid >> 1, aq = (tid & 1) * 8;
  int bk = tid >> 4, bq4 = (tid & 15) * 4;

  float4 pa0, pa1, pb0, pb1;
  {
    const float* ap = A + (size_t)(rowBase + arow) * 128 + aq;
    pa0 = *(const float4*)ap;
    pa1 = *(const float4*)(ap + 4);
    const float* bp = W + (size_t)bk * N + colBase;
    pb0 = *(const float4*)(bp + bq4);
    pb1 = *(const float4*)(bp + 64 + bq4);
  }
  for (int t = 0; t < 8; ++t) {
    As[aq + 0][arow] = pa0.x; As[aq + 1][arow] = pa0.y;
    As[aq + 2][arow] = pa0.z; As[aq + 3][arow] = pa0.w;
    As[aq + 4][arow] = pa1.x; As[aq + 5][arow] = pa1.y;
    As[aq + 6][arow] = pa1.z; As[aq + 7][arow] = pa1.w;
    *(float4*)&Bs[bk][bq4] = pb0;
    *(float4*)&Bs[bk][64 + bq4] = pb1;
    __syncthreads();
    if (t + 1 < 8) {
      int k0 = (t + 1) << 4;
      const float* ap = A + (size_t)(rowBase + arow) * 128 + k0 + aq;
      pa0 = *(const float4*)ap;
      pa1 = *(const float4*)(ap + 4);
      const float* bp = W + (size_t)(k0 + bk) * N + colBase;
      pb0 = *(const float4*)(bp + bq4);
      pb1 = *(const float4*)(bp + 64 + bq4);
    }
#pragma unroll
    for (int kk = 0; kk < 16; ++kk) {
      float a[8];
      v2f bv[4];
      *(float4*)&a[0] = *(const float4*)&As[kk][ty * 8];
      *(float4*)&a[4] = *(const float4*)&As[kk][ty * 8 + 4];
      *(float4*)&bv[0] = *(const float4*)&Bs[kk][tx * 4];
      *(float4*)&bv[2] = *(const float4*)&Bs[kk][64 + tx * 4];
#pragma unroll
      for (int r = 0; r < 8; ++r)
#pragma unroll
        for (int c = 0; c < 4; ++c) acc[r][c] += a[r] * bv[c];
    }
    __syncthreads();
  }
#pragma unroll
  for (int r = 0; r < 8; ++r) {
    int row = rowBase + ty * 8 + r;
#pragma unroll
    for (int h = 0; h < 2; ++h) {
      int col = colBase + h * 64 + tx * 4;
      float4 v;
      *(v2f*)&v.x = acc[r][h * 2 + 0];
      *(v2f*)&v.z = acc[r][h * 2 + 1];
      *(float4*)&C[(size_t)row * N + col] = v;
    }
  }
}

// ---------------- K-sliced 128x128-tile GEMM, raw partials (N=128) -------------
// blockIdx.z = k-slice (128 wide). P layout: slice z at P + z*M*128.
__global__ __launch_bounds__(256) void gemm128ks_kernel(
    const float* __restrict__ A, const float* __restrict__ W,
    float* __restrict__ P, int M, int K) {
  __shared__ float As[16][132];
  __shared__ float Bs[16][132];
  int tid = threadIdx.x;
  int tx = tid & 15;
  int ty = tid >> 4;
  int rowBase = blockIdx.y * 128;
  int kbase = blockIdx.z * 128;
  v2f acc[8][4] = {};

  int arow = tid >> 1, aq = (tid & 1) * 8;
  int bk = tid >> 4, bq4 = (tid & 15) * 4;

  float4 pa0, pa1, pb0, pb1;
  {
    const float* ap = A + (size_t)(rowBase + arow) * K + kbase + aq;
    pa0 = *(const float4*)ap;
    pa1 = *(const float4*)(ap + 4);
    const float* bp = W + (size_t)(kbase + bk) * 128;
    pb0 = *(const float4*)(bp + bq4);
    pb1 = *(const float4*)(bp + 64 + bq4);
  }
  for (int t = 0; t < 8; ++t) {
    As[aq + 0][arow] = pa0.x; As[aq + 1][arow] = pa0.y;
    As[aq + 2][arow] = pa0.z; As[aq + 3][arow] = pa0.w;
    As[aq + 4][arow] = pa1.x; As[aq + 5][arow] = pa1.y;
    As[aq + 6][arow] = pa1.z; As[aq + 7][arow] = pa1.w;
    *(float4*)&Bs[bk][bq4] = pb0;
    *(float4*)&Bs[bk][64 + bq4] = pb1;
    __syncthreads();
    if (t + 1 < 8) {
      int k0 = kbase + ((t + 1) << 4);
      const float* ap = A + (size_t)(rowBase + arow) * K + k0 + aq;
      pa0 = *(const float4*)ap;
      pa1 = *(const float4*)(ap + 4);
      const float* bp = W + (size_t)(k0 + bk) * 128;
      pb0 = *(const float4*)(bp + bq4);
      pb1 = *(const float4*)(bp + 64 + bq4);
    }
#pragma unroll
    for (int kk = 0; kk < 16; ++kk) {
      float a[8];
      v2f bv[4];
      *(float4*)&a[0] = *(const float4*)&As[kk][ty * 8];
      *(float4*)&a[4] = *(const float4*)&As[kk][ty * 8 + 4];
      *(float4*)&bv[0] = *(const float4*)&Bs[kk][tx * 4];
      *(float4*)&bv[2] = *(const float4*)&Bs[kk][64 + tx * 4];
#pragma unroll
      for (int r = 0; r < 8; ++r)
#pragma unroll
        for (int c = 0; c < 4; ++c) acc[r][c] += a[r] * bv[c];
    }
    __syncthreads();
  }
  float* dst = P + (size_t)blockIdx.z * M * 128;
#pragma unroll
  for (int r = 0; r < 8; ++r) {
    int row = rowBase + ty * 8 + r;
#pragma unroll
    for (int h = 0; h < 2; ++h) {
      int col = h * 64 + tx * 4;
      float4 v;
      *(v2f*)&v.x = acc[r][h * 2 + 0];
      *(v2f*)&v.z = acc[r][h * 2 + 1];
      *(float4*)&dst[(size_t)row * 128 + col] = v;
    }
  }
}

// ---------------- preconv2 with fused 4-partial combine on A-load --------------
// A(row,k) = relu((P0+P1+P2+P3)(row,k) * sc[k] + bb[k]), K=128.
// C = A @ W + bias (plain store). 32x128 tile.
__global__ __launch_bounds__(256) void gemm_psum4_kernel(
    const float* __restrict__ P, const float* __restrict__ sc,
    const float* __restrict__ bb, const float* __restrict__ W,
    const float* __restrict__ bias, float* __restrict__ C, int M) {
  __shared__ float As[16][36];
  __shared__ float Bs[16][132];
  int tid = threadIdx.x;
  int tx = tid & 31;
  int ty = tid >> 5;
  int rowBase = blockIdx.y * 32;
  v2f acc[4][2] = {};
  const size_t PS = (size_t)M * 128;

  int arow = tid >> 2, aq = (tid & 3) * 4;
  int bk = tid >> 5, bc = (tid & 31) * 4;

  float4 p0, p1, p2, p3, s4, b4, pb0, pb1;
  {
    if (tid < 128) {
      size_t o = (size_t)(rowBase + arow) * 128 + aq;
      p0 = *(const float4*)(P + o);
      p1 = *(const float4*)(P + PS + o);
      p2 = *(const float4*)(P + 2 * PS + o);
      p3 = *(const float4*)(P + 3 * PS + o);
      s4 = *(const float4*)(sc + aq);
      b4 = *(const float4*)(bb + aq);
    }
    pb0 = *(const float4*)(W + (size_t)bk * 128 + bc);
    pb1 = *(const float4*)(W + (size_t)(bk + 8) * 128 + bc);
  }
  for (int t = 0; t < 8; ++t) {
    if (tid < 128) {
      As[aq + 0][arow] = fmaxf((((p0.x + p1.x) + p2.x) + p3.x) * s4.x + b4.x, 0.0f);
      As[aq + 1][arow] = fmaxf((((p0.y + p1.y) + p2.y) + p3.y) * s4.y + b4.y, 0.0f);
      As[aq + 2][arow] = fmaxf((((p0.z + p1.z) + p2.z) + p3.z) * s4.z + b4.z, 0.0f);
      As[aq + 3][arow] = fmaxf((((p0.w + p1.w) + p2.w) + p3.w) * s4.w + b4.w, 0.0f);
    }
    *(float4*)&Bs[bk][bc] = pb0;
    *(float4*)&Bs[bk + 8][bc] = pb1;
    __syncthreads();
    if (t + 1 < 8) {
      int k0 = (t + 1) << 4;
      if (tid < 128) {
        size_t o = (size_t)(rowBase + arow) * 128 + k0 + aq;
        p0 = *(const float4*)(P + o);
        p1 = *(const float4*)(P + PS + o);
        p2 = *(const float4*)(P + 2 * PS + o);
        p3 = *(const float4*)(P + 3 * PS + o);
        s4 = *(const float4*)(sc + k0 + aq);
        b4 = *(const float4*)(bb + k0 + aq);
      }
      pb0 = *(const float4*)(W + (size_t)(k0 + bk) * 128 + bc);
      pb1 = *(const float4*)(W + (size_t)(k0 + bk + 8) * 128 + bc);
    }
#pragma unroll
    for (int kk = 0; kk < 16; ++kk) {
      float a[4];
      v2f bv[2];
      *(float4*)&a[0] = *(const float4*)&As[kk][ty * 4];
      *(float4*)&bv[0] = *(const float4*)&Bs[kk][tx * 4];
#pragma unroll
      for (int r = 0; r < 4; ++r)
#pragma unroll
        for (int c = 0; c < 2; ++c) acc[r][c] += a[r] * bv[c];
    }
    __syncthreads();
  }
#pragma unroll
  for (int r = 0; r < 4; ++r) {
    int row = rowBase + ty * 4 + r;
    int col = tx * 4;
    float av[4];
    *(v2f*)&av[0] = acc[r][0];
    *(v2f*)&av[2] = acc[r][1];
    float4 v;
    v.x = av[0] + bias[col + 0];
    v.y = av[1] + bias[col + 1];
    v.z = av[2] + bias[col + 2];
    v.w = av[3] + bias[col + 3];
    *(float4*)&C[(size_t)row * 128 + col] = v;
  }
}

// ---------------- Wg GEMM with fused h-combine on A-load -----------------------
__global__ __launch_bounds__(256) void gemm_hsum_kernel(
    const float* __restrict__ P0, const float* __restrict__ P1,
    const float* __restrict__ hbias, const float* __restrict__ W,
    const float* __restrict__ bias, float* __restrict__ C, int M) {
  __shared__ float As[16][36];
  __shared__ float Bs[16][132];
  int tid = threadIdx.x;
  int tx = tid & 31;
  int ty = tid >> 5;
  int rowBase = blockIdx.y * 32;
  v2f acc[4][2] = {};

  int arow = tid >> 2, aq = (tid & 3) * 4;
  int bk = tid >> 5, bc = (tid & 31) * 4;

  float4 pq0, pq1, pb0, pb1, hb;
  {
    if (tid < 128) {
      size_t o = (size_t)(rowBase + arow) * 512 + aq;
      pq0 = *(const float4*)(P0 + o);
      pq1 = *(const float4*)(P1 + o);
      hb = *(const float4*)(hbias + aq);
    }
    pb0 = *(const float4*)(W + (size_t)bk * 128 + bc);
    pb1 = *(const float4*)(W + (size_t)(bk + 8) * 128 + bc);
  }
  for (int t = 0; t < 32; ++t) {
    if (tid < 128) {
      As[aq + 0][arow] = fmaxf(pq0.x + pq1.x + hb.x, 0.0f);
      As[aq + 1][arow] = fmaxf(pq0.y + pq1.y + hb.y, 0.0f);
      As[aq + 2][arow] = fmaxf(pq0.z + pq1.z + hb.z, 0.0f);
      As[aq + 3][arow] = fmaxf(pq0.w + pq1.w + hb.w, 0.0f);
    }
    *(float4*)&Bs[bk][bc] = pb0;
    *(float4*)&Bs[bk + 8][bc] = pb1;
    __syncthreads();
    if (t + 1 < 32) {
      int k0 = (t + 1) << 4;
      if (tid < 128) {
        size_t o = (size_t)(rowBase + arow) * 512 + k0 + aq;
        pq0 = *(const float4*)(P0 + o);
        pq1 = *(const float4*)(P1 + o);
        hb = *(const float4*)(hbias + k0 + aq);
      }
      pb0 = *(const float4*)(W + (size_t)(k0 + bk) * 128 + bc);
      pb1 = *(const float4*)(W + (size_t)(k0 + bk + 8) * 128 + bc);
    }
#pragma unroll
    for (int kk = 0; kk < 16; ++kk) {
      float a[4];
      v2f bv[2];
      *(float4*)&a[0] = *(const float4*)&As[kk][ty * 4];
      *(float4*)&bv[0] = *(const float4*)&Bs[kk][tx * 4];
#pragma unroll
      for (int r = 0; r < 4; ++r)
#pragma unroll
        for (int c = 0; c < 2; ++c) acc[r][c] += a[r] * bv[c];
    }
    __syncthreads();
  }
#pragma unroll
  for (int r = 0; r < 4; ++r) {
    int row = rowBase + ty * 4 + r;
    int col = tx * 4;
    float av[4];
    *(v2f*)&av[0] = acc[r][0];
    *(v2f*)&av[2] = acc[r][1];
    size_t o = (size_t)row * 128 + col;
    float4 old = *(float4*)&C[o];
    float4 v;
    v.x = av[0] + bias[col + 0] + old.x;
    v.y = av[1] + bias[col + 1] + old.y;
    v.z = av[2] + bias[col + 2] + old.z;
    v.w = av[3] + bias[col + 3] + old.w;
    *(float4*)&C[o] = v;
  }
}

// ---------------- fp32 GEMM, 128x128 tile, 8x8/thread, packed v2f FMA ----------
__global__ __launch_bounds__(256) void gemm128_kernel(
    const float* __restrict__ A, const float* __restrict__ W,
    const float* __restrict__ A2, const float* __restrict__ W2,
    const float* __restrict__ bias, float* __restrict__ C,
    int M, int N, int K, int flags) {
  __shared__ float As[16][132];
  __shared__ float Bs[16][132];
  int tid = threadIdx.x;
  int tx = tid & 15;
  int ty = tid >> 4;
  int colBase = blockIdx.x * 128, rowBase = blockIdx.y * 128;
  v2f acc[8][4] = {};
  int ktiles = K >> 4;
  int total = (A2 ? 2 : 1) * ktiles;

  int arow = tid >> 1, aq = (tid & 1) * 8;
  int bk = tid >> 4, bq4 = (tid & 15) * 4;

  float4 pa0, pa1, pb0, pb1;
  {
    const float* ap = A + (size_t)(rowBase + arow) * K + aq;
    pa0 = *(const float4*)ap;
    pa1 = *(const float4*)(ap + 4);
    const float* bp = W + (size_t)bk * N + colBase;
    pb0 = *(const float4*)(bp + bq4);
    pb1 = *(const float4*)(bp + 64 + bq4);
  }
  for (int t = 0; t < total; ++t) {
    As[aq + 0][arow] = pa0.x; As[aq + 1][arow] = pa0.y;
    As[aq + 2][arow] = pa0.z; As[aq + 3][arow] = pa0.w;
    As[aq + 4][arow] = pa1.x; As[aq + 5][arow] = pa1.y;
    As[aq + 6][arow] = pa1.z; As[aq + 7][arow] = pa1.w;
    *(float4*)&Bs[bk][bq4] = pb0;
    *(float4*)&Bs[bk][64 + bq4] = pb1;
    __syncthreads();
    if (t + 1 < total) {
      int tn = t + 1;
      const float* Ap = (tn >= ktiles) ? A2 : A;
      const float* Wp = (tn >= ktiles) ? W2 : W;
      int k0 = ((tn >= ktiles) ? tn - ktiles : tn) << 4;
      const float* ap = Ap + (size_t)(rowBase + arow) * K + k0 + aq;
      pa0 = *(const float4*)ap;
      pa1 = *(const float4*)(ap + 4);
      const float* bp = Wp + (size_t)(k0 + bk) * N + colBase;
      pb0 = *(const float4*)(bp + bq4);
      pb1 = *(const float4*)(bp + 64 + bq4);
    }
#pragma unroll
    for (int kk = 0; kk < 16; ++kk) {
      float a[8];
      v2f bv[4];
      *(float4*)&a[0] = *(const float4*)&As[kk][ty * 8];
      *(float4*)&a[4] = *(const float4*)&As[kk][ty * 8 + 4];
      *(float4*)&bv[0] = *(const float4*)&Bs[kk][tx * 4];
      *(float4*)&bv[2] = *(const float4*)&Bs[kk][64 + tx * 4];
#pragma unroll
      for (int r = 0; r < 8; ++r)
#pragma unroll
        for (int c = 0; c < 4; ++c) acc[r][c] += a[r] * bv[c];
    }
    __syncthreads();
  }
#pragma unroll
  for (int r = 0; r < 8; ++r) {
    int row = rowBase + ty * 8 + r;
#pragma unroll
    for (int h = 0; h < 2; ++h) {
      int col = colBase + h * 64 + tx * 4;
      float av[4];
      *(v2f*)&av[0] = acc[r][h * 2 + 0];
      *(v2f*)&av[2] = acc[r][h * 2 + 1];
      float4 v;
      float* vp = (float*)&v;
#pragma unroll
      for (int c = 0; c < 4; ++c) {
        float t = av[c];
        if (bias) t += bias[col + c];
        if (flags & GF_RELU) t = fmaxf(t, 0.0f);
        vp[c] = t;
      }
      size_t o = (size_t)row * N + col;
      if (flags & GF_ACCUM) {
        float4 old = *(float4*)&C[o];
        v.x += old.x; v.y += old.y; v.z += old.z; v.w += old.w;
      }
      *(float4*)&C[o] = v;
    }
  }
}

// ---------------- fused FFN: x += relu(xn2@W1 + b1) @ W2 + b2 ------------------
__global__ __launch_bounds__(256) void ffn_fused_kernel(
    const float* __restrict__ xn, const float* __restrict__ W1,
    const float* __restrict__ b1, const float* __restrict__ W2,
    const float* __restrict__ b2, float* __restrict__ x) {
  __shared__ float Axn[128 * 36];
  __shared__ float Hs [128 * 36];
  __shared__ float Bs [16 * 132];
  int tid = threadIdx.x;
  int rowBase = blockIdx.x * 32;
  int tx = tid & 31, ty = tid >> 5;
  {
    int row = tid >> 3, ks = (tid & 7) * 16;
    const float* s1 = xn + (size_t)(rowBase + row) * 128 + ks;
#pragma unroll
    for (int q = 0; q < 4; ++q) {
      float4 v = *(const float4*)(s1 + q * 4);
      int k = ks + q * 4;
      Axn[(k + 0) * 36 + row] = v.x; Axn[(k + 1) * 36 + row] = v.y;
      Axn[(k + 2) * 36 + row] = v.z; Axn[(k + 3) * 36 + row] = v.w;
    }
  }
  int bk = tid >> 4, bc = (tid & 15) * 8;
  v2f hacc[4][2] = {};
  {
    float4 p0 = *(const float4*)(W1 + (size_t)bk * 128 + bc);
    float4 p1 = *(const float4*)(W1 + (size_t)bk * 128 + bc + 4);
    for (int kt = 0; kt < 8; ++kt) {
      __syncthreads();
      *(float4*)&Bs[bk * 132 + bc] = p0;
      *(float4*)&Bs[bk * 132 + bc + 4] = p1;
      __syncthreads();
      if (kt < 7) {
        p0 = *(const float4*)(W1 + (size_t)(kt * 16 + 16 + bk) * 128 + bc);
        p1 = *(const float4*)(W1 + (size_t)(kt * 16 + 16 + bk) * 128 + bc + 4);
      }
      int k0 = kt * 16;
#pragma unroll
      for (int kk = 0; kk < 16; ++kk) {
        float av[4];
        v2f bv[2];
        *(float4*)av = *(const float4*)&Axn[(k0 + kk) * 36 + ty * 4];
        *(float4*)&bv[0] = *(const float4*)&Bs[kk * 132 + tx * 4];
#pragma unroll
        for (int r = 0; r < 4; ++r)
#pragma unroll
          for (int c = 0; c < 2; ++c) hacc[r][c] += av[r] * bv[c];
      }
    }
  }
  __syncthreads();
#pragma unroll
  for (int r = 0; r < 4; ++r) {
    float hv[4];
    *(v2f*)&hv[0] = hacc[r][0];
    *(v2f*)&hv[2] = hacc[r][1];
#pragma unroll
    for (int c = 0; c < 4; ++c) {
      float v = hv[c] + b1[tx * 4 + c];
      v = fmaxf(v, 0.0f);
      Hs[(tx * 4 + c) * 36 + ty * 4 + r] = v;
    }
  }
  v2f oacc[4][2] = {};
  {
    float4 q0 = *(const float4*)(W2 + (size_t)bk * 128 + bc);
    float4 q1 = *(const float4*)(W2 + (size_t)bk * 128 + bc + 4);
    for (int kt = 0; kt < 8; ++kt) {
      __syncthreads();
      *(float4*)&Bs[bk * 132 + bc] = q0;
      *(float4*)&Bs[bk * 132 + bc + 4] = q1;
      __syncthreads();
      if (kt < 7) {
        q0 = *(const float4*)(W2 + (size_t)(kt * 16 + 16 + bk) * 128 + bc);
        q1 = *(const float4*)(W2 + (size_t)(kt * 16 + 16 + bk) * 128 + bc + 4);
      }
      int k0 = kt * 16;
#pragma unroll
      for (int kk = 0; kk < 16; ++kk) {
        float av[4];
        v2f bv[2];
        *(float4*)av = *(const float4*)&Hs[(k0 + kk) * 36 + ty * 4];
        *(float4*)&bv[0] = *(const float4*)&Bs[kk * 132 + tx * 4];
#pragma unroll
        for (int r = 0; r < 4; ++r)
#pragma unroll
          for (int c = 0; c < 2; ++c) oacc[r][c] += av[r] * bv[c];
      }
    }
  }
#pragma unroll
  for (int r = 0; r < 4; ++r) {
    int row = rowBase + ty * 4 + r;
    float ov[4];
    *(v2f*)&ov[0] = oacc[r][0];
    *(v2f*)&ov[2] = oacc[r][1];
    float4 old = *(float4*)&x[(size_t)row * 128 + tx * 4];
    float4 v;
    v.x = ov[0] + b2[tx * 4 + 0]; v.x += old.x;
    v.y = ov[1] + b2[tx * 4 + 1]; v.y += old.y;
    v.z = ov[2] + b2[tx * 4 + 2]; v.z += old.z;
    v.w = ov[3] + b2[tx * 4 + 3]; v.w += old.w;
    *(float4*)&x[(size_t)row * 128 + tx * 4] = v;
  }
}

// ---------------- q = x@Wq ; p = dinv*q ---------------------------------------
__global__ void qp_kernel(const float* __restrict__ x, const float* __restrict__ Wq,
                          const float* __restrict__ dinv, float* __restrict__ p, int Ni) {
  int node = blockIdx.x;
  int lane = threadIdx.x;
  int b = node / Ni, i = node % Ni;
  float v = x[(size_t)node * 128 + lane] * Wq[lane] +
            x[(size_t)node * 128 + 64 + lane] * Wq[64 + lane];
  for (int off = 32; off >= 1; off >>= 1) v += __shfl_xor(v, off, 64);
  if (lane == 0) p[b * Nmax + i] = dinv[b * Nmax + i] * v;
}

// ---------------- s = dinv * (A @ p) + bq -------------------------------------
__global__ void score_kernel(const u32* __restrict__ adj, const float* __restrict__ p,
                             const float* __restrict__ dinv, const float* __restrict__ bq,
                             float* __restrict__ s, int Ni) {
  int i = blockIdx.x, b = blockIdx.y, lane = threadIdx.x;
  int wpr = Ni >> 5;
  float acc = 0.0f;
  if (lane < wpr) {
    u32 bits = adj[((size_t)(b * Nmax + i)) * 64 + lane];
    while (bits) {
      int bit = __ffs(bits) - 1;
      bits &= bits - 1;
      acc += p[b * Nmax + (lane << 5) + bit];
    }
  }
  for (int off = 32; off >= 1; off >>= 1) acc += __shfl_xor(acc, off, 64);
  if (lane == 0) s[b * Nmax + i] = dinv[b * Nmax + i] * acc + bq[0];
}

// ---------------- top-k via exact rank counting --------------------------------
__global__ void topk_rank_kernel(const float* __restrict__ s, int Ni, int* __restrict__ topi) {
  int b = blockIdx.y;
  int e0 = blockIdx.x * 256;
  int t = threadIdx.x;
  __shared__ u64 keys[2048];
  for (int e = t; e < Ni; e += 256) {
    u32 u = __float_as_uint(s[b * Nmax + e]);
    u32 mono = (u & 0x80000000u) ? ~u : (u | 0x80000000u);
    keys[e] = ((u64)(~mono) << 32) | (u32)e;
  }
  __syncthreads();
  int e = e0 + t;
  if (e >= Ni) return;
  u64 my = keys[e];
  int rank = 0;
  for (int q = 0; q < Ni; ++q) rank += (keys[q] < my) ? 1 : 0;
  int kkeep = Ni >> 1;
  if (rank < kkeep) topi[b * 1024 + rank] = e;
}

// ---------------- gather + tanh gate ------------------------------------------
__global__ void gather_kernel(const float* __restrict__ x, const float* __restrict__ c,
                              const float* __restrict__ s, const int* __restrict__ topi,
                              float* __restrict__ xo, float* __restrict__ co, int Ni) {
  int inew = blockIdx.x, b = blockIdx.y, t = threadIdx.x;
  int kkeep = Ni >> 1;
  int old = topi[b * 1024 + inew];
  float gate = tanhf(s[b * Nmax + old]);
  xo[((size_t)b * kkeep + inew) * 128 + t] = x[((size_t)b * Ni + old) * 128 + t] * gate;
  if (t < 2) co[((size_t)b * kkeep + inew) * 2 + t] = c[((size_t)b * Ni + old) * 2 + t];
}

// ---------------- picks: two-stage [max ; mean] reduction ----------------------
__global__ void picks_partial_kernel(const float* __restrict__ x, float* __restrict__ part,
                                     int kkeep, int G) {
  int b = blockIdx.x, g = blockIdx.y, t = threadIdx.x;
  int per = kkeep / G;
  int start = g * per;
  float mx = -INFINITY, sm = 0.0f;
  for (int i = start; i < start + per; ++i) {
    float v = x[((size_t)b * kkeep + i) * 128 + t];
    mx = fmaxf(mx, v);
    sm += v;
  }
  part[((size_t)(b * G + g)) * 256 + t] = mx;
  part[((size_t)(b * G + g)) * 256 + 128 + t] = sm;
}

__global__ void picks_combine_kernel(const float* __restrict__ part, float* __restrict__ picks,
                                     int kkeep, int G) {
  int b = blockIdx.x, t = threadIdx.x;
  float mx = -INFINITY, sm = 0.0f;
  for (int g = 0; g < G; ++g) {
    mx = fmaxf(mx, part[((size_t)(b * G + g)) * 256 + t]);
    sm += part[((size_t)(b * G + g)) * 256 + 128 + t];
  }
  picks[b * 256 + t] += mx;
  picks[b * 256 + 128 + t] += sm / (float)kkeep;
}

// ---------------- final 2-layer MLP -------------------------------------------
__global__ void final_kernel(const float* __restrict__ picks, const float* __restrict__ Wf1,
                             const float* __restrict__ bf1, const float* __restrict__ Wf2,
                             const float* __restrict__ bf2, float* __restrict__ out) {
  int b = blockIdx.x, t = threadIdx.x;
  __shared__ float pk[256];
  __shared__ float fm[128];
  pk[t] = picks[b * 256 + t];
  pk[t + 128] = picks[b * 256 + 128 + t];
  __syncthreads();
  float acc = bf1[t];
  for (int k = 0; k < 256; ++k) acc += pk[k] * Wf1[k * 128 + t];
  fm[t] = fmaxf(acc, 0.0f);
  __syncthreads();
  if (t < 32) {
    float a2 = bf2[t];
    for (int k = 0; k < 128; ++k) a2 += fm[k] * Wf2[k * 32 + t];
    out[b * 32 + t] = fmaxf(a2, 0.0f);
  }
}

extern "C" void kernel_launch(void* const* d_in, const int* in_sizes, int n_in,
                              void* d_out, int out_size, void* d_ws, size_t ws_size,
                              hipStream_t stream) {
  const float* feats = (const float*)d_in[0];
  const float* cent  = (const float*)d_in[1];
  const float* Wp1 = (const float*)d_in[2];
  const float* bp1 = (const float*)d_in[3];
  const float* bn_g = (const float*)d_in[4];
  const float* bn_b = (const float*)d_in[5];
  const float* Wp2 = (const float*)d_in[6];
  const float* bp2 = (const float*)d_in[7];
  const float* g1  = (const float*)d_in[8];
  const float* be1 = (const float*)d_in[9];
  const float* g2  = (const float*)d_in[10];
  const float* be2 = (const float*)d_in[11];
  const float* Ws  = (const float*)d_in[12];
  const float* Wn  = (const float*)d_in[13];
  const float* bs  = (const float*)d_in[14];
  const float* Wg  = (const float*)d_in[15];
  const float* bg  = (const float*)d_in[16];
  const float* W1  = (const float*)d_in[17];
  const float* b1  = (const float*)d_in[18];
  const float* W2  = (const float*)d_in[19];
  const float* b2  = (const float*)d_in[20];
  const float* Wq  = (const float*)d_in[21];
  const float* bq  = (const float*)d_in[22];
  const float* Wf1 = (const float*)d_in[23];
  const float* bf1 = (const float*)d_in[24];
  const float* Wf2 = (const float*)d_in[25];
  const float* bf2 = (const float*)d_in[26];
  float* out = (float*)d_out;

  float* p = (float*)d_ws;
  const size_t SZX = (size_t)Bn * Nmax * 128;
  float* SC = p;    p += 128;
  float* BBv = p;   p += 128;
  float* DINV = p;  p += Bn * Nmax;
  float* PV = p;    p += Bn * Nmax;
  float* SS = p;    p += Bn * Nmax;
  float* PICKS = p; p += Bn * 256;
  float* PART = p;  p += (size_t)Bn * 32 * 256;
  float* C0 = p;    p += (size_t)Bn * Nmax * 2;
  float* C1 = p;    p += (size_t)Bn * Nmax * 2;
  int* KNN = (int*)p;  p += (size_t)Bn * Nmax * KNN_K;
  int* TOPI = (int*)p; p += Bn * 1024;
  u32* ADJ = (u32*)p;  p += (size_t)Bn * Nmax * 64;
  float* X0 = p;    p += SZX;
  float* X1 = p;    p += SZX;
  float* BA = p;    p += SZX;
  float* BB = p;    p += SZX;
  float* HB = p;    // h partial 0 / preconv partials: 4*SZX
  size_t base_floats = (size_t)(p - (float*)d_ws);
  const size_t WPSZ = (size_t)3 * 128 * 512;
  bool fused = ws_size >= (base_floats + 4 * SZX + 2 * WPSZ) * sizeof(float);
  float* WSP = HB + 4 * SZX;
  float* WNP = WSP + WPSZ;
  float* PK = WNP + WPSZ;  // h partial 1: 4*SZX
  bool fused2 = ws_size >= (base_floats + 8 * SZX + 2 * WPSZ) * sizeof(float);

  hipLaunchKernelGGL(precompute_kernel, dim3(1), dim3(256), 0, stream,
                     bn_g, bn_b, bp1, SC, BBv, PICKS);
  if (fused) {
    hipLaunchKernelGGL(repack_ws_kernel, dim3(768), dim3(256), 0, stream, Ws, Wn, WSP, WNP);
  }

  // ---- preconv ----
  const int M0 = Bn * Nmax;
  if (fused) {
    // K-sliced 128-tile partials into HB; combine fused into preconv2 A-load
    hipLaunchKernelGGL(gemm128ks_kernel, dim3(1, M0 / 128, 4), dim3(256), 0, stream,
                       feats, Wp1, HB, M0, 512);
    hipLaunchKernelGGL(gemm_psum4_kernel, dim3(1, M0 / 32), dim3(256), 0, stream,
                       HB, SC, BBv, Wp2, bp2, X0, M0);
  } else {
    hipLaunchKernelGGL(gemm_kernel<32>, dim3(1, M0 / 32), dim3(256), 0, stream,
                       feats, Wp1, (const float*)nullptr, (const float*)nullptr,
                       SC, BBv, BA, M0, 128, 512, GF_RELU);
    hipLaunchKernelGGL(gemm_kernel<32>, dim3(1, M0 / 32), dim3(256), 0, stream,
                       BA, Wp2, (const float*)nullptr, (const float*)nullptr,
                       (const float*)nullptr, bp2, X0, M0, 128, 128, 0);
  }

  float* xc = X0;
  float* xo = X1;
  const float* cc = cent;
  float* co = C0;
  int Ni = Nmax;
  for (int L = 0; L < 3; ++L) {
    int M = Bn * Ni;
    if (Ni == 2048)      hipLaunchKernelGGL(knn_sel_kernel<32>, dim3(Ni, Bn), dim3(64), 0, stream, cc, KNN, Ni);
    else if (Ni == 1024) hipLaunchKernelGGL(knn_sel_kernel<16>, dim3(Ni, Bn), dim3(64), 0, stream, cc, KNN, Ni);
    else                 hipLaunchKernelGGL(knn_sel_kernel<8>,  dim3(Ni, Bn), dim3(64), 0, stream, cc, KNN, Ni);
    hipMemsetAsync(ADJ, 0, (size_t)Bn * Nmax * 64 * sizeof(u32), stream);
    int tot = Bn * Ni * KNN_K;
    hipLaunchKernelGGL(build_adj_kernel, dim3((tot + 255) / 256), dim3(256), 0, stream,
                       KNN, ADJ, Ni);
    hipLaunchKernelGGL(layernorm_kernel, dim3(M / 4), dim3(256), 0, stream,
                       xc, g1 + L * 128, be1 + L * 128, BA);
    hipLaunchKernelGGL(aggregate_kernel, dim3(Ni, Bn), dim3(128), Ni * sizeof(int), stream,
                       ADJ, BA, BB, DINV, Ni);
    if (fused2) {
      hipLaunchKernelGGL(gemm128dual_kernel, dim3(4, M / 128, 2), dim3(256), 0, stream,
                         BA, WSP + (size_t)L * 128 * 512,
                         BB, WNP + (size_t)L * 128 * 512,
                         HB, PK, M, 512);
      hipLaunchKernelGGL(gemm_hsum_kernel, dim3(1, M / 32), dim3(256), 0, stream,
                         HB, PK, bs + L * 512, Wg + (size_t)L * 512 * 128,
                         bg + L * 128, xc, M);
    } else if (fused) {
      hipLaunchKernelGGL(gemm128_kernel, dim3(4, M / 128), dim3(256), 0, stream,
                         BA, WSP + (size_t)L * 128 * 512,
                         BB, WNP + (size_t)L * 128 * 512,
                         bs + L * 512, HB, M, 512, 128, GF_RELU);
      hipLaunchKernelGGL(gemm_kernel<32>, dim3(1, M / 32), dim3(256), 0, stream,
                         HB, Wg + (size_t)L * 512 * 128,
                         (const float*)nullptr, (const float*)nullptr,
                         (const float*)nullptr, bg + L * 128,
                         xc, M, 128, 512, GF_ACCUM);
    } else {
      for (int hh = 0; hh < 4; ++hh) {
        hipLaunchKernelGGL(gemm_kernel<32>, dim3(1, M / 32), dim3(256), 0, stream,
                           BA, Ws + ((size_t)(L * 4 + hh)) * 128 * 128,
                           BB, Wn + ((size_t)(L * 4 + hh)) * 128 * 128,
                           (const float*)nullptr, bs + (L * 4 + hh) * 128,
                           HB, M, 128, 128, GF_RELU);
        hipLaunchKernelGGL(gemm_kernel<32>, dim3(1, M / 32), dim3(256), 0, stream,
                           HB, Wg + ((size_t)L * 512 + hh * 128) * 128,
                           (const float*)nullptr, (const float*)nullptr,
                           (const float*)nullptr, (hh == 0) ? (bg + L * 128) : (const float*)nullptr,
                           xc, M, 128, 128, GF_ACCUM);
      }
    }
    hipLaunchKernelGGL(layernorm_kernel, dim3(M / 4), dim3(256), 0, stream,
                       xc, g2 + L * 128, be2 + L * 128, BA);
    hipLaunchKernelGGL(ffn_fused_kernel, dim3(M / 32), dim3(256), 0, stream,
                       BA, W1 + (size_t)L * 128 * 128, b1 + L * 128,
                       W2 + (size_t)L * 128 * 128, b2 + L * 128, xc);
    hipLaunchKernelGGL(qp_kernel, dim3(M), dim3(64), 0, stream, xc, Wq + L * 128, DINV, PV, Ni);
    hipLaunchKernelGGL(score_kernel, dim3(Ni, Bn), dim3(64), 0, stream, ADJ, PV, DINV, bq + L, SS, Ni);
    hipLaunchKernelGGL(topk_rank_kernel, dim3((Ni + 255) / 256, Bn), dim3(256), 0, stream,
                       SS, Ni, TOPI);
    int kkeep = Ni >> 1;
    hipLaunchKernelGGL(gather_kernel, dim3(kkeep, Bn), dim3(128), 0, stream,
                       xc, cc, SS, TOPI, xo, co, Ni);
    int G = kkeep / 32;
    hipLaunchKernelGGL(picks_partial_kernel, dim3(Bn, G), dim3(128), 0, stream,
                       xo, PART, kkeep, G);
    hipLaunchKernelGGL(picks_combine_kernel, dim3(Bn), dim3(128), 0, stream,
                       PART, PICKS, kkeep, G);
    float* tmp = xc; xc = xo; xo = tmp;
    cc = co;
    co = (co == C0) ? C1 : C0;
    Ni = kkeep;
  }
  hipLaunchKernelGGL(final_kernel, dim3(Bn), dim3(128), 0, stream,
                     PICKS, Wf1, bf1, Wf2, bf2, out);
}

// Round 13
// 689.773 us; speedup vs baseline: 1.0923x; 1.0024x over previous
//
#include <hip/hip_runtime.h>
#include <math.h>

#define EPSV 1e-5f
#define GF_RELU 1
#define GF_ACCUM 2

typedef unsigned long long u64;
typedef unsigned int u32;
typedef float v2f __attribute__((ext_vector_type(2)));

static const int Bn = 8;
static const int Nmax = 2048;
static const int KNN_K = 8;

// ---------------- precompute: fold BN into scale/bias, zero picks ----------------
__global__ void precompute_kernel(const float* __restrict__ bn_g, const float* __restrict__ bn_b,
                                  const float* __restrict__ bp1,
                                  float* __restrict__ sc, float* __restrict__ bb,
                                  float* __restrict__ picks) {
  int t = threadIdx.x;
  if (t < 128) {
    float s = bn_g[t] / sqrtf(1.0f + EPSV);
    sc[t] = s;
    bb[t] = bp1[t] * s + bn_b[t];
  }
  for (int i = t; i < Bn * 256; i += blockDim.x) picks[i] = 0.0f;
}

// ---------------- repack Ws/Wn [L][h][d][e] -> [L][d][h*128+e] -----------------
__global__ void repack_ws_kernel(const float* __restrict__ Ws, const float* __restrict__ Wn,
                                 float* __restrict__ WsP, float* __restrict__ WnP) {
  int idx = blockIdx.x * 256 + threadIdx.x;
  const int total = 3 * 4 * 128 * 128;
  if (idx >= total) return;
  int e = idx & 127, d = (idx >> 7) & 127, h = (idx >> 14) & 3, L = idx >> 16;
  size_t dst = ((size_t)L * 128 + d) * 512 + h * 128 + e;
  WsP[dst] = Ws[idx];
  WnP[dst] = Wn[idx];
}

// ---------------- KNN: keys in registers, 8 wave-min extraction rounds ---------
template<int T>
__global__ __launch_bounds__(64) void knn_sel_kernel(const float* __restrict__ cent,
                                                     int* __restrict__ knn_idx, int Ni) {
  int i = blockIdx.x, b = blockIdx.y, lane = threadIdx.x;
  const float2* cb = (const float2*)(cent + (size_t)b * Ni * 2);
  float2 ci = cb[i];
  u64 keys[T];
#pragma unroll
  for (int t = 0; t < T; ++t) {
    int j = (t << 6) + lane;
    float2 cj = cb[j];
    float dx = __fsub_rn(ci.x, cj.x);
    float dy = __fsub_rn(ci.y, cj.y);
    float d2 = __fadd_rn(__fmul_rn(dx, dx), __fmul_rn(dy, dy));
    keys[t] = ((u64)__float_as_uint(d2) << 32) | (u32)j;
  }
  u64 prev = 0;
  for (int r = 0; r < KNN_K; ++r) {
    u64 best = ~0ULL;
    if (r == 0) {
#pragma unroll
      for (int t = 0; t < T; ++t) { if (keys[t] < best) best = keys[t]; }
    } else {
#pragma unroll
      for (int t = 0; t < T; ++t) { if (keys[t] > prev && keys[t] < best) best = keys[t]; }
    }
    for (int off = 32; off >= 1; off >>= 1) {
      u64 o = __shfl_xor(best, off, 64);
      if (o < best) best = o;
    }
    if (lane == 0) knn_idx[((size_t)(b * Ni + i)) * KNN_K + r] = (int)(best & 0xffffffffULL);
    prev = best;
  }
}

// ---------------- adjacency bitmask: A = mask | mask^T -------------------------
__global__ void build_adj_kernel(const int* __restrict__ knn_idx, u32* __restrict__ adj, int Ni) {
  int e = blockIdx.x * blockDim.x + threadIdx.x;
  int total = Bn * Ni * KNN_K;
  if (e >= total) return;
  int b = e / (Ni * KNN_K);
  int rem = e % (Ni * KNN_K);
  int r = rem / KNN_K;
  int j = knn_idx[e];
  atomicOr(&adj[((size_t)(b * Nmax + r)) * 64 + (j >> 5)], 1u << (j & 31));
  atomicOr(&adj[((size_t)(b * Nmax + j)) * 64 + (r >> 5)], 1u << (r & 31));
}

// ---------------- layernorm: one wave per row, shuffle butterfly (fallback) ----
__global__ __launch_bounds__(256) void layernorm_kernel(const float* __restrict__ x,
                                                        const float* __restrict__ g,
                                                        const float* __restrict__ be,
                                                        float* __restrict__ xn) {
  int row = blockIdx.x * 4 + (threadIdx.x >> 6);
  int lane = threadIdx.x & 63;
  const float* xr = x + (size_t)row * 128;
  float v1 = xr[lane], v2 = xr[lane + 64];
  float s = v1 + v2;
  for (int off = 32; off >= 1; off >>= 1) s += __shfl_xor(s, off, 64);
  float mean = s / 128.0f;
  float d1 = v1 - mean, d2 = v2 - mean;
  float q = d1 * d1 + d2 * d2;
  for (int off = 32; off >= 1; off >>= 1) q += __shfl_xor(q, off, 64);
  float rs = rsqrtf(q / 128.0f + EPSV);
  float* xo = xn + (size_t)row * 128;
  xo[lane] = d1 * rs * g[lane] + be[lane];
  xo[lane + 64] = d2 * rs * g[lane + 64] + be[lane + 64];
}

// ---------------- neighbor-mean aggregation + degree ---------------------------
__global__ void aggregate_kernel(const u32* __restrict__ adj, const float* __restrict__ xn,
                                 float* __restrict__ m, float* __restrict__ dinv, int Ni) {
  int i = blockIdx.x, b = blockIdx.y, t = threadIdx.x;
  __shared__ int cnt;
  extern __shared__ int list[];
  if (t == 0) cnt = 0;
  __syncthreads();
  int wpr = Ni >> 5;
  for (int w = t; w < wpr; w += blockDim.x) {
    u32 bits = adj[((size_t)(b * Nmax + i)) * 64 + w];
    while (bits) {
      int bit = __ffs(bits) - 1;
      bits &= bits - 1;
      int pos = atomicAdd(&cnt, 1);
      list[pos] = (w << 5) + bit;
    }
  }
  __syncthreads();
  int d = cnt;
  float acc = 0.0f;
  for (int k = 0; k < d; ++k) acc += xn[((size_t)b * Ni + list[k]) * 128 + t];
  m[((size_t)b * Ni + i) * 128 + t] = acc / (float)d;
  if (t == 0) dinv[b * Nmax + i] = 1.0f / sqrtf((float)d);
}

// ---------------- fp32 GEMM, TMx128 tile, packed v2f FMA, register prefetch ----
template<int TM>
__global__ __launch_bounds__(256) void gemm_kernel(
    const float* __restrict__ A, const float* __restrict__ W,
    const float* __restrict__ A2, const float* __restrict__ W2,
    const float* __restrict__ scale, const float* __restrict__ bias,
    float* __restrict__ C, int M, int N, int K, int flags) {
  constexpr int RPT = TM / 8;
  __shared__ float As[16][TM + 4];
  __shared__ float Bs[16][132];
  int tid = threadIdx.x;
  int tx = tid & 31;
  int ty = tid >> 5;
  int colBase = blockIdx.x * 128, rowBase = blockIdx.y * TM;
  v2f acc[RPT][2] = {};
  int ktiles = K >> 4;
  int total = (A2 ? 2 : 1) * ktiles;

  int arow = tid >> 2, aq = (tid & 3) * 4;
  int bk = tid >> 5, bc = (tid & 31) * 4;

  float4 pa, pb0, pb1;
  {
    if (TM == 64 || tid < TM * 4)
      pa = *(const float4*)(A + (size_t)(rowBase + arow) * K + aq);
    pb0 = *(const float4*)(W + (size_t)bk * N + colBase + bc);
    pb1 = *(const float4*)(W + (size_t)(bk + 8) * N + colBase + bc);
  }
  for (int t = 0; t < total; ++t) {
    if (TM == 64 || tid < TM * 4) {
      As[aq + 0][arow] = pa.x;
      As[aq + 1][arow] = pa.y;
      As[aq + 2][arow] = pa.z;
      As[aq + 3][arow] = pa.w;
    }
    *(float4*)&Bs[bk][bc] = pb0;
    *(float4*)&Bs[bk + 8][bc] = pb1;
    __syncthreads();
    if (t + 1 < total) {
      int tn = t + 1;
      const float* Ap = (tn >= ktiles) ? A2 : A;
      const float* Wp = (tn >= ktiles) ? W2 : W;
      int k0 = ((tn >= ktiles) ? tn - ktiles : tn) << 4;
      if (TM == 64 || tid < TM * 4)
        pa = *(const float4*)(Ap + (size_t)(rowBase + arow) * K + k0 + aq);
      pb0 = *(const float4*)(Wp + (size_t)(k0 + bk) * N + colBase + bc);
      pb1 = *(const float4*)(Wp + (size_t)(k0 + bk + 8) * N + colBase + bc);
    }
#pragma unroll
    for (int kk = 0; kk < 16; ++kk) {
      float a[RPT];
      v2f bv[2];
      if (RPT == 8) {
        *(float4*)&a[0] = *(const float4*)&As[kk][ty * 8];
        *(float4*)&a[4] = *(const float4*)&As[kk][ty * 8 + 4];
      } else {
        *(float4*)&a[0] = *(const float4*)&As[kk][ty * 4];
      }
      *(float4*)&bv[0] = *(const float4*)&Bs[kk][tx * 4];
#pragma unroll
      for (int r = 0; r < RPT; ++r)
#pragma unroll
        for (int c = 0; c < 2; ++c) acc[r][c] += a[r] * bv[c];
    }
    __syncthreads();
  }
#pragma unroll
  for (int r = 0; r < RPT; ++r) {
    int row = rowBase + ty * RPT + r;
    int col = colBase + tx * 4;
    float av[4];
    *(v2f*)&av[0] = acc[r][0];
    *(v2f*)&av[2] = acc[r][1];
    float4 v;
    float* vp = (float*)&v;
#pragma unroll
    for (int c = 0; c < 4; ++c) {
      float t = av[c];
      if (scale) t *= scale[col + c];
      if (bias) t += bias[col + c];
      if (flags & GF_RELU) t = fmaxf(t, 0.0f);
      vp[c] = t;
    }
    size_t o = (size_t)row * N + col;
    if (flags & GF_ACCUM) {
      float4 old = *(float4*)&C[o];
      v.x += old.x; v.y += old.y; v.z += old.z; v.w += old.w;
    }
    *(float4*)&C[o] = v;
  }
}

// ---------------- dual-operand 128x128-tile GEMM, raw partials -----------------
__global__ __launch_bounds__(256) void gemm128dual_kernel(
    const float* __restrict__ A0, const float* __restrict__ W0,
    const float* __restrict__ A1, const float* __restrict__ W1,
    float* __restrict__ C0p, float* __restrict__ C1p, int M, int N) {
  const float* A = blockIdx.z ? A1 : A0;
  const float* W = blockIdx.z ? W1 : W0;
  float* C = blockIdx.z ? C1p : C0p;
  __shared__ float As[16][132];
  __shared__ float Bs[16][132];
  int tid = threadIdx.x;
  int tx = tid & 15;
  int ty = tid >> 4;
  int colBase = blockIdx.x * 128, rowBase = blockIdx.y * 128;
  v2f acc[8][4] = {};

  int arow = tid >> 1, aq = (tid & 1) * 8;
  int bk = tid >> 4, bq4 = (tid & 15) * 4;

  float4 pa0, pa1, pb0, pb1;
  {
    const float* ap = A + (size_t)(rowBase + arow) * 128 + aq;
    pa0 = *(const float4*)ap;
    pa1 = *(const float4*)(ap + 4);
    const float* bp = W + (size_t)bk * N + colBase;
    pb0 = *(const float4*)(bp + bq4);
    pb1 = *(const float4*)(bp + 64 + bq4);
  }
  for (int t = 0; t < 8; ++t) {
    As[aq + 0][arow] = pa0.x; As[aq + 1][arow] = pa0.y;
    As[aq + 2][arow] = pa0.z; As[aq + 3][arow] = pa0.w;
    As[aq + 4][arow] = pa1.x; As[aq + 5][arow] = pa1.y;
    As[aq + 6][arow] = pa1.z; As[aq + 7][arow] = pa1.w;
    *(float4*)&Bs[bk][bq4] = pb0;
    *(float4*)&Bs[bk][64 + bq4] = pb1;
    __syncthreads();
    if (t + 1 < 8) {
      int k0 = (t + 1) << 4;
      const float* ap = A + (size_t)(rowBase + arow) * 128 + k0 + aq;
      pa0 = *(const float4*)ap;
      pa1 = *(const float4*)(ap + 4);
      const float* bp = W + (size_t)(k0 + bk) * N + colBase;
      pb0 = *(const float4*)(bp + bq4);
      pb1 = *(const float4*)(bp + 64 + bq4);
    }
#pragma unroll
    for (int kk = 0; kk < 16; ++kk) {
      float a[8];
      v2f bv[4];
      *(float4*)&a[0] = *(const float4*)&As[kk][ty * 8];
      *(float4*)&a[4] = *(const float4*)&As[kk][ty * 8 + 4];
      *(float4*)&bv[0] = *(const float4*)&Bs[kk][tx * 4];
      *(float4*)&bv[2] = *(const float4*)&Bs[kk][64 + tx * 4];
#pragma unroll
      for (int r = 0; r < 8; ++r)
#pragma unroll
        for (int c = 0; c < 4; ++c) acc[r][c] += a[r] * bv[c];
    }
    __syncthreads();
  }
#pragma unroll
  for (int r = 0; r < 8; ++r) {
    int row = rowBase + ty * 8 + r;
#pragma unroll
    for (int h = 0; h < 2; ++h) {
      int col = colBase + h * 64 + tx * 4;
      float4 v;
      *(v2f*)&v.x = acc[r][h * 2 + 0];
      *(v2f*)&v.z = acc[r][h * 2 + 1];
      *(float4*)&C[(size_t)row * N + col] = v;
    }
  }
}

// ---------------- K-sliced 128x128-tile GEMM, raw partials (N=128) -------------
__global__ __launch_bounds__(256) void gemm128ks_kernel(
    const float* __restrict__ A, const float* __restrict__ W,
    float* __restrict__ P, int M, int K) {
  __shared__ float As[16][132];
  __shared__ float Bs[16][132];
  int tid = threadIdx.x;
  int tx = tid & 15;
  int ty = tid >> 4;
  int rowBase = blockIdx.y * 128;
  int kbase = blockIdx.z * 128;
  v2f acc[8][4] = {};

  int arow = tid >> 1, aq = (tid & 1) * 8;
  int bk = tid >> 4, bq4 = (tid & 15) * 4;

  float4 pa0, pa1, pb0, pb1;
  {
    const float* ap = A + (size_t)(rowBase + arow) * K + kbase + aq;
    pa0 = *(const float4*)ap;
    pa1 = *(const float4*)(ap + 4);
    const float* bp = W + (size_t)(kbase + bk) * 128;
    pb0 = *(const float4*)(bp + bq4);
    pb1 = *(const float4*)(bp + 64 + bq4);
  }
  for (int t = 0; t < 8; ++t) {
    As[aq + 0][arow] = pa0.x; As[aq + 1][arow] = pa0.y;
    As[aq + 2][arow] = pa0.z; As[aq + 3][arow] = pa0.w;
    As[aq + 4][arow] = pa1.x; As[aq + 5][arow] = pa1.y;
    As[aq + 6][arow] = pa1.z; As[aq + 7][arow] = pa1.w;
    *(float4*)&Bs[bk][bq4] = pb0;
    *(float4*)&Bs[bk][64 + bq4] = pb1;
    __syncthreads();
    if (t + 1 < 8) {
      int k0 = kbase + ((t + 1) << 4);
      const float* ap = A + (size_t)(rowBase + arow) * K + k0 + aq;
      pa0 = *(const float4*)ap;
      pa1 = *(const float4*)(ap + 4);
      const float* bp = W + (size_t)(k0 + bk) * 128;
      pb0 = *(const float4*)(bp + bq4);
      pb1 = *(const float4*)(bp + 64 + bq4);
    }
#pragma unroll
    for (int kk = 0; kk < 16; ++kk) {
      float a[8];
      v2f bv[4];
      *(float4*)&a[0] = *(const float4*)&As[kk][ty * 8];
      *(float4*)&a[4] = *(const float4*)&As[kk][ty * 8 + 4];
      *(float4*)&bv[0] = *(const float4*)&Bs[kk][tx * 4];
      *(float4*)&bv[2] = *(const float4*)&Bs[kk][64 + tx * 4];
#pragma unroll
      for (int r = 0; r < 8; ++r)
#pragma unroll
        for (int c = 0; c < 4; ++c) acc[r][c] += a[r] * bv[c];
    }
    __syncthreads();
  }
  float* dst = P + (size_t)blockIdx.z * M * 128;
#pragma unroll
  for (int r = 0; r < 8; ++r) {
    int row = rowBase + ty * 8 + r;
#pragma unroll
    for (int h = 0; h < 2; ++h) {
      int col = h * 64 + tx * 4;
      float4 v;
      *(v2f*)&v.x = acc[r][h * 2 + 0];
      *(v2f*)&v.z = acc[r][h * 2 + 1];
      *(float4*)&dst[(size_t)row * 128 + col] = v;
    }
  }
}

// ---------------- Wg GEMM, 128x128 tile, K-sliced, fused h-combine on A-load ---
// A(row,k) = relu(P0+P1+hbias)(row,k), K=512 split into 4 slices (blockIdx.z).
// Raw partials to Q[z] (selected from Q0..Q3 by z).
__global__ __launch_bounds__(256) void gemm128hsum_kernel(
    const float* __restrict__ P0, const float* __restrict__ P1,
    const float* __restrict__ hbias, const float* __restrict__ W,
    float* __restrict__ Q0, float* __restrict__ Q1,
    float* __restrict__ Q2, float* __restrict__ Q3, int M) {
  float* Q = (blockIdx.z == 0) ? Q0 : (blockIdx.z == 1) ? Q1 : (blockIdx.z == 2) ? Q2 : Q3;
  __shared__ float As[16][132];
  __shared__ float Bs[16][132];
  int tid = threadIdx.x;
  int tx = tid & 15;
  int ty = tid >> 4;
  int rowBase = blockIdx.y * 128;
  int kbase = blockIdx.z * 128;
  v2f acc[8][4] = {};

  int arow = tid >> 1, aq = (tid & 1) * 8;
  int bk = tid >> 4, bq4 = (tid & 15) * 4;

  float4 q0a, q0b, q1a, q1b, hba, hbb, pb0, pb1;
  {
    size_t o = (size_t)(rowBase + arow) * 512 + kbase + aq;
    q0a = *(const float4*)(P0 + o);  q0b = *(const float4*)(P0 + o + 4);
    q1a = *(const float4*)(P1 + o);  q1b = *(const float4*)(P1 + o + 4);
    hba = *(const float4*)(hbias + kbase + aq);
    hbb = *(const float4*)(hbias + kbase + aq + 4);
    const float* bp = W + (size_t)(kbase + bk) * 128;
    pb0 = *(const float4*)(bp + bq4);
    pb1 = *(const float4*)(bp + 64 + bq4);
  }
  for (int t = 0; t < 8; ++t) {
    As[aq + 0][arow] = fmaxf(q0a.x + q1a.x + hba.x, 0.0f);
    As[aq + 1][arow] = fmaxf(q0a.y + q1a.y + hba.y, 0.0f);
    As[aq + 2][arow] = fmaxf(q0a.z + q1a.z + hba.z, 0.0f);
    As[aq + 3][arow] = fmaxf(q0a.w + q1a.w + hba.w, 0.0f);
    As[aq + 4][arow] = fmaxf(q0b.x + q1b.x + hbb.x, 0.0f);
    As[aq + 5][arow] = fmaxf(q0b.y + q1b.y + hbb.y, 0.0f);
    As[aq + 6][arow] = fmaxf(q0b.z + q1b.z + hbb.z, 0.0f);
    As[aq + 7][arow] = fmaxf(q0b.w + q1b.w + hbb.w, 0.0f);
    *(float4*)&Bs[bk][bq4] = pb0;
    *(float4*)&Bs[bk][64 + bq4] = pb1;
    __syncthreads();
    if (t + 1 < 8) {
      int k0 = kbase + ((t + 1) << 4);
      size_t o = (size_t)(rowBase + arow) * 512 + k0 + aq;
      q0a = *(const float4*)(P0 + o);  q0b = *(const float4*)(P0 + o + 4);
      q1a = *(const float4*)(P1 + o);  q1b = *(const float4*)(P1 + o + 4);
      hba = *(const float4*)(hbias + k0 + aq);
      hbb = *(const float4*)(hbias + k0 + aq + 4);
      const float* bp = W + (size_t)(k0 + bk) * 128;
      pb0 = *(const float4*)(bp + bq4);
      pb1 = *(const float4*)(bp + 64 + bq4);
    }
#pragma unroll
    for (int kk = 0; kk < 16; ++kk) {
      float a[8];
      v2f bv[4];
      *(float4*)&a[0] = *(const float4*)&As[kk][ty * 8];
      *(float4*)&a[4] = *(const float4*)&As[kk][ty * 8 + 4];
      *(float4*)&bv[0] = *(const float4*)&Bs[kk][tx * 4];
      *(float4*)&bv[2] = *(const float4*)&Bs[kk][64 + tx * 4];
#pragma unroll
      for (int r = 0; r < 8; ++r)
#pragma unroll
        for (int c = 0; c < 4; ++c) acc[r][c] += a[r] * bv[c];
    }
    __syncthreads();
  }
#pragma unroll
  for (int r = 0; r < 8; ++r) {
    int row = rowBase + ty * 8 + r;
#pragma unroll
    for (int h = 0; h < 2; ++h) {
      int col = h * 64 + tx * 4;
      float4 v;
      *(v2f*)&v.x = acc[r][h * 2 + 0];
      *(v2f*)&v.z = acc[r][h * 2 + 1];
      *(float4*)&Q[(size_t)row * 128 + col] = v;
    }
  }
}

// ---------------- combine 4 Wg partials + residual + LN2 -----------------------
// x += Q0+Q1+Q2+Q3 + bg ; xn = LN(x)*g + be. One wave per row.
__global__ __launch_bounds__(256) void combine_ln_kernel(
    const float* __restrict__ Q0, const float* __restrict__ Q1,
    const float* __restrict__ Q2, const float* __restrict__ Q3,
    const float* __restrict__ bg, const float* __restrict__ g,
    const float* __restrict__ be, float* __restrict__ x, float* __restrict__ xn) {
  int row = blockIdx.x * 4 + (threadIdx.x >> 6);
  int lane = threadIdx.x & 63;
  size_t o1 = (size_t)row * 128 + lane;
  size_t o2 = o1 + 64;
  float v1 = x[o1] + ((((Q0[o1] + Q1[o1]) + Q2[o1]) + Q3[o1]) + bg[lane]);
  float v2 = x[o2] + ((((Q0[o2] + Q1[o2]) + Q2[o2]) + Q3[o2]) + bg[lane + 64]);
  x[o1] = v1;
  x[o2] = v2;
  float s = v1 + v2;
  for (int off = 32; off >= 1; off >>= 1) s += __shfl_xor(s, off, 64);
  float mean = s / 128.0f;
  float d1 = v1 - mean, d2 = v2 - mean;
  float q = d1 * d1 + d2 * d2;
  for (int off = 32; off >= 1; off >>= 1) q += __shfl_xor(q, off, 64);
  float rs = rsqrtf(q / 128.0f + EPSV);
  xn[o1] = d1 * rs * g[lane] + be[lane];
  xn[o2] = d2 * rs * g[lane + 64] + be[lane + 64];
}

// ---------------- preconv2 with fused 4-partial combine + LN1 epilogue ---------
__global__ __launch_bounds__(256) void gemm_psum4_ln_kernel(
    const float* __restrict__ P, const float* __restrict__ sc,
    const float* __restrict__ bb, const float* __restrict__ W,
    const float* __restrict__ bias, const float* __restrict__ g,
    const float* __restrict__ be, float* __restrict__ C,
    float* __restrict__ xn, int M) {
  __shared__ float As[16][36];
  __shared__ float Bs[16][132];
  int tid = threadIdx.x;
  int tx = tid & 31;
  int ty = tid >> 5;
  int rowBase = blockIdx.y * 32;
  v2f acc[4][2] = {};
  const size_t PS = (size_t)M * 128;

  int arow = tid >> 2, aq = (tid & 3) * 4;
  int bk = tid >> 5, bc = (tid & 31) * 4;

  float4 p0, p1, p2, p3, s4, b4, pb0, pb1;
  {
    if (tid < 128) {
      size_t o = (size_t)(rowBase + arow) * 128 + aq;
      p0 = *(const float4*)(P + o);
      p1 = *(const float4*)(P + PS + o);
      p2 = *(const float4*)(P + 2 * PS + o);
      p3 = *(const float4*)(P + 3 * PS + o);
      s4 = *(const float4*)(sc + aq);
      b4 = *(const float4*)(bb + aq);
    }
    pb0 = *(const float4*)(W + (size_t)bk * 128 + bc);
    pb1 = *(const float4*)(W + (size_t)(bk + 8) * 128 + bc);
  }
  for (int t = 0; t < 8; ++t) {
    if (tid < 128) {
      As[aq + 0][arow] = fmaxf((((p0.x + p1.x) + p2.x) + p3.x) * s4.x + b4.x, 0.0f);
      As[aq + 1][arow] = fmaxf((((p0.y + p1.y) + p2.y) + p3.y) * s4.y + b4.y, 0.0f);
      As[aq + 2][arow] = fmaxf((((p0.z + p1.z) + p2.z) + p3.z) * s4.z + b4.z, 0.0f);
      As[aq + 3][arow] = fmaxf((((p0.w + p1.w) + p2.w) + p3.w) * s4.w + b4.w, 0.0f);
    }
    *(float4*)&Bs[bk][bc] = pb0;
    *(float4*)&Bs[bk + 8][bc] = pb1;
    __syncthreads();
    if (t + 1 < 8) {
      int k0 = (t + 1) << 4;
      if (tid < 128) {
        size_t o = (size_t)(rowBase + arow) * 128 + k0 + aq;
        p0 = *(const float4*)(P + o);
        p1 = *(const float4*)(P + PS + o);
        p2 = *(const float4*)(P + 2 * PS + o);
        p3 = *(const float4*)(P + 3 * PS + o);
        s4 = *(const float4*)(sc + k0 + aq);
        b4 = *(const float4*)(bb + k0 + aq);
      }
      pb0 = *(const float4*)(W + (size_t)(k0 + bk) * 128 + bc);
      pb1 = *(const float4*)(W + (size_t)(k0 + bk + 8) * 128 + bc);
    }
#pragma unroll
    for (int kk = 0; kk < 16; ++kk) {
      float a[4];
      v2f bv[2];
      *(float4*)&a[0] = *(const float4*)&As[kk][ty * 4];
      *(float4*)&bv[0] = *(const float4*)&Bs[kk][tx * 4];
#pragma unroll
      for (int r = 0; r < 4; ++r)
#pragma unroll
        for (int c = 0; c < 2; ++c) acc[r][c] += a[r] * bv[c];
    }
    __syncthreads();
  }
  // epilogue: X0 write + LN1 per row (butterfly over 32 tx lanes)
  float4 g4 = *(const float4*)(g + tx * 4);
  float4 be4 = *(const float4*)(be + tx * 4);
#pragma unroll
  for (int r = 0; r < 4; ++r) {
    int row = rowBase + ty * 4 + r;
    int col = tx * 4;
    float av[4];
    *(v2f*)&av[0] = acc[r][0];
    *(v2f*)&av[2] = acc[r][1];
    float4 v;
    v.x = av[0] + bias[col + 0];
    v.y = av[1] + bias[col + 1];
    v.z = av[2] + bias[col + 2];
    v.w = av[3] + bias[col + 3];
    *(float4*)&C[(size_t)row * 128 + col] = v;
    float s = ((v.x + v.y) + (v.z + v.w));
    for (int off = 16; off >= 1; off >>= 1) s += __shfl_xor(s, off, 64);
    float mean = s / 128.0f;
    float d0 = v.x - mean, d1 = v.y - mean, d2 = v.z - mean, d3 = v.w - mean;
    float q = ((d0 * d0 + d1 * d1) + (d2 * d2 + d3 * d3));
    for (int off = 16; off >= 1; off >>= 1) q += __shfl_xor(q, off, 64);
    float rs = rsqrtf(q / 128.0f + EPSV);
    float4 w;
    w.x = d0 * rs * g4.x + be4.x;
    w.y = d1 * rs * g4.y + be4.y;
    w.z = d2 * rs * g4.z + be4.z;
    w.w = d3 * rs * g4.w + be4.w;
    *(float4*)&xn[(size_t)row * 128 + col] = w;
  }
}

// ---------------- preconv2 with fused 4-partial combine (fallback, no LN) ------
__global__ __launch_bounds__(256) void gemm_psum4_kernel(
    const float* __restrict__ P, const float* __restrict__ sc,
    const float* __restrict__ bb, const float* __restrict__ W,
    const float* __restrict__ bias, float* __restrict__ C, int M) {
  __shared__ float As[16][36];
  __shared__ float Bs[16][132];
  int tid = threadIdx.x;
  int tx = tid & 31;
  int ty = tid >> 5;
  int rowBase = blockIdx.y * 32;
  v2f acc[4][2] = {};
  const size_t PS = (size_t)M * 128;

  int arow = tid >> 2, aq = (tid & 3) * 4;
  int bk = tid >> 5, bc = (tid & 31) * 4;

  float4 p0, p1, p2, p3, s4, b4, pb0, pb1;
  {
    if (tid < 128) {
      size_t o = (size_t)(rowBase + arow) * 128 + aq;
      p0 = *(const float4*)(P + o);
      p1 = *(const float4*)(P + PS + o);
      p2 = *(const float4*)(P + 2 * PS + o);
      p3 = *(const float4*)(P + 3 * PS + o);
      s4 = *(const float4*)(sc + aq);
      b4 = *(const float4*)(bb + aq);
    }
    pb0 = *(const float4*)(W + (size_t)bk * 128 + bc);
    pb1 = *(const float4*)(W + (size_t)(bk + 8) * 128 + bc);
  }
  for (int t = 0; t < 8; ++t) {
    if (tid < 128) {
      As[aq + 0][arow] = fmaxf((((p0.x + p1.x) + p2.x) + p3.x) * s4.x + b4.x, 0.0f);
      As[aq + 1][arow] = fmaxf((((p0.y + p1.y) + p2.y) + p3.y) * s4.y + b4.y, 0.0f);
      As[aq + 2][arow] = fmaxf((((p0.z + p1.z) + p2.z) + p3.z) * s4.z + b4.z, 0.0f);
      As[aq + 3][arow] = fmaxf((((p0.w + p1.w) + p2.w) + p3.w) * s4.w + b4.w, 0.0f);
    }
    *(float4*)&Bs[bk][bc] = pb0;
    *(float4*)&Bs[bk + 8][bc] = pb1;
    __syncthreads();
    if (t + 1 < 8) {
      int k0 = (t + 1) << 4;
      if (tid < 128) {
        size_t o = (size_t)(rowBase + arow) * 128 + k0 + aq;
        p0 = *(const float4*)(P + o);
        p1 = *(const float4*)(P + PS + o);
        p2 = *(const float4*)(P + 2 * PS + o);
        p3 = *(const float4*)(P + 3 * PS + o);
        s4 = *(const float4*)(sc + k0 + aq);
        b4 = *(const float4*)(bb + k0 + aq);
      }
      pb0 = *(const float4*)(W + (size_t)(k0 + bk) * 128 + bc);
      pb1 = *(const float4*)(W + (size_t)(k0 + bk + 8) * 128 + bc);
    }
#pragma unroll
    for (int kk = 0; kk < 16; ++kk) {
      float a[4];
      v2f bv[2];
      *(float4*)&a[0] = *(const float4*)&As[kk][ty * 4];
      *(float4*)&bv[0] = *(const float4*)&Bs[kk][tx * 4];
#pragma unroll
      for (int r = 0; r < 4; ++r)
#pragma unroll
        for (int c = 0; c < 2; ++c) acc[r][c] += a[r] * bv[c];
    }
    __syncthreads();
  }
#pragma unroll
  for (int r = 0; r < 4; ++r) {
    int row = rowBase + ty * 4 + r;
    int col = tx * 4;
    float av[4];
    *(v2f*)&av[0] = acc[r][0];
    *(v2f*)&av[2] = acc[r][1];
    float4 v;
    v.x = av[0] + bias[col + 0];
    v.y = av[1] + bias[col + 1];
    v.z = av[2] + bias[col + 2];
    v.w = av[3] + bias[col + 3];
    *(float4*)&C[(size_t)row * 128 + col] = v;
  }
}

// ---------------- Wg GEMM with fused h-combine (fallback) ----------------------
__global__ __launch_bounds__(256) void gemm_hsum_kernel(
    const float* __restrict__ P0, const float* __restrict__ P1,
    const float* __restrict__ hbias, const float* __restrict__ W,
    const float* __restrict__ bias, float* __restrict__ C, int M) {
  __shared__ float As[16][36];
  __shared__ float Bs[16][132];
  int tid = threadIdx.x;
  int tx = tid & 31;
  int ty = tid >> 5;
  int rowBase = blockIdx.y * 32;
  v2f acc[4][2] = {};

  int arow = tid >> 2, aq = (tid & 3) * 4;
  int bk = tid >> 5, bc = (tid & 31) * 4;

  float4 pq0, pq1, pb0, pb1, hb;
  {
    if (tid < 128) {
      size_t o = (size_t)(rowBase + arow) * 512 + aq;
      pq0 = *(const float4*)(P0 + o);
      pq1 = *(const float4*)(P1 + o);
      hb = *(const float4*)(hbias + aq);
    }
    pb0 = *(const float4*)(W + (size_t)bk * 128 + bc);
    pb1 = *(const float4*)(W + (size_t)(bk + 8) * 128 + bc);
  }
  for (int t = 0; t < 32; ++t) {
    if (tid < 128) {
      As[aq + 0][arow] = fmaxf(pq0.x + pq1.x + hb.x, 0.0f);
      As[aq + 1][arow] = fmaxf(pq0.y + pq1.y + hb.y, 0.0f);
      As[aq + 2][arow] = fmaxf(pq0.z + pq1.z + hb.z, 0.0f);
      As[aq + 3][arow] = fmaxf(pq0.w + pq1.w + hb.w, 0.0f);
    }
    *(float4*)&Bs[bk][bc] = pb0;
    *(float4*)&Bs[bk + 8][bc] = pb1;
    __syncthreads();
    if (t + 1 < 32) {
      int k0 = (t + 1) << 4;
      if (tid < 128) {
        size_t o = (size_t)(rowBase + arow) * 512 + k0 + aq;
        pq0 = *(const float4*)(P0 + o);
        pq1 = *(const float4*)(P1 + o);
        hb = *(const float4*)(hbias + k0 + aq);
      }
      pb0 = *(const float4*)(W + (size_t)(k0 + bk) * 128 + bc);
      pb1 = *(const float4*)(W + (size_t)(k0 + bk + 8) * 128 + bc);
    }
#pragma unroll
    for (int kk = 0; kk < 16; ++kk) {
      float a[4];
      v2f bv[2];
      *(float4*)&a[0] = *(const float4*)&As[kk][ty * 4];
      *(float4*)&bv[0] = *(const float4*)&Bs[kk][tx * 4];
#pragma unroll
      for (int r = 0; r < 4; ++r)
#pragma unroll
        for (int c = 0; c < 2; ++c) acc[r][c] += a[r] * bv[c];
    }
    __syncthreads();
  }
#pragma unroll
  for (int r = 0; r < 4; ++r) {
    int row = rowBase + ty * 4 + r;
    int col = tx * 4;
    float av[4];
    *(v2f*)&av[0] = acc[r][0];
    *(v2f*)&av[2] = acc[r][1];
    size_t o = (size_t)row * 128 + col;
    float4 old = *(float4*)&C[o];
    float4 v;
    v.x = av[0] + bias[col + 0] + old.x;
    v.y = av[1] + bias[col + 1] + old.y;
    v.z = av[2] + bias[col + 2] + old.z;
    v.w = av[3] + bias[col + 3] + old.w;
    *(float4*)&C[o] = v;
  }
}

// ---------------- fp32 GEMM, 128x128 tile (generic) ----------------------------
__global__ __launch_bounds__(256) void gemm128_kernel(
    const float* __restrict__ A, const float* __restrict__ W,
    const float* __restrict__ A2, const float* __restrict__ W2,
    const float* __restrict__ bias, float* __restrict__ C,
    int M, int N, int K, int flags) {
  __shared__ float As[16][132];
  __shared__ float Bs[16][132];
  int tid = threadIdx.x;
  int tx = tid & 15;
  int ty = tid >> 4;
  int colBase = blockIdx.x * 128, rowBase = blockIdx.y * 128;
  v2f acc[8][4] = {};
  int ktiles = K >> 4;
  int total = (A2 ? 2 : 1) * ktiles;

  int arow = tid >> 1, aq = (tid & 1) * 8;
  int bk = tid >> 4, bq4 = (tid & 15) * 4;

  float4 pa0, pa1, pb0, pb1;
  {
    const float* ap = A + (size_t)(rowBase + arow) * K + aq;
    pa0 = *(const float4*)ap;
    pa1 = *(const float4*)(ap + 4);
    const float* bp = W + (size_t)bk * N + colBase;
    pb0 = *(const float4*)(bp + bq4);
    pb1 = *(const float4*)(bp + 64 + bq4);
  }
  for (int t = 0; t < total; ++t) {
    As[aq + 0][arow] = pa0.x; As[aq + 1][arow] = pa0.y;
    As[aq + 2][arow] = pa0.z; As[aq + 3][arow] = pa0.w;
    As[aq + 4][arow] = pa1.x; As[aq + 5][arow] = pa1.y;
    As[aq + 6][arow] = pa1.z; As[aq + 7][arow] = pa1.w;
    *(float4*)&Bs[bk][bq4] = pb0;
    *(float4*)&Bs[bk][64 + bq4] = pb1;
    __syncthreads();
    if (t + 1 < total) {
      int tn = t + 1;
      const float* Ap = (tn >= ktiles) ? A2 : A;
      const float* Wp = (tn >= ktiles) ? W2 : W;
      int k0 = ((tn >= ktiles) ? tn - ktiles : tn) << 4;
      const float* ap = Ap + (size_t)(rowBase + arow) * K + k0 + aq;
      pa0 = *(const float4*)ap;
      pa1 = *(const float4*)(ap + 4);
      const float* bp = Wp + (size_t)(k0 + bk) * N + colBase;
      pb0 = *(const float4*)(bp + bq4);
      pb1 = *(const float4*)(bp + 64 + bq4);
    }
#pragma unroll
    for (int kk = 0; kk < 16; ++kk) {
      float a[8];
      v2f bv[4];
      *(float4*)&a[0] = *(const float4*)&As[kk][ty * 8];
      *(float4*)&a[4] = *(const float4*)&As[kk][ty * 8 + 4];
      *(float4*)&bv[0] = *(const float4*)&Bs[kk][tx * 4];
      *(float4*)&bv[2] = *(const float4*)&Bs[kk][64 + tx * 4];
#pragma unroll
      for (int r = 0; r < 8; ++r)
#pragma unroll
        for (int c = 0; c < 4; ++c) acc[r][c] += a[r] * bv[c];
    }
    __syncthreads();
  }
#pragma unroll
  for (int r = 0; r < 8; ++r) {
    int row = rowBase + ty * 8 + r;
#pragma unroll
    for (int h = 0; h < 2; ++h) {
      int col = colBase + h * 64 + tx * 4;
      float av[4];
      *(v2f*)&av[0] = acc[r][h * 2 + 0];
      *(v2f*)&av[2] = acc[r][h * 2 + 1];
      float4 v;
      float* vp = (float*)&v;
#pragma unroll
      for (int c = 0; c < 4; ++c) {
        float t = av[c];
        if (bias) t += bias[col + c];
        if (flags & GF_RELU) t = fmaxf(t, 0.0f);
        vp[c] = t;
      }
      size_t o = (size_t)row * N + col;
      if (flags & GF_ACCUM) {
        float4 old = *(float4*)&C[o];
        v.x += old.x; v.y += old.y; v.z += old.z; v.w += old.w;
      }
      *(float4*)&C[o] = v;
    }
  }
}

// ---------------- fused FFN: x += relu(xn2@W1 + b1) @ W2 + b2 ------------------
__global__ __launch_bounds__(256) void ffn_fused_kernel(
    const float* __restrict__ xn, const float* __restrict__ W1,
    const float* __restrict__ b1, const float* __restrict__ W2,
    const float* __restrict__ b2, float* __restrict__ x) {
  __shared__ float Axn[128 * 36];
  __shared__ float Hs [128 * 36];
  __shared__ float Bs [16 * 132];
  int tid = threadIdx.x;
  int rowBase = blockIdx.x * 32;
  int tx = tid & 31, ty = tid >> 5;
  {
    int row = tid >> 3, ks = (tid & 7) * 16;
    const float* s1 = xn + (size_t)(rowBase + row) * 128 + ks;
#pragma unroll
    for (int q = 0; q < 4; ++q) {
      float4 v = *(const float4*)(s1 + q * 4);
      int k = ks + q * 4;
      Axn[(k + 0) * 36 + row] = v.x; Axn[(k + 1) * 36 + row] = v.y;
      Axn[(k + 2) * 36 + row] = v.z; Axn[(k + 3) * 36 + row] = v.w;
    }
  }
  int bk = tid >> 4, bc = (tid & 15) * 8;
  v2f hacc[4][2] = {};
  {
    float4 p0 = *(const float4*)(W1 + (size_t)bk * 128 + bc);
    float4 p1 = *(const float4*)(W1 + (size_t)bk * 128 + bc + 4);
    for (int kt = 0; kt < 8; ++kt) {
      __syncthreads();
      *(float4*)&Bs[bk * 132 + bc] = p0;
      *(float4*)&Bs[bk * 132 + bc + 4] = p1;
      __syncthreads();
      if (kt < 7) {
        p0 = *(const float4*)(W1 + (size_t)(kt * 16 + 16 + bk) * 128 + bc);
        p1 = *(const float4*)(W1 + (size_t)(kt * 16 + 16 + bk) * 128 + bc + 4);
      }
      int k0 = kt * 16;
#pragma unroll
      for (int kk = 0; kk < 16; ++kk) {
        float av[4];
        v2f bv[2];
        *(float4*)av = *(const float4*)&Axn[(k0 + kk) * 36 + ty * 4];
        *(float4*)&bv[0] = *(const float4*)&Bs[kk * 132 + tx * 4];
#pragma unroll
        for (int r = 0; r < 4; ++r)
#pragma unroll
          for (int c = 0; c < 2; ++c) hacc[r][c] += av[r] * bv[c];
      }
    }
  }
  __syncthreads();
#pragma unroll
  for (int r = 0; r < 4; ++r) {
    float hv[4];
    *(v2f*)&hv[0] = hacc[r][0];
    *(v2f*)&hv[2] = hacc[r][1];
#pragma unroll
    for (int c = 0; c < 4; ++c) {
      float v = hv[c] + b1[tx * 4 + c];
      v = fmaxf(v, 0.0f);
      Hs[(tx * 4 + c) * 36 + ty * 4 + r] = v;
    }
  }
  v2f oacc[4][2] = {};
  {
    float4 q0 = *(const float4*)(W2 + (size_t)bk * 128 + bc);
    float4 q1 = *(const float4*)(W2 + (size_t)bk * 128 + bc + 4);
    for (int kt = 0; kt < 8; ++kt) {
      __syncthreads();
      *(float4*)&Bs[bk * 132 + bc] = q0;
      *(float4*)&Bs[bk * 132 + bc + 4] = q1;
      __syncthreads();
      if (kt < 7) {
        q0 = *(const float4*)(W2 + (size_t)(kt * 16 + 16 + bk) * 128 + bc);
        q1 = *(const float4*)(W2 + (size_t)(kt * 16 + 16 + bk) * 128 + bc + 4);
      }
      int k0 = kt * 16;
#pragma unroll
      for (int kk = 0; kk < 16; ++kk) {
        float av[4];
        v2f bv[2];
        *(float4*)av = *(const float4*)&Hs[(k0 + kk) * 36 + ty * 4];
        *(float4*)&bv[0] = *(const float4*)&Bs[kk * 132 + tx * 4];
#pragma unroll
        for (int r = 0; r < 4; ++r)
#pragma unroll
          for (int c = 0; c < 2; ++c) oacc[r][c] += av[r] * bv[c];
      }
    }
  }
#pragma unroll
  for (int r = 0; r < 4; ++r) {
    int row = rowBase + ty * 4 + r;
    float ov[4];
    *(v2f*)&ov[0] = oacc[r][0];
    *(v2f*)&ov[2] = oacc[r][1];
    float4 old = *(float4*)&x[(size_t)row * 128 + tx * 4];
    float4 v;
    v.x = ov[0] + b2[tx * 4 + 0]; v.x += old.x;
    v.y = ov[1] + b2[tx * 4 + 1]; v.y += old.y;
    v.z = ov[2] + b2[tx * 4 + 2]; v.z += old.z;
    v.w = ov[3] + b2[tx * 4 + 3]; v.w += old.w;
    *(float4*)&x[(size_t)row * 128 + tx * 4] = v;
  }
}

// ---------------- q = x@Wq ; p = dinv*q ---------------------------------------
__global__ void qp_kernel(const float* __restrict__ x, const float* __restrict__ Wq,
                          const float* __restrict__ dinv, float* __restrict__ p, int Ni) {
  int node = blockIdx.x;
  int lane = threadIdx.x;
  int b = node / Ni, i = node % Ni;
  float v = x[(size_t)node * 128 + lane] * Wq[lane] +
            x[(size_t)node * 128 + 64 + lane] * Wq[64 + lane];
  for (int off = 32; off >= 1; off >>= 1) v += __shfl_xor(v, off, 64);
  if (lane == 0) p[b * Nmax + i] = dinv[b * Nmax + i] * v;
}

// ---------------- s = dinv * (A @ p) + bq -------------------------------------
__global__ void score_kernel(const u32* __restrict__ adj, const float* __restrict__ p,
                             const float* __restrict__ dinv, const float* __restrict__ bq,
                             float* __restrict__ s, int Ni) {
  int i = blockIdx.x, b = blockIdx.y, lane = threadIdx.x;
  int wpr = Ni >> 5;
  float acc = 0.0f;
  if (lane < wpr) {
    u32 bits = adj[((size_t)(b * Nmax + i)) * 64 + lane];
    while (bits) {
      int bit = __ffs(bits) - 1;
      bits &= bits - 1;
      acc += p[b * Nmax + (lane << 5) + bit];
    }
  }
  for (int off = 32; off >= 1; off >>= 1) acc += __shfl_xor(acc, off, 64);
  if (lane == 0) s[b * Nmax + i] = dinv[b * Nmax + i] * acc + bq[0];
}

// ---------------- top-k via exact rank counting --------------------------------
__global__ void topk_rank_kernel(const float* __restrict__ s, int Ni, int* __restrict__ topi) {
  int b = blockIdx.y;
  int e0 = blockIdx.x * 256;
  int t = threadIdx.x;
  __shared__ u64 keys[2048];
  for (int e = t; e < Ni; e += 256) {
    u32 u = __float_as_uint(s[b * Nmax + e]);
    u32 mono = (u & 0x80000000u) ? ~u : (u | 0x80000000u);
    keys[e] = ((u64)(~mono) << 32) | (u32)e;
  }
  __syncthreads();
  int e = e0 + t;
  if (e >= Ni) return;
  u64 my = keys[e];
  int rank = 0;
  for (int q = 0; q < Ni; ++q) rank += (keys[q] < my) ? 1 : 0;
  int kkeep = Ni >> 1;
  if (rank < kkeep) topi[b * 1024 + rank] = e;
}

// ---------------- gather + tanh gate + optional fused LN1 ----------------------
// 64 threads; lane holds cols (lane, lane+64). If g!=nullptr also writes
// xn = LN(xo_row)*g+be for the next layer.
__global__ __launch_bounds__(64) void gather_kernel(
    const float* __restrict__ x, const float* __restrict__ c,
    const float* __restrict__ s, const int* __restrict__ topi,
    float* __restrict__ xo, float* __restrict__ co,
    const float* __restrict__ g, const float* __restrict__ be,
    float* __restrict__ xn, int Ni) {
  int inew = blockIdx.x, b = blockIdx.y, lane = threadIdx.x;
  int kkeep = Ni >> 1;
  int old = topi[b * 1024 + inew];
  float gate = tanhf(s[b * Nmax + old]);
  size_t ri = ((size_t)b * Ni + old) * 128;
  size_t ro = ((size_t)b * kkeep + inew) * 128;
  float v1 = x[ri + lane] * gate;
  float v2 = x[ri + 64 + lane] * gate;
  xo[ro + lane] = v1;
  xo[ro + 64 + lane] = v2;
  if (lane < 2) co[((size_t)b * kkeep + inew) * 2 + lane] = c[((size_t)b * Ni + old) * 2 + lane];
  if (g) {
    float sm = v1 + v2;
    for (int off = 32; off >= 1; off >>= 1) sm += __shfl_xor(sm, off, 64);
    float mean = sm / 128.0f;
    float d1 = v1 - mean, d2 = v2 - mean;
    float q = d1 * d1 + d2 * d2;
    for (int off = 32; off >= 1; off >>= 1) q += __shfl_xor(q, off, 64);
    float rs = rsqrtf(q / 128.0f + EPSV);
    xn[ro + lane] = d1 * rs * g[lane] + be[lane];
    xn[ro + 64 + lane] = d2 * rs * g[lane + 64] + be[lane + 64];
  }
}

// ---------------- picks: two-stage [max ; mean] reduction ----------------------
__global__ void picks_partial_kernel(const float* __restrict__ x, float* __restrict__ part,
                                     int kkeep, int G) {
  int b = blockIdx.x, g = blockIdx.y, t = threadIdx.x;
  int per = kkeep / G;
  int start = g * per;
  float mx = -INFINITY, sm = 0.0f;
  for (int i = start; i < start + per; ++i) {
    float v = x[((size_t)b * kkeep + i) * 128 + t];
    mx = fmaxf(mx, v);
    sm += v;
  }
  part[((size_t)(b * G + g)) * 256 + t] = mx;
  part[((size_t)(b * G + g)) * 256 + 128 + t] = sm;
}

__global__ void picks_combine_kernel(const float* __restrict__ part, float* __restrict__ picks,
                                     int kkeep, int G) {
  int b = blockIdx.x, t = threadIdx.x;
  float mx = -INFINITY, sm = 0.0f;
  for (int g = 0; g < G; ++g) {
    mx = fmaxf(mx, part[((size_t)(b * G + g)) * 256 + t]);
    sm += part[((size_t)(b * G + g)) * 256 + 128 + t];
  }
  picks[b * 256 + t] += mx;
  picks[b * 256 + 128 + t] += sm / (float)kkeep;
}

// ---------------- final 2-layer MLP -------------------------------------------
__global__ void final_kernel(const float* __restrict__ picks, const float* __restrict__ Wf1,
                             const float* __restrict__ bf1, const float* __restrict__ Wf2,
                             const float* __restrict__ bf2, float* __restrict__ out) {
  int b = blockIdx.x, t = threadIdx.x;
  __shared__ float pk[256];
  __shared__ float fm[128];
  pk[t] = picks[b * 256 + t];
  pk[t + 128] = picks[b * 256 + 128 + t];
  __syncthreads();
  float acc = bf1[t];
  for (int k = 0; k < 256; ++k) acc += pk[k] * Wf1[k * 128 + t];
  fm[t] = fmaxf(acc, 0.0f);
  __syncthreads();
  if (t < 32) {
    float a2 = bf2[t];
    for (int k = 0; k < 128; ++k) a2 += fm[k] * Wf2[k * 32 + t];
    out[b * 32 + t] = fmaxf(a2, 0.0f);
  }
}

extern "C" void kernel_launch(void* const* d_in, const int* in_sizes, int n_in,
                              void* d_out, int out_size, void* d_ws, size_t ws_size,
                              hipStream_t stream) {
  const float* feats = (const float*)d_in[0];
  const float* cent  = (const float*)d_in[1];
  const float* Wp1 = (const float*)d_in[2];
  const float* bp1 = (const float*)d_in[3];
  const float* bn_g = (const float*)d_in[4];
  const float* bn_b = (const float*)d_in[5];
  const float* Wp2 = (const float*)d_in[6];
  const float* bp2 = (const float*)d_in[7];
  const float* g1  = (const float*)d_in[8];
  const float* be1 = (const float*)d_in[9];
  const float* g2  = (const float*)d_in[10];
  const float* be2 = (const float*)d_in[11];
  const float* Ws  = (const float*)d_in[12];
  const float* Wn  = (const float*)d_in[13];
  const float* bs  = (const float*)d_in[14];
  const float* Wg  = (const float*)d_in[15];
  const float* bg  = (const float*)d_in[16];
  const float* W1  = (const float*)d_in[17];
  const float* b1  = (const float*)d_in[18];
  const float* W2  = (const float*)d_in[19];
  const float* b2  = (const float*)d_in[20];
  const float* Wq  = (const float*)d_in[21];
  const float* bq  = (const float*)d_in[22];
  const float* Wf1 = (const float*)d_in[23];
  const float* bf1 = (const float*)d_in[24];
  const float* Wf2 = (const float*)d_in[25];
  const float* bf2 = (const float*)d_in[26];
  float* out = (float*)d_out;

  float* p = (float*)d_ws;
  const size_t SZX = (size_t)Bn * Nmax * 128;
  float* SC = p;    p += 128;
  float* BBv = p;   p += 128;
  float* DINV = p;  p += Bn * Nmax;
  float* PV = p;    p += Bn * Nmax;
  float* SS = p;    p += Bn * Nmax;
  float* PICKS = p; p += Bn * 256;
  float* PART = p;  p += (size_t)Bn * 32 * 256;
  float* C0 = p;    p += (size_t)Bn * Nmax * 2;
  float* C1 = p;    p += (size_t)Bn * Nmax * 2;
  int* KNN = (int*)p;  p += (size_t)Bn * Nmax * KNN_K;
  int* TOPI = (int*)p; p += Bn * 1024;
  u32* ADJ = (u32*)p;  p += (size_t)Bn * Nmax * 64;
  float* X0 = p;    p += SZX;
  float* X1 = p;    p += SZX;
  float* BA = p;    p += SZX;
  float* BB = p;    p += SZX;
  float* HB = p;    // h partial 0 / preconv partials: 4*SZX
  size_t base_floats = (size_t)(p - (float*)d_ws);
  const size_t WPSZ = (size_t)3 * 128 * 512;
  bool fused = ws_size >= (base_floats + 4 * SZX + 2 * WPSZ) * sizeof(float);
  float* WSP = HB + 4 * SZX;
  float* WNP = WSP + WPSZ;
  float* PK = WNP + WPSZ;      // h partial 1: 4*SZX
  float* QD = PK + 4 * SZX;    // Wg partial slice 3: 1*SZX
  bool fused2 = ws_size >= (base_floats + 8 * SZX + 2 * WPSZ) * sizeof(float);
  bool fused3 = ws_size >= (base_floats + 9 * SZX + 2 * WPSZ) * sizeof(float);

  hipLaunchKernelGGL(precompute_kernel, dim3(1), dim3(256), 0, stream,
                     bn_g, bn_b, bp1, SC, BBv, PICKS);
  if (fused) {
    hipLaunchKernelGGL(repack_ws_kernel, dim3(768), dim3(256), 0, stream, Ws, Wn, WSP, WNP);
  }

  // ---- preconv ----
  const int M0 = Bn * Nmax;
  if (fused3) {
    hipLaunchKernelGGL(gemm128ks_kernel, dim3(1, M0 / 128, 4), dim3(256), 0, stream,
                       feats, Wp1, HB, M0, 512);
    hipLaunchKernelGGL(gemm_psum4_ln_kernel, dim3(1, M0 / 32), dim3(256), 0, stream,
                       HB, SC, BBv, Wp2, bp2, g1, be1, X0, BA, M0);
  } else if (fused) {
    hipLaunchKernelGGL(gemm128ks_kernel, dim3(1, M0 / 128, 4), dim3(256), 0, stream,
                       feats, Wp1, HB, M0, 512);
    hipLaunchKernelGGL(gemm_psum4_kernel, dim3(1, M0 / 32), dim3(256), 0, stream,
                       HB, SC, BBv, Wp2, bp2, X0, M0);
  } else {
    hipLaunchKernelGGL(gemm_kernel<32>, dim3(1, M0 / 32), dim3(256), 0, stream,
                       feats, Wp1, (const float*)nullptr, (const float*)nullptr,
                       SC, BBv, BA, M0, 128, 512, GF_RELU);
    hipLaunchKernelGGL(gemm_kernel<32>, dim3(1, M0 / 32), dim3(256), 0, stream,
                       BA, Wp2, (const float*)nullptr, (const float*)nullptr,
                       (const float*)nullptr, bp2, X0, M0, 128, 128, 0);
  }

  float* xc = X0;
  float* xo = X1;
  const float* cc = cent;
  float* co = C0;
  int Ni = Nmax;
  for (int L = 0; L < 3; ++L) {
    int M = Bn * Ni;
    if (Ni == 2048)      hipLaunchKernelGGL(knn_sel_kernel<32>, dim3(Ni, Bn), dim3(64), 0, stream, cc, KNN, Ni);
    else if (Ni == 1024) hipLaunchKernelGGL(knn_sel_kernel<16>, dim3(Ni, Bn), dim3(64), 0, stream, cc, KNN, Ni);
    else                 hipLaunchKernelGGL(knn_sel_kernel<8>,  dim3(Ni, Bn), dim3(64), 0, stream, cc, KNN, Ni);
    hipMemsetAsync(ADJ, 0, (size_t)Bn * Nmax * 64 * sizeof(u32), stream);
    int tot = Bn * Ni * KNN_K;
    hipLaunchKernelGGL(build_adj_kernel, dim3((tot + 255) / 256), dim3(256), 0, stream,
                       KNN, ADJ, Ni);
    if (!fused3) {
      hipLaunchKernelGGL(layernorm_kernel, dim3(M / 4), dim3(256), 0, stream,
                         xc, g1 + L * 128, be1 + L * 128, BA);
    }
    hipLaunchKernelGGL(aggregate_kernel, dim3(Ni, Bn), dim3(128), Ni * sizeof(int), stream,
                       ADJ, BA, BB, DINV, Ni);
    if (fused3) {
      hipLaunchKernelGGL(gemm128dual_kernel, dim3(4, M / 128, 2), dim3(256), 0, stream,
                         BA, WSP + (size_t)L * 128 * 512,
                         BB, WNP + (size_t)L * 128 * 512,
                         HB, PK, M, 512);
      // Wg 128-tile K-sliced, fused h-combine; partials to BA, BB, xo, QD
      hipLaunchKernelGGL(gemm128hsum_kernel, dim3(1, M / 128, 4), dim3(256), 0, stream,
                         HB, PK, bs + L * 512, Wg + (size_t)L * 512 * 128,
                         BA, BB, xo, QD, M);
      // x += sum(Q) + bg ; BA = LN2(x)
      hipLaunchKernelGGL(combine_ln_kernel, dim3(M / 4), dim3(256), 0, stream,
                         BA, BB, xo, QD, bg + L * 128, g2 + L * 128, be2 + L * 128,
                         xc, BA);
    } else if (fused2) {
      hipLaunchKernelGGL(gemm128dual_kernel, dim3(4, M / 128, 2), dim3(256), 0, stream,
                         BA, WSP + (size_t)L * 128 * 512,
                         BB, WNP + (size_t)L * 128 * 512,
                         HB, PK, M, 512);
      hipLaunchKernelGGL(gemm_hsum_kernel, dim3(1, M / 32), dim3(256), 0, stream,
                         HB, PK, bs + L * 512, Wg + (size_t)L * 512 * 128,
                         bg + L * 128, xc, M);
      hipLaunchKernelGGL(layernorm_kernel, dim3(M / 4), dim3(256), 0, stream,
                         xc, g2 + L * 128, be2 + L * 128, BA);
    } else if (fused) {
      hipLaunchKernelGGL(gemm128_kernel, dim3(4, M / 128), dim3(256), 0, stream,
                         BA, WSP + (size_t)L * 128 * 512,
                         BB, WNP + (size_t)L * 128 * 512,
                         bs + L * 512, HB, M, 512, 128, GF_RELU);
      hipLaunchKernelGGL(gemm_kernel<32>, dim3(1, M / 32), dim3(256), 0, stream,
                         HB, Wg + (size_t)L * 512 * 128,
                         (const float*)nullptr, (const float*)nullptr,
                         (const float*)nullptr, bg + L * 128,
                         xc, M, 128, 512, GF_ACCUM);
      hipLaunchKernelGGL(layernorm_kernel, dim3(M / 4), dim3(256), 0, stream,
                         xc, g2 + L * 128, be2 + L * 128, BA);
    } else {
      for (int hh = 0; hh < 4; ++hh) {
        hipLaunchKernelGGL(gemm_kernel<32>, dim3(1, M / 32), dim3(256), 0, stream,
                           BA, Ws + ((size_t)(L * 4 + hh)) * 128 * 128,
                           BB, Wn + ((size_t)(L * 4 + hh)) * 128 * 128,
                           (const float*)nullptr, bs + (L * 4 + hh) * 128,
                           HB, M, 128, 128, GF_RELU);
        hipLaunchKernelGGL(gemm_kernel<32>, dim3(1, M / 32), dim3(256), 0, stream,
                           HB, Wg + ((size_t)L * 512 + hh * 128) * 128,
                           (const float*)nullptr, (const float*)nullptr,
                           (const float*)nullptr, (hh == 0) ? (bg + L * 128) : (const float*)nullptr,
                           xc, M, 128, 128, GF_ACCUM);
      }
      hipLaunchKernelGGL(layernorm_kernel, dim3(M / 4), dim3(256), 0, stream,
                         xc, g2 + L * 128, be2 + L * 128, BA);
    }
    hipLaunchKernelGGL(ffn_fused_kernel, dim3(M / 32), dim3(256), 0, stream,
                       BA, W1 + (size_t)L * 128 * 128, b1 + L * 128,
                       W2 + (size_t)L * 128 * 128, b2 + L * 128, xc);
    hipLaunchKernelGGL(qp_kernel, dim3(M), dim3(64), 0, stream, xc, Wq + L * 128, DINV, PV, Ni);
    hipLaunchKernelGGL(score_kernel, dim3(Ni, Bn), dim3(64), 0, stream, ADJ, PV, DINV, bq + L, SS, Ni);
    hipLaunchKernelGGL(topk_rank_kernel, dim3((Ni + 255) / 256, Bn), dim3(256), 0, stream,
                       SS, Ni, TOPI);
    int kkeep = Ni >> 1;
    // gather + (fused3: LN1 for next layer, except after last layer)
    const float* gn = (fused3 && L < 2) ? (g1 + (L + 1) * 128) : (const float*)nullptr;
    const float* bn = (fused3 && L < 2) ? (be1 + (L + 1) * 128) : (const float*)nullptr;
    hipLaunchKernelGGL(gather_kernel, dim3(kkeep, Bn), dim3(64), 0, stream,
                       xc, cc, SS, TOPI, xo, co, gn, bn, BA, Ni);
    int G = kkeep / 32;
    hipLaunchKernelGGL(picks_partial_kernel, dim3(Bn, G), dim3(128), 0, stream,
                       xo, PART, kkeep, G);
    hipLaunchKernelGGL(picks_combine_kernel, dim3(Bn), dim3(128), 0, stream,
                       PART, PICKS, kkeep, G);
    float* tmp = xc; xc = xo; xo = tmp;
    cc = co;
    co = (co == C0) ? C1 : C0;
    Ni = kkeep;
  }
  hipLaunchKernelGGL(final_kernel, dim3(Bn), dim3(128), 0, stream,
                     PICKS, Wf1, bf1, Wf2, bf2, out);
}

// Round 14
// 677.574 us; speedup vs baseline: 1.1120x; 1.0180x over previous
//
#include <hip/hip_runtime.h>
#include <math.h>

#define EPSV 1e-5f
#define GF_RELU 1
#define GF_ACCUM 2

typedef unsigned long long u64;
typedef unsigned int u32;
typedef float v2f __attribute__((ext_vector_type(2)));

static const int Bn = 8;
static const int Nmax = 2048;
static const int KNN_K = 8;

// ---------------- precompute: fold BN into scale/bias, zero picks ----------------
__global__ void precompute_kernel(const float* __restrict__ bn_g, const float* __restrict__ bn_b,
                                  const float* __restrict__ bp1,
                                  float* __restrict__ sc, float* __restrict__ bb,
                                  float* __restrict__ picks) {
  int t = threadIdx.x;
  if (t < 128) {
    float s = bn_g[t] / sqrtf(1.0f + EPSV);
    sc[t] = s;
    bb[t] = bp1[t] * s + bn_b[t];
  }
  for (int i = t; i < Bn * 256; i += blockDim.x) picks[i] = 0.0f;
}

// ---------------- repack Ws/Wn [L][h][d][e] -> [L][d][h*128+e] -----------------
__global__ void repack_ws_kernel(const float* __restrict__ Ws, const float* __restrict__ Wn,
                                 float* __restrict__ WsP, float* __restrict__ WnP) {
  int idx = blockIdx.x * 256 + threadIdx.x;
  const int total = 3 * 4 * 128 * 128;
  if (idx >= total) return;
  int e = idx & 127, d = (idx >> 7) & 127, h = (idx >> 14) & 3, L = idx >> 16;
  size_t dst = ((size_t)L * 128 + d) * 512 + h * 128 + e;
  WsP[dst] = Ws[idx];
  WnP[dst] = Wn[idx];
}

// ---------------- KNN: keys in registers, 8 wave-min extraction rounds ---------
template<int T>
__global__ __launch_bounds__(64) void knn_sel_kernel(const float* __restrict__ cent,
                                                     int* __restrict__ knn_idx, int Ni) {
  int i = blockIdx.x, b = blockIdx.y, lane = threadIdx.x;
  const float2* cb = (const float2*)(cent + (size_t)b * Ni * 2);
  float2 ci = cb[i];
  u64 keys[T];
#pragma unroll
  for (int t = 0; t < T; ++t) {
    int j = (t << 6) + lane;
    float2 cj = cb[j];
    float dx = __fsub_rn(ci.x, cj.x);
    float dy = __fsub_rn(ci.y, cj.y);
    float d2 = __fadd_rn(__fmul_rn(dx, dx), __fmul_rn(dy, dy));
    keys[t] = ((u64)__float_as_uint(d2) << 32) | (u32)j;
  }
  u64 prev = 0;
  for (int r = 0; r < KNN_K; ++r) {
    u64 best = ~0ULL;
    if (r == 0) {
#pragma unroll
      for (int t = 0; t < T; ++t) { if (keys[t] < best) best = keys[t]; }
    } else {
#pragma unroll
      for (int t = 0; t < T; ++t) { if (keys[t] > prev && keys[t] < best) best = keys[t]; }
    }
    for (int off = 32; off >= 1; off >>= 1) {
      u64 o = __shfl_xor(best, off, 64);
      if (o < best) best = o;
    }
    if (lane == 0) knn_idx[((size_t)(b * Ni + i)) * KNN_K + r] = (int)(best & 0xffffffffULL);
    prev = best;
  }
}

// ---------------- adjacency bitmask: A = mask | mask^T -------------------------
__global__ void build_adj_kernel(const int* __restrict__ knn_idx, u32* __restrict__ adj, int Ni) {
  int e = blockIdx.x * blockDim.x + threadIdx.x;
  int total = Bn * Ni * KNN_K;
  if (e >= total) return;
  int b = e / (Ni * KNN_K);
  int rem = e % (Ni * KNN_K);
  int r = rem / KNN_K;
  int j = knn_idx[e];
  atomicOr(&adj[((size_t)(b * Nmax + r)) * 64 + (j >> 5)], 1u << (j & 31));
  atomicOr(&adj[((size_t)(b * Nmax + j)) * 64 + (r >> 5)], 1u << (r & 31));
}

// ---------------- layernorm: one wave per row, shuffle butterfly (fallback) ----
__global__ __launch_bounds__(256) void layernorm_kernel(const float* __restrict__ x,
                                                        const float* __restrict__ g,
                                                        const float* __restrict__ be,
                                                        float* __restrict__ xn) {
  int row = blockIdx.x * 4 + (threadIdx.x >> 6);
  int lane = threadIdx.x & 63;
  const float* xr = x + (size_t)row * 128;
  float v1 = xr[lane], v2 = xr[lane + 64];
  float s = v1 + v2;
  for (int off = 32; off >= 1; off >>= 1) s += __shfl_xor(s, off, 64);
  float mean = s / 128.0f;
  float d1 = v1 - mean, d2 = v2 - mean;
  float q = d1 * d1 + d2 * d2;
  for (int off = 32; off >= 1; off >>= 1) q += __shfl_xor(q, off, 64);
  float rs = rsqrtf(q / 128.0f + EPSV);
  float* xo = xn + (size_t)row * 128;
  xo[lane] = d1 * rs * g[lane] + be[lane];
  xo[lane + 64] = d2 * rs * g[lane + 64] + be[lane + 64];
}

// ---------------- neighbor-mean aggregation + degree ---------------------------
__global__ void aggregate_kernel(const u32* __restrict__ adj, const float* __restrict__ xn,
                                 float* __restrict__ m, float* __restrict__ dinv, int Ni) {
  int i = blockIdx.x, b = blockIdx.y, t = threadIdx.x;
  __shared__ int cnt;
  extern __shared__ int list[];
  if (t == 0) cnt = 0;
  __syncthreads();
  int wpr = Ni >> 5;
  for (int w = t; w < wpr; w += blockDim.x) {
    u32 bits = adj[((size_t)(b * Nmax + i)) * 64 + w];
    while (bits) {
      int bit = __ffs(bits) - 1;
      bits &= bits - 1;
      int pos = atomicAdd(&cnt, 1);
      list[pos] = (w << 5) + bit;
    }
  }
  __syncthreads();
  int d = cnt;
  float acc = 0.0f;
  for (int k = 0; k < d; ++k) acc += xn[((size_t)b * Ni + list[k]) * 128 + t];
  m[((size_t)b * Ni + i) * 128 + t] = acc / (float)d;
  if (t == 0) dinv[b * Nmax + i] = 1.0f / sqrtf((float)d);
}

// ---------------- fp32 GEMM, TMx128 tile, packed v2f FMA, register prefetch ----
template<int TM>
__global__ __launch_bounds__(256) void gemm_kernel(
    const float* __restrict__ A, const float* __restrict__ W,
    const float* __restrict__ A2, const float* __restrict__ W2,
    const float* __restrict__ scale, const float* __restrict__ bias,
    float* __restrict__ C, int M, int N, int K, int flags) {
  constexpr int RPT = TM / 8;
  __shared__ float As[16][TM + 4];
  __shared__ float Bs[16][132];
  int tid = threadIdx.x;
  int tx = tid & 31;
  int ty = tid >> 5;
  int colBase = blockIdx.x * 128, rowBase = blockIdx.y * TM;
  v2f acc[RPT][2] = {};
  int ktiles = K >> 4;
  int total = (A2 ? 2 : 1) * ktiles;

  int arow = tid >> 2, aq = (tid & 3) * 4;
  int bk = tid >> 5, bc = (tid & 31) * 4;

  float4 pa, pb0, pb1;
  {
    if (TM == 64 || tid < TM * 4)
      pa = *(const float4*)(A + (size_t)(rowBase + arow) * K + aq);
    pb0 = *(const float4*)(W + (size_t)bk * N + colBase + bc);
    pb1 = *(const float4*)(W + (size_t)(bk + 8) * N + colBase + bc);
  }
  for (int t = 0; t < total; ++t) {
    if (TM == 64 || tid < TM * 4) {
      As[aq + 0][arow] = pa.x;
      As[aq + 1][arow] = pa.y;
      As[aq + 2][arow] = pa.z;
      As[aq + 3][arow] = pa.w;
    }
    *(float4*)&Bs[bk][bc] = pb0;
    *(float4*)&Bs[bk + 8][bc] = pb1;
    __syncthreads();
    if (t + 1 < total) {
      int tn = t + 1;
      const float* Ap = (tn >= ktiles) ? A2 : A;
      const float* Wp = (tn >= ktiles) ? W2 : W;
      int k0 = ((tn >= ktiles) ? tn - ktiles : tn) << 4;
      if (TM == 64 || tid < TM * 4)
        pa = *(const float4*)(Ap + (size_t)(rowBase + arow) * K + k0 + aq);
      pb0 = *(const float4*)(Wp + (size_t)(k0 + bk) * N + colBase + bc);
      pb1 = *(const float4*)(Wp + (size_t)(k0 + bk + 8) * N + colBase + bc);
    }
#pragma unroll
    for (int kk = 0; kk < 16; ++kk) {
      float a[RPT];
      v2f bv[2];
      if (RPT == 8) {
        *(float4*)&a[0] = *(const float4*)&As[kk][ty * 8];
        *(float4*)&a[4] = *(const float4*)&As[kk][ty * 8 + 4];
      } else {
        *(float4*)&a[0] = *(const float4*)&As[kk][ty * 4];
      }
      *(float4*)&bv[0] = *(const float4*)&Bs[kk][tx * 4];
#pragma unroll
      for (int r = 0; r < RPT; ++r)
#pragma unroll
        for (int c = 0; c < 2; ++c) acc[r][c] += a[r] * bv[c];
    }
    __syncthreads();
  }
#pragma unroll
  for (int r = 0; r < RPT; ++r) {
    int row = rowBase + ty * RPT + r;
    int col = colBase + tx * 4;
    float av[4];
    *(v2f*)&av[0] = acc[r][0];
    *(v2f*)&av[2] = acc[r][1];
    float4 v;
    float* vp = (float*)&v;
#pragma unroll
    for (int c = 0; c < 4; ++c) {
      float t = av[c];
      if (scale) t *= scale[col + c];
      if (bias) t += bias[col + c];
      if (flags & GF_RELU) t = fmaxf(t, 0.0f);
      vp[c] = t;
    }
    size_t o = (size_t)row * N + col;
    if (flags & GF_ACCUM) {
      float4 old = *(float4*)&C[o];
      v.x += old.x; v.y += old.y; v.z += old.z; v.w += old.w;
    }
    *(float4*)&C[o] = v;
  }
}

// ---------------- dual-operand 128x128-tile GEMM, double-buffered LDS ----------
// One barrier per k-tile: store(t)->barrier(t)->compute(t)->store(t+1). Any wave
// reaching store(t+1) implies all passed barrier(t), i.e. finished compute(t-1),
// the last readers of buffer (t+1)&1. Raw partials out.
__global__ __launch_bounds__(256) void gemm128dual_kernel(
    const float* __restrict__ A0, const float* __restrict__ W0,
    const float* __restrict__ A1, const float* __restrict__ W1,
    float* __restrict__ C0p, float* __restrict__ C1p, int M, int N) {
  const float* A = blockIdx.z ? A1 : A0;
  const float* W = blockIdx.z ? W1 : W0;
  float* C = blockIdx.z ? C1p : C0p;
  __shared__ float As[2][16][132];
  __shared__ float Bs[2][16][132];
  int tid = threadIdx.x;
  int tx = tid & 15;
  int ty = tid >> 4;
  int colBase = blockIdx.x * 128, rowBase = blockIdx.y * 128;
  v2f acc[8][4] = {};

  int arow = tid >> 1, aq = (tid & 1) * 8;
  int bk = tid >> 4, bq4 = (tid & 15) * 4;

  float4 pa0, pa1, pb0, pb1;
  {
    const float* ap = A + (size_t)(rowBase + arow) * 128 + aq;
    pa0 = *(const float4*)ap;
    pa1 = *(const float4*)(ap + 4);
    const float* bp = W + (size_t)bk * N + colBase;
    pb0 = *(const float4*)(bp + bq4);
    pb1 = *(const float4*)(bp + 64 + bq4);
  }
  for (int t = 0; t < 8; ++t) {
    int buf = t & 1;
    As[buf][aq + 0][arow] = pa0.x; As[buf][aq + 1][arow] = pa0.y;
    As[buf][aq + 2][arow] = pa0.z; As[buf][aq + 3][arow] = pa0.w;
    As[buf][aq + 4][arow] = pa1.x; As[buf][aq + 5][arow] = pa1.y;
    As[buf][aq + 6][arow] = pa1.z; As[buf][aq + 7][arow] = pa1.w;
    *(float4*)&Bs[buf][bk][bq4] = pb0;
    *(float4*)&Bs[buf][bk][64 + bq4] = pb1;
    __syncthreads();
    if (t + 1 < 8) {
      int k0 = (t + 1) << 4;
      const float* ap = A + (size_t)(rowBase + arow) * 128 + k0 + aq;
      pa0 = *(const float4*)ap;
      pa1 = *(const float4*)(ap + 4);
      const float* bp = W + (size_t)(k0 + bk) * N + colBase;
      pb0 = *(const float4*)(bp + bq4);
      pb1 = *(const float4*)(bp + 64 + bq4);
    }
#pragma unroll
    for (int kk = 0; kk < 16; ++kk) {
      float a[8];
      v2f bv[4];
      *(float4*)&a[0] = *(const float4*)&As[buf][kk][ty * 8];
      *(float4*)&a[4] = *(const float4*)&As[buf][kk][ty * 8 + 4];
      *(float4*)&bv[0] = *(const float4*)&Bs[buf][kk][tx * 4];
      *(float4*)&bv[2] = *(const float4*)&Bs[buf][kk][64 + tx * 4];
#pragma unroll
      for (int r = 0; r < 8; ++r)
#pragma unroll
        for (int c = 0; c < 4; ++c) acc[r][c] += a[r] * bv[c];
    }
  }
#pragma unroll
  for (int r = 0; r < 8; ++r) {
    int row = rowBase + ty * 8 + r;
#pragma unroll
    for (int h = 0; h < 2; ++h) {
      int col = colBase + h * 64 + tx * 4;
      float4 v;
      *(v2f*)&v.x = acc[r][h * 2 + 0];
      *(v2f*)&v.z = acc[r][h * 2 + 1];
      *(float4*)&C[(size_t)row * N + col] = v;
    }
  }
}

// ---------------- K-sliced 128x128-tile GEMM, double-buffered (N=128) ----------
__global__ __launch_bounds__(256) void gemm128ks_kernel(
    const float* __restrict__ A, const float* __restrict__ W,
    float* __restrict__ P, int M, int K) {
  __shared__ float As[2][16][132];
  __shared__ float Bs[2][16][132];
  int tid = threadIdx.x;
  int tx = tid & 15;
  int ty = tid >> 4;
  int rowBase = blockIdx.y * 128;
  int kbase = blockIdx.z * 128;
  v2f acc[8][4] = {};

  int arow = tid >> 1, aq = (tid & 1) * 8;
  int bk = tid >> 4, bq4 = (tid & 15) * 4;

  float4 pa0, pa1, pb0, pb1;
  {
    const float* ap = A + (size_t)(rowBase + arow) * K + kbase + aq;
    pa0 = *(const float4*)ap;
    pa1 = *(const float4*)(ap + 4);
    const float* bp = W + (size_t)(kbase + bk) * 128;
    pb0 = *(const float4*)(bp + bq4);
    pb1 = *(const float4*)(bp + 64 + bq4);
  }
  for (int t = 0; t < 8; ++t) {
    int buf = t & 1;
    As[buf][aq + 0][arow] = pa0.x; As[buf][aq + 1][arow] = pa0.y;
    As[buf][aq + 2][arow] = pa0.z; As[buf][aq + 3][arow] = pa0.w;
    As[buf][aq + 4][arow] = pa1.x; As[buf][aq + 5][arow] = pa1.y;
    As[buf][aq + 6][arow] = pa1.z; As[buf][aq + 7][arow] = pa1.w;
    *(float4*)&Bs[buf][bk][bq4] = pb0;
    *(float4*)&Bs[buf][bk][64 + bq4] = pb1;
    __syncthreads();
    if (t + 1 < 8) {
      int k0 = kbase + ((t + 1) << 4);
      const float* ap = A + (size_t)(rowBase + arow) * K + k0 + aq;
      pa0 = *(const float4*)ap;
      pa1 = *(const float4*)(ap + 4);
      const float* bp = W + (size_t)(k0 + bk) * 128;
      pb0 = *(const float4*)(bp + bq4);
      pb1 = *(const float4*)(bp + 64 + bq4);
    }
#pragma unroll
    for (int kk = 0; kk < 16; ++kk) {
      float a[8];
      v2f bv[4];
      *(float4*)&a[0] = *(const float4*)&As[buf][kk][ty * 8];
      *(float4*)&a[4] = *(const float4*)&As[buf][kk][ty * 8 + 4];
      *(float4*)&bv[0] = *(const float4*)&Bs[buf][kk][tx * 4];
      *(float4*)&bv[2] = *(const float4*)&Bs[buf][kk][64 + tx * 4];
#pragma unroll
      for (int r = 0; r < 8; ++r)
#pragma unroll
        for (int c = 0; c < 4; ++c) acc[r][c] += a[r] * bv[c];
    }
  }
  float* dst = P + (size_t)blockIdx.z * M * 128;
#pragma unroll
  for (int r = 0; r < 8; ++r) {
    int row = rowBase + ty * 8 + r;
#pragma unroll
    for (int h = 0; h < 2; ++h) {
      int col = h * 64 + tx * 4;
      float4 v;
      *(v2f*)&v.x = acc[r][h * 2 + 0];
      *(v2f*)&v.z = acc[r][h * 2 + 1];
      *(float4*)&dst[(size_t)row * 128 + col] = v;
    }
  }
}

// ---------------- Wg GEMM, 128-tile K-sliced, fused h-combine, dbuf ------------
__global__ __launch_bounds__(256) void gemm128hsum_kernel(
    const float* __restrict__ P0, const float* __restrict__ P1,
    const float* __restrict__ hbias, const float* __restrict__ W,
    float* __restrict__ Q0, float* __restrict__ Q1,
    float* __restrict__ Q2, float* __restrict__ Q3, int M) {
  float* Q = (blockIdx.z == 0) ? Q0 : (blockIdx.z == 1) ? Q1 : (blockIdx.z == 2) ? Q2 : Q3;
  __shared__ float As[2][16][132];
  __shared__ float Bs[2][16][132];
  int tid = threadIdx.x;
  int tx = tid & 15;
  int ty = tid >> 4;
  int rowBase = blockIdx.y * 128;
  int kbase = blockIdx.z * 128;
  v2f acc[8][4] = {};

  int arow = tid >> 1, aq = (tid & 1) * 8;
  int bk = tid >> 4, bq4 = (tid & 15) * 4;

  float4 q0a, q0b, q1a, q1b, hba, hbb, pb0, pb1;
  {
    size_t o = (size_t)(rowBase + arow) * 512 + kbase + aq;
    q0a = *(const float4*)(P0 + o);  q0b = *(const float4*)(P0 + o + 4);
    q1a = *(const float4*)(P1 + o);  q1b = *(const float4*)(P1 + o + 4);
    hba = *(const float4*)(hbias + kbase + aq);
    hbb = *(const float4*)(hbias + kbase + aq + 4);
    const float* bp = W + (size_t)(kbase + bk) * 128;
    pb0 = *(const float4*)(bp + bq4);
    pb1 = *(const float4*)(bp + 64 + bq4);
  }
  for (int t = 0; t < 8; ++t) {
    int buf = t & 1;
    As[buf][aq + 0][arow] = fmaxf(q0a.x + q1a.x + hba.x, 0.0f);
    As[buf][aq + 1][arow] = fmaxf(q0a.y + q1a.y + hba.y, 0.0f);
    As[buf][aq + 2][arow] = fmaxf(q0a.z + q1a.z + hba.z, 0.0f);
    As[buf][aq + 3][arow] = fmaxf(q0a.w + q1a.w + hba.w, 0.0f);
    As[buf][aq + 4][arow] = fmaxf(q0b.x + q1b.x + hbb.x, 0.0f);
    As[buf][aq + 5][arow] = fmaxf(q0b.y + q1b.y + hbb.y, 0.0f);
    As[buf][aq + 6][arow] = fmaxf(q0b.z + q1b.z + hbb.z, 0.0f);
    As[buf][aq + 7][arow] = fmaxf(q0b.w + q1b.w + hbb.w, 0.0f);
    *(float4*)&Bs[buf][bk][bq4] = pb0;
    *(float4*)&Bs[buf][bk][64 + bq4] = pb1;
    __syncthreads();
    if (t + 1 < 8) {
      int k0 = kbase + ((t + 1) << 4);
      size_t o = (size_t)(rowBase + arow) * 512 + k0 + aq;
      q0a = *(const float4*)(P0 + o);  q0b = *(const float4*)(P0 + o + 4);
      q1a = *(const float4*)(P1 + o);  q1b = *(const float4*)(P1 + o + 4);
      hba = *(const float4*)(hbias + k0 + aq);
      hbb = *(const float4*)(hbias + k0 + aq + 4);
      const float* bp = W + (size_t)(k0 + bk) * 128;
      pb0 = *(const float4*)(bp + bq4);
      pb1 = *(const float4*)(bp + 64 + bq4);
    }
#pragma unroll
    for (int kk = 0; kk < 16; ++kk) {
      float a[8];
      v2f bv[4];
      *(float4*)&a[0] = *(const float4*)&As[buf][kk][ty * 8];
      *(float4*)&a[4] = *(const float4*)&As[buf][kk][ty * 8 + 4];
      *(float4*)&bv[0] = *(const float4*)&Bs[buf][kk][tx * 4];
      *(float4*)&bv[2] = *(const float4*)&Bs[buf][kk][64 + tx * 4];
#pragma unroll
      for (int r = 0; r < 8; ++r)
#pragma unroll
        for (int c = 0; c < 4; ++c) acc[r][c] += a[r] * bv[c];
    }
  }
#pragma unroll
  for (int r = 0; r < 8; ++r) {
    int row = rowBase + ty * 8 + r;
#pragma unroll
    for (int h = 0; h < 2; ++h) {
      int col = h * 64 + tx * 4;
      float4 v;
      *(v2f*)&v.x = acc[r][h * 2 + 0];
      *(v2f*)&v.z = acc[r][h * 2 + 1];
      *(float4*)&Q[(size_t)row * 128 + col] = v;
    }
  }
}

// ---------------- combine 4 Wg partials + residual + LN2 -----------------------
__global__ __launch_bounds__(256) void combine_ln_kernel(
    const float* __restrict__ Q0, const float* __restrict__ Q1,
    const float* __restrict__ Q2, const float* __restrict__ Q3,
    const float* __restrict__ bg, const float* __restrict__ g,
    const float* __restrict__ be, float* __restrict__ x, float* __restrict__ xn) {
  int row = blockIdx.x * 4 + (threadIdx.x >> 6);
  int lane = threadIdx.x & 63;
  size_t o1 = (size_t)row * 128 + lane;
  size_t o2 = o1 + 64;
  float v1 = x[o1] + ((((Q0[o1] + Q1[o1]) + Q2[o1]) + Q3[o1]) + bg[lane]);
  float v2 = x[o2] + ((((Q0[o2] + Q1[o2]) + Q2[o2]) + Q3[o2]) + bg[lane + 64]);
  x[o1] = v1;
  x[o2] = v2;
  float s = v1 + v2;
  for (int off = 32; off >= 1; off >>= 1) s += __shfl_xor(s, off, 64);
  float mean = s / 128.0f;
  float d1 = v1 - mean, d2 = v2 - mean;
  float q = d1 * d1 + d2 * d2;
  for (int off = 32; off >= 1; off >>= 1) q += __shfl_xor(q, off, 64);
  float rs = rsqrtf(q / 128.0f + EPSV);
  xn[o1] = d1 * rs * g[lane] + be[lane];
  xn[o2] = d2 * rs * g[lane + 64] + be[lane + 64];
}

// ---------------- preconv2 with fused 4-partial combine + LN1 epilogue ---------
__global__ __launch_bounds__(256) void gemm_psum4_ln_kernel(
    const float* __restrict__ P, const float* __restrict__ sc,
    const float* __restrict__ bb, const float* __restrict__ W,
    const float* __restrict__ bias, const float* __restrict__ g,
    const float* __restrict__ be, float* __restrict__ C,
    float* __restrict__ xn, int M) {
  __shared__ float As[16][36];
  __shared__ float Bs[16][132];
  int tid = threadIdx.x;
  int tx = tid & 31;
  int ty = tid >> 5;
  int rowBase = blockIdx.y * 32;
  v2f acc[4][2] = {};
  const size_t PS = (size_t)M * 128;

  int arow = tid >> 2, aq = (tid & 3) * 4;
  int bk = tid >> 5, bc = (tid & 31) * 4;

  float4 p0, p1, p2, p3, s4, b4, pb0, pb1;
  {
    if (tid < 128) {
      size_t o = (size_t)(rowBase + arow) * 128 + aq;
      p0 = *(const float4*)(P + o);
      p1 = *(const float4*)(P + PS + o);
      p2 = *(const float4*)(P + 2 * PS + o);
      p3 = *(const float4*)(P + 3 * PS + o);
      s4 = *(const float4*)(sc + aq);
      b4 = *(const float4*)(bb + aq);
    }
    pb0 = *(const float4*)(W + (size_t)bk * 128 + bc);
    pb1 = *(const float4*)(W + (size_t)(bk + 8) * 128 + bc);
  }
  for (int t = 0; t < 8; ++t) {
    if (tid < 128) {
      As[aq + 0][arow] = fmaxf((((p0.x + p1.x) + p2.x) + p3.x) * s4.x + b4.x, 0.0f);
      As[aq + 1][arow] = fmaxf((((p0.y + p1.y) + p2.y) + p3.y) * s4.y + b4.y, 0.0f);
      As[aq + 2][arow] = fmaxf((((p0.z + p1.z) + p2.z) + p3.z) * s4.z + b4.z, 0.0f);
      As[aq + 3][arow] = fmaxf((((p0.w + p1.w) + p2.w) + p3.w) * s4.w + b4.w, 0.0f);
    }
    *(float4*)&Bs[bk][bc] = pb0;
    *(float4*)&Bs[bk + 8][bc] = pb1;
    __syncthreads();
    if (t + 1 < 8) {
      int k0 = (t + 1) << 4;
      if (tid < 128) {
        size_t o = (size_t)(rowBase + arow) * 128 + k0 + aq;
        p0 = *(const float4*)(P + o);
        p1 = *(const float4*)(P + PS + o);
        p2 = *(const float4*)(P + 2 * PS + o);
        p3 = *(const float4*)(P + 3 * PS + o);
        s4 = *(const float4*)(sc + k0 + aq);
        b4 = *(const float4*)(bb + k0 + aq);
      }
      pb0 = *(const float4*)(W + (size_t)(k0 + bk) * 128 + bc);
      pb1 = *(const float4*)(W + (size_t)(k0 + bk + 8) * 128 + bc);
    }
#pragma unroll
    for (int kk = 0; kk < 16; ++kk) {
      float a[4];
      v2f bv[2];
      *(float4*)&a[0] = *(const float4*)&As[kk][ty * 4];
      *(float4*)&bv[0] = *(const float4*)&Bs[kk][tx * 4];
#pragma unroll
      for (int r = 0; r < 4; ++r)
#pragma unroll
        for (int c = 0; c < 2; ++c) acc[r][c] += a[r] * bv[c];
    }
    __syncthreads();
  }
  float4 g4 = *(const float4*)(g + tx * 4);
  float4 be4 = *(const float4*)(be + tx * 4);
#pragma unroll
  for (int r = 0; r < 4; ++r) {
    int row = rowBase + ty * 4 + r;
    int col = tx * 4;
    float av[4];
    *(v2f*)&av[0] = acc[r][0];
    *(v2f*)&av[2] = acc[r][1];
    float4 v;
    v.x = av[0] + bias[col + 0];
    v.y = av[1] + bias[col + 1];
    v.z = av[2] + bias[col + 2];
    v.w = av[3] + bias[col + 3];
    *(float4*)&C[(size_t)row * 128 + col] = v;
    float s = ((v.x + v.y) + (v.z + v.w));
    for (int off = 16; off >= 1; off >>= 1) s += __shfl_xor(s, off, 64);
    float mean = s / 128.0f;
    float d0 = v.x - mean, d1 = v.y - mean, d2 = v.z - mean, d3 = v.w - mean;
    float q = ((d0 * d0 + d1 * d1) + (d2 * d2 + d3 * d3));
    for (int off = 16; off >= 1; off >>= 1) q += __shfl_xor(q, off, 64);
    float rs = rsqrtf(q / 128.0f + EPSV);
    float4 w;
    w.x = d0 * rs * g4.x + be4.x;
    w.y = d1 * rs * g4.y + be4.y;
    w.z = d2 * rs * g4.z + be4.z;
    w.w = d3 * rs * g4.w + be4.w;
    *(float4*)&xn[(size_t)row * 128 + col] = w;
  }
}

// ---------------- preconv2 with fused 4-partial combine (fallback, no LN) ------
__global__ __launch_bounds__(256) void gemm_psum4_kernel(
    const float* __restrict__ P, const float* __restrict__ sc,
    const float* __restrict__ bb, const float* __restrict__ W,
    const float* __restrict__ bias, float* __restrict__ C, int M) {
  __shared__ float As[16][36];
  __shared__ float Bs[16][132];
  int tid = threadIdx.x;
  int tx = tid & 31;
  int ty = tid >> 5;
  int rowBase = blockIdx.y * 32;
  v2f acc[4][2] = {};
  const size_t PS = (size_t)M * 128;

  int arow = tid >> 2, aq = (tid & 3) * 4;
  int bk = tid >> 5, bc = (tid & 31) * 4;

  float4 p0, p1, p2, p3, s4, b4, pb0, pb1;
  {
    if (tid < 128) {
      size_t o = (size_t)(rowBase + arow) * 128 + aq;
      p0 = *(const float4*)(P + o);
      p1 = *(const float4*)(P + PS + o);
      p2 = *(const float4*)(P + 2 * PS + o);
      p3 = *(const float4*)(P + 3 * PS + o);
      s4 = *(const float4*)(sc + aq);
      b4 = *(const float4*)(bb + aq);
    }
    pb0 = *(const float4*)(W + (size_t)bk * 128 + bc);
    pb1 = *(const float4*)(W + (size_t)(bk + 8) * 128 + bc);
  }
  for (int t = 0; t < 8; ++t) {
    if (tid < 128) {
      As[aq + 0][arow] = fmaxf((((p0.x + p1.x) + p2.x) + p3.x) * s4.x + b4.x, 0.0f);
      As[aq + 1][arow] = fmaxf((((p0.y + p1.y) + p2.y) + p3.y) * s4.y + b4.y, 0.0f);
      As[aq + 2][arow] = fmaxf((((p0.z + p1.z) + p2.z) + p3.z) * s4.z + b4.z, 0.0f);
      As[aq + 3][arow] = fmaxf((((p0.w + p1.w) + p2.w) + p3.w) * s4.w + b4.w, 0.0f);
    }
    *(float4*)&Bs[bk][bc] = pb0;
    *(float4*)&Bs[bk + 8][bc] = pb1;
    __syncthreads();
    if (t + 1 < 8) {
      int k0 = (t + 1) << 4;
      if (tid < 128) {
        size_t o = (size_t)(rowBase + arow) * 128 + k0 + aq;
        p0 = *(const float4*)(P + o);
        p1 = *(const float4*)(P + PS + o);
        p2 = *(const float4*)(P + 2 * PS + o);
        p3 = *(const float4*)(P + 3 * PS + o);
        s4 = *(const float4*)(sc + k0 + aq);
        b4 = *(const float4*)(bb + k0 + aq);
      }
      pb0 = *(const float4*)(W + (size_t)(k0 + bk) * 128 + bc);
      pb1 = *(const float4*)(W + (size_t)(k0 + bk + 8) * 128 + bc);
    }
#pragma unroll
    for (int kk = 0; kk < 16; ++kk) {
      float a[4];
      v2f bv[2];
      *(float4*)&a[0] = *(const float4*)&As[kk][ty * 4];
      *(float4*)&bv[0] = *(const float4*)&Bs[kk][tx * 4];
#pragma unroll
      for (int r = 0; r < 4; ++r)
#pragma unroll
        for (int c = 0; c < 2; ++c) acc[r][c] += a[r] * bv[c];
    }
    __syncthreads();
  }
#pragma unroll
  for (int r = 0; r < 4; ++r) {
    int row = rowBase + ty * 4 + r;
    int col = tx * 4;
    float av[4];
    *(v2f*)&av[0] = acc[r][0];
    *(v2f*)&av[2] = acc[r][1];
    float4 v;
    v.x = av[0] + bias[col + 0];
    v.y = av[1] + bias[col + 1];
    v.z = av[2] + bias[col + 2];
    v.w = av[3] + bias[col + 3];
    *(float4*)&C[(size_t)row * 128 + col] = v;
  }
}

// ---------------- Wg GEMM with fused h-combine (fallback) ----------------------
__global__ __launch_bounds__(256) void gemm_hsum_kernel(
    const float* __restrict__ P0, const float* __restrict__ P1,
    const float* __restrict__ hbias, const float* __restrict__ W,
    const float* __restrict__ bias, float* __restrict__ C, int M) {
  __shared__ float As[16][36];
  __shared__ float Bs[16][132];
  int tid = threadIdx.x;
  int tx = tid & 31;
  int ty = tid >> 5;
  int rowBase = blockIdx.y * 32;
  v2f acc[4][2] = {};

  int arow = tid >> 2, aq = (tid & 3) * 4;
  int bk = tid >> 5, bc = (tid & 31) * 4;

  float4 pq0, pq1, pb0, pb1, hb;
  {
    if (tid < 128) {
      size_t o = (size_t)(rowBase + arow) * 512 + aq;
      pq0 = *(const float4*)(P0 + o);
      pq1 = *(const float4*)(P1 + o);
      hb = *(const float4*)(hbias + aq);
    }
    pb0 = *(const float4*)(W + (size_t)bk * 128 + bc);
    pb1 = *(const float4*)(W + (size_t)(bk + 8) * 128 + bc);
  }
  for (int t = 0; t < 32; ++t) {
    if (tid < 128) {
      As[aq + 0][arow] = fmaxf(pq0.x + pq1.x + hb.x, 0.0f);
      As[aq + 1][arow] = fmaxf(pq0.y + pq1.y + hb.y, 0.0f);
      As[aq + 2][arow] = fmaxf(pq0.z + pq1.z + hb.z, 0.0f);
      As[aq + 3][arow] = fmaxf(pq0.w + pq1.w + hb.w, 0.0f);
    }
    *(float4*)&Bs[bk][bc] = pb0;
    *(float4*)&Bs[bk + 8][bc] = pb1;
    __syncthreads();
    if (t + 1 < 32) {
      int k0 = (t + 1) << 4;
      if (tid < 128) {
        size_t o = (size_t)(rowBase + arow) * 512 + k0 + aq;
        pq0 = *(const float4*)(P0 + o);
        pq1 = *(const float4*)(P1 + o);
        hb = *(const float4*)(hbias + k0 + aq);
      }
      pb0 = *(const float4*)(W + (size_t)(k0 + bk) * 128 + bc);
      pb1 = *(const float4*)(W + (size_t)(k0 + bk + 8) * 128 + bc);
    }
#pragma unroll
    for (int kk = 0; kk < 16; ++kk) {
      float a[4];
      v2f bv[2];
      *(float4*)&a[0] = *(const float4*)&As[kk][ty * 4];
      *(float4*)&bv[0] = *(const float4*)&Bs[kk][tx * 4];
#pragma unroll
      for (int r = 0; r < 4; ++r)
#pragma unroll
        for (int c = 0; c < 2; ++c) acc[r][c] += a[r] * bv[c];
    }
    __syncthreads();
  }
#pragma unroll
  for (int r = 0; r < 4; ++r) {
    int row = rowBase + ty * 4 + r;
    int col = tx * 4;
    float av[4];
    *(v2f*)&av[0] = acc[r][0];
    *(v2f*)&av[2] = acc[r][1];
    size_t o = (size_t)row * 128 + col;
    float4 old = *(float4*)&C[o];
    float4 v;
    v.x = av[0] + bias[col + 0] + old.x;
    v.y = av[1] + bias[col + 1] + old.y;
    v.z = av[2] + bias[col + 2] + old.z;
    v.w = av[3] + bias[col + 3] + old.w;
    *(float4*)&C[o] = v;
  }
}

// ---------------- fp32 GEMM, 128x128 tile (generic) ----------------------------
__global__ __launch_bounds__(256) void gemm128_kernel(
    const float* __restrict__ A, const float* __restrict__ W,
    const float* __restrict__ A2, const float* __restrict__ W2,
    const float* __restrict__ bias, float* __restrict__ C,
    int M, int N, int K, int flags) {
  __shared__ float As[16][132];
  __shared__ float Bs[16][132];
  int tid = threadIdx.x;
  int tx = tid & 15;
  int ty = tid >> 4;
  int colBase = blockIdx.x * 128, rowBase = blockIdx.y * 128;
  v2f acc[8][4] = {};
  int ktiles = K >> 4;
  int total = (A2 ? 2 : 1) * ktiles;

  int arow = tid >> 1, aq = (tid & 1) * 8;
  int bk = tid >> 4, bq4 = (tid & 15) * 4;

  float4 pa0, pa1, pb0, pb1;
  {
    const float* ap = A + (size_t)(rowBase + arow) * K + aq;
    pa0 = *(const float4*)ap;
    pa1 = *(const float4*)(ap + 4);
    const float* bp = W + (size_t)bk * N + colBase;
    pb0 = *(const float4*)(bp + bq4);
    pb1 = *(const float4*)(bp + 64 + bq4);
  }
  for (int t = 0; t < total; ++t) {
    As[aq + 0][arow] = pa0.x; As[aq + 1][arow] = pa0.y;
    As[aq + 2][arow] = pa0.z; As[aq + 3][arow] = pa0.w;
    As[aq + 4][arow] = pa1.x; As[aq + 5][arow] = pa1.y;
    As[aq + 6][arow] = pa1.z; As[aq + 7][arow] = pa1.w;
    *(float4*)&Bs[bk][bq4] = pb0;
    *(float4*)&Bs[bk][64 + bq4] = pb1;
    __syncthreads();
    if (t + 1 < total) {
      int tn = t + 1;
      const float* Ap = (tn >= ktiles) ? A2 : A;
      const float* Wp = (tn >= ktiles) ? W2 : W;
      int k0 = ((tn >= ktiles) ? tn - ktiles : tn) << 4;
      const float* ap = Ap + (size_t)(rowBase + arow) * K + k0 + aq;
      pa0 = *(const float4*)ap;
      pa1 = *(const float4*)(ap + 4);
      const float* bp = Wp + (size_t)(k0 + bk) * N + colBase;
      pb0 = *(const float4*)(bp + bq4);
      pb1 = *(const float4*)(bp + 64 + bq4);
    }
#pragma unroll
    for (int kk = 0; kk < 16; ++kk) {
      float a[8];
      v2f bv[4];
      *(float4*)&a[0] = *(const float4*)&As[kk][ty * 8];
      *(float4*)&a[4] = *(const float4*)&As[kk][ty * 8 + 4];
      *(float4*)&bv[0] = *(const float4*)&Bs[kk][tx * 4];
      *(float4*)&bv[2] = *(const float4*)&Bs[kk][64 + tx * 4];
#pragma unroll
      for (int r = 0; r < 8; ++r)
#pragma unroll
        for (int c = 0; c < 4; ++c) acc[r][c] += a[r] * bv[c];
    }
    __syncthreads();
  }
#pragma unroll
  for (int r = 0; r < 8; ++r) {
    int row = rowBase + ty * 8 + r;
#pragma unroll
    for (int h = 0; h < 2; ++h) {
      int col = colBase + h * 64 + tx * 4;
      float av[4];
      *(v2f*)&av[0] = acc[r][h * 2 + 0];
      *(v2f*)&av[2] = acc[r][h * 2 + 1];
      float4 v;
      float* vp = (float*)&v;
#pragma unroll
      for (int c = 0; c < 4; ++c) {
        float t = av[c];
        if (bias) t += bias[col + c];
        if (flags & GF_RELU) t = fmaxf(t, 0.0f);
        vp[c] = t;
      }
      size_t o = (size_t)row * N + col;
      if (flags & GF_ACCUM) {
        float4 old = *(float4*)&C[o];
        v.x += old.x; v.y += old.y; v.z += old.z; v.w += old.w;
      }
      *(float4*)&C[o] = v;
    }
  }
}

// ---------------- fused FFN: x += relu(xn2@W1 + b1) @ W2 + b2 ------------------
__global__ __launch_bounds__(256) void ffn_fused_kernel(
    const float* __restrict__ xn, const float* __restrict__ W1,
    const float* __restrict__ b1, const float* __restrict__ W2,
    const float* __restrict__ b2, float* __restrict__ x) {
  __shared__ float Axn[128 * 36];
  __shared__ float Hs [128 * 36];
  __shared__ float Bs [16 * 132];
  int tid = threadIdx.x;
  int rowBase = blockIdx.x * 32;
  int tx = tid & 31, ty = tid >> 5;
  {
    int row = tid >> 3, ks = (tid & 7) * 16;
    const float* s1 = xn + (size_t)(rowBase + row) * 128 + ks;
#pragma unroll
    for (int q = 0; q < 4; ++q) {
      float4 v = *(const float4*)(s1 + q * 4);
      int k = ks + q * 4;
      Axn[(k + 0) * 36 + row] = v.x; Axn[(k + 1) * 36 + row] = v.y;
      Axn[(k + 2) * 36 + row] = v.z; Axn[(k + 3) * 36 + row] = v.w;
    }
  }
  int bk = tid >> 4, bc = (tid & 15) * 8;
  v2f hacc[4][2] = {};
  {
    float4 p0 = *(const float4*)(W1 + (size_t)bk * 128 + bc);
    float4 p1 = *(const float4*)(W1 + (size_t)bk * 128 + bc + 4);
    for (int kt = 0; kt < 8; ++kt) {
      __syncthreads();
      *(float4*)&Bs[bk * 132 + bc] = p0;
      *(float4*)&Bs[bk * 132 + bc + 4] = p1;
      __syncthreads();
      if (kt < 7) {
        p0 = *(const float4*)(W1 + (size_t)(kt * 16 + 16 + bk) * 128 + bc);
        p1 = *(const float4*)(W1 + (size_t)(kt * 16 + 16 + bk) * 128 + bc + 4);
      }
      int k0 = kt * 16;
#pragma unroll
      for (int kk = 0; kk < 16; ++kk) {
        float av[4];
        v2f bv[2];
        *(float4*)av = *(const float4*)&Axn[(k0 + kk) * 36 + ty * 4];
        *(float4*)&bv[0] = *(const float4*)&Bs[kk * 132 + tx * 4];
#pragma unroll
        for (int r = 0; r < 4; ++r)
#pragma unroll
          for (int c = 0; c < 2; ++c) hacc[r][c] += av[r] * bv[c];
      }
    }
  }
  __syncthreads();
#pragma unroll
  for (int r = 0; r < 4; ++r) {
    float hv[4];
    *(v2f*)&hv[0] = hacc[r][0];
    *(v2f*)&hv[2] = hacc[r][1];
#pragma unroll
    for (int c = 0; c < 4; ++c) {
      float v = hv[c] + b1[tx * 4 + c];
      v = fmaxf(v, 0.0f);
      Hs[(tx * 4 + c) * 36 + ty * 4 + r] = v;
    }
  }
  v2f oacc[4][2] = {};
  {
    float4 q0 = *(const float4*)(W2 + (size_t)bk * 128 + bc);
    float4 q1 = *(const float4*)(W2 + (size_t)bk * 128 + bc + 4);
    for (int kt = 0; kt < 8; ++kt) {
      __syncthreads();
      *(float4*)&Bs[bk * 132 + bc] = q0;
      *(float4*)&Bs[bk * 132 + bc + 4] = q1;
      __syncthreads();
      if (kt < 7) {
        q0 = *(const float4*)(W2 + (size_t)(kt * 16 + 16 + bk) * 128 + bc);
        q1 = *(const float4*)(W2 + (size_t)(kt * 16 + 16 + bk) * 128 + bc + 4);
      }
      int k0 = kt * 16;
#pragma unroll
      for (int kk = 0; kk < 16; ++kk) {
        float av[4];
        v2f bv[2];
        *(float4*)av = *(const float4*)&Hs[(k0 + kk) * 36 + ty * 4];
        *(float4*)&bv[0] = *(const float4*)&Bs[kk * 132 + tx * 4];
#pragma unroll
        for (int r = 0; r < 4; ++r)
#pragma unroll
          for (int c = 0; c < 2; ++c) oacc[r][c] += av[r] * bv[c];
      }
    }
  }
#pragma unroll
  for (int r = 0; r < 4; ++r) {
    int row = rowBase + ty * 4 + r;
    float ov[4];
    *(v2f*)&ov[0] = oacc[r][0];
    *(v2f*)&ov[2] = oacc[r][1];
    float4 old = *(float4*)&x[(size_t)row * 128 + tx * 4];
    float4 v;
    v.x = ov[0] + b2[tx * 4 + 0]; v.x += old.x;
    v.y = ov[1] + b2[tx * 4 + 1]; v.y += old.y;
    v.z = ov[2] + b2[tx * 4 + 2]; v.z += old.z;
    v.w = ov[3] + b2[tx * 4 + 3]; v.w += old.w;
    *(float4*)&x[(size_t)row * 128 + tx * 4] = v;
  }
}

// ---------------- q = x@Wq ; p = dinv*q ---------------------------------------
__global__ void qp_kernel(const float* __restrict__ x, const float* __restrict__ Wq,
                          const float* __restrict__ dinv, float* __restrict__ p, int Ni) {
  int node = blockIdx.x;
  int lane = threadIdx.x;
  int b = node / Ni, i = node % Ni;
  float v = x[(size_t)node * 128 + lane] * Wq[lane] +
            x[(size_t)node * 128 + 64 + lane] * Wq[64 + lane];
  for (int off = 32; off >= 1; off >>= 1) v += __shfl_xor(v, off, 64);
  if (lane == 0) p[b * Nmax + i] = dinv[b * Nmax + i] * v;
}

// ---------------- s = dinv * (A @ p) + bq -------------------------------------
__global__ void score_kernel(const u32* __restrict__ adj, const float* __restrict__ p,
                             const float* __restrict__ dinv, const float* __restrict__ bq,
                             float* __restrict__ s, int Ni) {
  int i = blockIdx.x, b = blockIdx.y, lane = threadIdx.x;
  int wpr = Ni >> 5;
  float acc = 0.0f;
  if (lane < wpr) {
    u32 bits = adj[((size_t)(b * Nmax + i)) * 64 + lane];
    while (bits) {
      int bit = __ffs(bits) - 1;
      bits &= bits - 1;
      acc += p[b * Nmax + (lane << 5) + bit];
    }
  }
  for (int off = 32; off >= 1; off >>= 1) acc += __shfl_xor(acc, off, 64);
  if (lane == 0) s[b * Nmax + i] = dinv[b * Nmax + i] * acc + bq[0];
}

// ---------------- top-k via exact rank counting --------------------------------
__global__ void topk_rank_kernel(const float* __restrict__ s, int Ni, int* __restrict__ topi) {
  int b = blockIdx.y;
  int e0 = blockIdx.x * 256;
  int t = threadIdx.x;
  __shared__ u64 keys[2048];
  for (int e = t; e < Ni; e += 256) {
    u32 u = __float_as_uint(s[b * Nmax + e]);
    u32 mono = (u & 0x80000000u) ? ~u : (u | 0x80000000u);
    keys[e] = ((u64)(~mono) << 32) | (u32)e;
  }
  __syncthreads();
  int e = e0 + t;
  if (e >= Ni) return;
  u64 my = keys[e];
  int rank = 0;
  for (int q = 0; q < Ni; ++q) rank += (keys[q] < my) ? 1 : 0;
  int kkeep = Ni >> 1;
  if (rank < kkeep) topi[b * 1024 + rank] = e;
}

// ---------------- gather + tanh gate + optional fused LN1 ----------------------
__global__ __launch_bounds__(64) void gather_kernel(
    const float* __restrict__ x, const float* __restrict__ c,
    const float* __restrict__ s, const int* __restrict__ topi,
    float* __restrict__ xo, float* __restrict__ co,
    const float* __restrict__ g, const float* __restrict__ be,
    float* __restrict__ xn, int Ni) {
  int inew = blockIdx.x, b = blockIdx.y, lane = threadIdx.x;
  int kkeep = Ni >> 1;
  int old = topi[b * 1024 + inew];
  float gate = tanhf(s[b * Nmax + old]);
  size_t ri = ((size_t)b * Ni + old) * 128;
  size_t ro = ((size_t)b * kkeep + inew) * 128;
  float v1 = x[ri + lane] * gate;
  float v2 = x[ri + 64 + lane] * gate;
  xo[ro + lane] = v1;
  xo[ro + 64 + lane] = v2;
  if (lane < 2) co[((size_t)b * kkeep + inew) * 2 + lane] = c[((size_t)b * Ni + old) * 2 + lane];
  if (g) {
    float sm = v1 + v2;
    for (int off = 32; off >= 1; off >>= 1) sm += __shfl_xor(sm, off, 64);
    float mean = sm / 128.0f;
    float d1 = v1 - mean, d2 = v2 - mean;
    float q = d1 * d1 + d2 * d2;
    for (int off = 32; off >= 1; off >>= 1) q += __shfl_xor(q, off, 64);
    float rs = rsqrtf(q / 128.0f + EPSV);
    xn[ro + lane] = d1 * rs * g[lane] + be[lane];
    xn[ro + 64 + lane] = d2 * rs * g[lane + 64] + be[lane + 64];
  }
}

// ---------------- picks: two-stage [max ; mean] reduction ----------------------
__global__ void picks_partial_kernel(const float* __restrict__ x, float* __restrict__ part,
                                     int kkeep, int G) {
  int b = blockIdx.x, g = blockIdx.y, t = threadIdx.x;
  int per = kkeep / G;
  int start = g * per;
  float mx = -INFINITY, sm = 0.0f;
  for (int i = start; i < start + per; ++i) {
    float v = x[((size_t)b * kkeep + i) * 128 + t];
    mx = fmaxf(mx, v);
    sm += v;
  }
  part[((size_t)(b * G + g)) * 256 + t] = mx;
  part[((size_t)(b * G + g)) * 256 + 128 + t] = sm;
}

__global__ void picks_combine_kernel(const float* __restrict__ part, float* __restrict__ picks,
                                     int kkeep, int G) {
  int b = blockIdx.x, t = threadIdx.x;
  float mx = -INFINITY, sm = 0.0f;
  for (int g = 0; g < G; ++g) {
    mx = fmaxf(mx, part[((size_t)(b * G + g)) * 256 + t]);
    sm += part[((size_t)(b * G + g)) * 256 + 128 + t];
  }
  picks[b * 256 + t] += mx;
  picks[b * 256 + 128 + t] += sm / (float)kkeep;
}

// ---------------- final 2-layer MLP -------------------------------------------
__global__ void final_kernel(const float* __restrict__ picks, const float* __restrict__ Wf1,
                             const float* __restrict__ bf1, const float* __restrict__ Wf2,
                             const float* __restrict__ bf2, float* __restrict__ out) {
  int b = blockIdx.x, t = threadIdx.x;
  __shared__ float pk[256];
  __shared__ float fm[128];
  pk[t] = picks[b * 256 + t];
  pk[t + 128] = picks[b * 256 + 128 + t];
  __syncthreads();
  float acc = bf1[t];
  for (int k = 0; k < 256; ++k) acc += pk[k] * Wf1[k * 128 + t];
  fm[t] = fmaxf(acc, 0.0f);
  __syncthreads();
  if (t < 32) {
    float a2 = bf2[t];
    for (int k = 0; k < 128; ++k) a2 += fm[k] * Wf2[k * 32 + t];
    out[b * 32 + t] = fmaxf(a2, 0.0f);
  }
}

extern "C" void kernel_launch(void* const* d_in, const int* in_sizes, int n_in,
                              void* d_out, int out_size, void* d_ws, size_t ws_size,
                              hipStream_t stream) {
  const float* feats = (const float*)d_in[0];
  const float* cent  = (const float*)d_in[1];
  const float* Wp1 = (const float*)d_in[2];
  const float* bp1 = (const float*)d_in[3];
  const float* bn_g = (const float*)d_in[4];
  const float* bn_b = (const float*)d_in[5];
  const float* Wp2 = (const float*)d_in[6];
  const float* bp2 = (const float*)d_in[7];
  const float* g1  = (const float*)d_in[8];
  const float* be1 = (const float*)d_in[9];
  const float* g2  = (const float*)d_in[10];
  const float* be2 = (const float*)d_in[11];
  const float* Ws  = (const float*)d_in[12];
  const float* Wn  = (const float*)d_in[13];
  const float* bs  = (const float*)d_in[14];
  const float* Wg  = (const float*)d_in[15];
  const float* bg  = (const float*)d_in[16];
  const float* W1  = (const float*)d_in[17];
  const float* b1  = (const float*)d_in[18];
  const float* W2  = (const float*)d_in[19];
  const float* b2  = (const float*)d_in[20];
  const float* Wq  = (const float*)d_in[21];
  const float* bq  = (const float*)d_in[22];
  const float* Wf1 = (const float*)d_in[23];
  const float* bf1 = (const float*)d_in[24];
  const float* Wf2 = (const float*)d_in[25];
  const float* bf2 = (const float*)d_in[26];
  float* out = (float*)d_out;

  float* p = (float*)d_ws;
  const size_t SZX = (size_t)Bn * Nmax * 128;
  float* SC = p;    p += 128;
  float* BBv = p;   p += 128;
  float* DINV = p;  p += Bn * Nmax;
  float* PV = p;    p += Bn * Nmax;
  float* SS = p;    p += Bn * Nmax;
  float* PICKS = p; p += Bn * 256;
  float* PART = p;  p += (size_t)Bn * 32 * 256;
  float* C0 = p;    p += (size_t)Bn * Nmax * 2;
  float* C1 = p;    p += (size_t)Bn * Nmax * 2;
  int* KNN = (int*)p;  p += (size_t)Bn * Nmax * KNN_K;
  int* TOPI = (int*)p; p += Bn * 1024;
  u32* ADJ = (u32*)p;  p += (size_t)Bn * Nmax * 64;
  float* X0 = p;    p += SZX;
  float* X1 = p;    p += SZX;
  float* BA = p;    p += SZX;
  float* BB = p;    p += SZX;
  float* HB = p;    // h partial 0 / preconv partials: 4*SZX
  size_t base_floats = (size_t)(p - (float*)d_ws);
  const size_t WPSZ = (size_t)3 * 128 * 512;
  bool fused = ws_size >= (base_floats + 4 * SZX + 2 * WPSZ) * sizeof(float);
  float* WSP = HB + 4 * SZX;
  float* WNP = WSP + WPSZ;
  float* PK = WNP + WPSZ;      // h partial 1: 4*SZX
  float* QD = PK + 4 * SZX;    // Wg partial slice 3: 1*SZX
  bool fused2 = ws_size >= (base_floats + 8 * SZX + 2 * WPSZ) * sizeof(float);
  bool fused3 = ws_size >= (base_floats + 9 * SZX + 2 * WPSZ) * sizeof(float);

  hipLaunchKernelGGL(precompute_kernel, dim3(1), dim3(256), 0, stream,
                     bn_g, bn_b, bp1, SC, BBv, PICKS);
  if (fused) {
    hipLaunchKernelGGL(repack_ws_kernel, dim3(768), dim3(256), 0, stream, Ws, Wn, WSP, WNP);
  }

  // ---- preconv ----
  const int M0 = Bn * Nmax;
  if (fused3) {
    hipLaunchKernelGGL(gemm128ks_kernel, dim3(1, M0 / 128, 4), dim3(256), 0, stream,
                       feats, Wp1, HB, M0, 512);
    hipLaunchKernelGGL(gemm_psum4_ln_kernel, dim3(1, M0 / 32), dim3(256), 0, stream,
                       HB, SC, BBv, Wp2, bp2, g1, be1, X0, BA, M0);
  } else if (fused) {
    hipLaunchKernelGGL(gemm128ks_kernel, dim3(1, M0 / 128, 4), dim3(256), 0, stream,
                       feats, Wp1, HB, M0, 512);
    hipLaunchKernelGGL(gemm_psum4_kernel, dim3(1, M0 / 32), dim3(256), 0, stream,
                       HB, SC, BBv, Wp2, bp2, X0, M0);
  } else {
    hipLaunchKernelGGL(gemm_kernel<32>, dim3(1, M0 / 32), dim3(256), 0, stream,
                       feats, Wp1, (const float*)nullptr, (const float*)nullptr,
                       SC, BBv, BA, M0, 128, 512, GF_RELU);
    hipLaunchKernelGGL(gemm_kernel<32>, dim3(1, M0 / 32), dim3(256), 0, stream,
                       BA, Wp2, (const float*)nullptr, (const float*)nullptr,
                       (const float*)nullptr, bp2, X0, M0, 128, 128, 0);
  }

  float* xc = X0;
  float* xo = X1;
  const float* cc = cent;
  float* co = C0;
  int Ni = Nmax;
  for (int L = 0; L < 3; ++L) {
    int M = Bn * Ni;
    if (Ni == 2048)      hipLaunchKernelGGL(knn_sel_kernel<32>, dim3(Ni, Bn), dim3(64), 0, stream, cc, KNN, Ni);
    else if (Ni == 1024) hipLaunchKernelGGL(knn_sel_kernel<16>, dim3(Ni, Bn), dim3(64), 0, stream, cc, KNN, Ni);
    else                 hipLaunchKernelGGL(knn_sel_kernel<8>,  dim3(Ni, Bn), dim3(64), 0, stream, cc, KNN, Ni);
    hipMemsetAsync(ADJ, 0, (size_t)Bn * Nmax * 64 * sizeof(u32), stream);
    int tot = Bn * Ni * KNN_K;
    hipLaunchKernelGGL(build_adj_kernel, dim3((tot + 255) / 256), dim3(256), 0, stream,
                       KNN, ADJ, Ni);
    if (!fused3) {
      hipLaunchKernelGGL(layernorm_kernel, dim3(M / 4), dim3(256), 0, stream,
                         xc, g1 + L * 128, be1 + L * 128, BA);
    }
    hipLaunchKernelGGL(aggregate_kernel, dim3(Ni, Bn), dim3(128), Ni * sizeof(int), stream,
                       ADJ, BA, BB, DINV, Ni);
    if (fused3) {
      hipLaunchKernelGGL(gemm128dual_kernel, dim3(4, M / 128, 2), dim3(256), 0, stream,
                         BA, WSP + (size_t)L * 128 * 512,
                         BB, WNP + (size_t)L * 128 * 512,
                         HB, PK, M, 512);
      hipLaunchKernelGGL(gemm128hsum_kernel, dim3(1, M / 128, 4), dim3(256), 0, stream,
                         HB, PK, bs + L * 512, Wg + (size_t)L * 512 * 128,
                         BA, BB, xo, QD, M);
      hipLaunchKernelGGL(combine_ln_kernel, dim3(M / 4), dim3(256), 0, stream,
                         BA, BB, xo, QD, bg + L * 128, g2 + L * 128, be2 + L * 128,
                         xc, BA);
    } else if (fused2) {
      hipLaunchKernelGGL(gemm128dual_kernel, dim3(4, M / 128, 2), dim3(256), 0, stream,
                         BA, WSP + (size_t)L * 128 * 512,
                         BB, WNP + (size_t)L * 128 * 512,
                         HB, PK, M, 512);
      hipLaunchKernelGGL(gemm_hsum_kernel, dim3(1, M / 32), dim3(256), 0, stream,
                         HB, PK, bs + L * 512, Wg + (size_t)L * 512 * 128,
                         bg + L * 128, xc, M);
      hipLaunchKernelGGL(layernorm_kernel, dim3(M / 4), dim3(256), 0, stream,
                         xc, g2 + L * 128, be2 + L * 128, BA);
    } else if (fused) {
      hipLaunchKernelGGL(gemm128_kernel, dim3(4, M / 128), dim3(256), 0, stream,
                         BA, WSP + (size_t)L * 128 * 512,
                         BB, WNP + (size_t)L * 128 * 512,
                         bs + L * 512, HB, M, 512, 128, GF_RELU);
      hipLaunchKernelGGL(gemm_kernel<32>, dim3(1, M / 32), dim3(256), 0, stream,
                         HB, Wg + (size_t)L * 512 * 128,
                         (const float*)nullptr, (const float*)nullptr,
                         (const float*)nullptr, bg + L * 128,
                         xc, M, 128, 512, GF_ACCUM);
      hipLaunchKernelGGL(layernorm_kernel, dim3(M / 4), dim3(256), 0, stream,
                         xc, g2 + L * 128, be2 + L * 128, BA);
    } else {
      for (int hh = 0; hh < 4; ++hh) {
        hipLaunchKernelGGL(gemm_kernel<32>, dim3(1, M / 32), dim3(256), 0, stream,
                           BA, Ws + ((size_t)(L * 4 + hh)) * 128 * 128,
                           BB, Wn + ((size_t)(L * 4 + hh)) * 128 * 128,
                           (const float*)nullptr, bs + (L * 4 + hh) * 128,
                           HB, M, 128, 128, GF_RELU);
        hipLaunchKernelGGL(gemm_kernel<32>, dim3(1, M / 32), dim3(256), 0, stream,
                           HB, Wg + ((size_t)L * 512 + hh * 128) * 128,
                           (const float*)nullptr, (const float*)nullptr,
                           (const float*)nullptr, (hh == 0) ? (bg + L * 128) : (const float*)nullptr,
                           xc, M, 128, 128, GF_ACCUM);
      }
      hipLaunchKernelGGL(layernorm_kernel, dim3(M / 4), dim3(256), 0, stream,
                         xc, g2 + L * 128, be2 + L * 128, BA);
    }
    hipLaunchKernelGGL(ffn_fused_kernel, dim3(M / 32), dim3(256), 0, stream,
                       BA, W1 + (size_t)L * 128 * 128, b1 + L * 128,
                       W2 + (size_t)L * 128 * 128, b2 + L * 128, xc);
    hipLaunchKernelGGL(qp_kernel, dim3(M), dim3(64), 0, stream, xc, Wq + L * 128, DINV, PV, Ni);
    hipLaunchKernelGGL(score_kernel, dim3(Ni, Bn), dim3(64), 0, stream, ADJ, PV, DINV, bq + L, SS, Ni);
    hipLaunchKernelGGL(topk_rank_kernel, dim3((Ni + 255) / 256, Bn), dim3(256), 0, stream,
                       SS, Ni, TOPI);
    int kkeep = Ni >> 1;
    const float* gn = (fused3 && L < 2) ? (g1 + (L + 1) * 128) : (const float*)nullptr;
    const float* bn = (fused3 && L < 2) ? (be1 + (L + 1) * 128) : (const float*)nullptr;
    hipLaunchKernelGGL(gather_kernel, dim3(kkeep, Bn), dim3(64), 0, stream,
                       xc, cc, SS, TOPI, xo, co, gn, bn, BA, Ni);
    int G = kkeep / 32;
    hipLaunchKernelGGL(picks_partial_kernel, dim3(Bn, G), dim3(128), 0, stream,
                       xo, PART, kkeep, G);
    hipLaunchKernelGGL(picks_combine_kernel, dim3(Bn), dim3(128), 0, stream,
                       PART, PICKS, kkeep, G);
    float* tmp = xc; xc = xo; xo = tmp;
    cc = co;
    co = (co == C0) ? C1 : C0;
    Ni = kkeep;
  }
  hipLaunchKernelGGL(final_kernel, dim3(Bn), dim3(128), 0, stream,
                     PICKS, Wf1, bf1, Wf2, bf2, out);
}